// Round 12
// baseline (503.585 us; speedup 1.0000x reference)
//
#include <hip/hip_runtime.h>

typedef unsigned int uint;
typedef unsigned short ushort;

// ---------------------------------------------------------------------------
// GAT x3 + ReLU + BatchNorm, MI355X.
// R20 change (single theory): R17/R19 both proved k_agg's hot loop at
// VGPR 32 is a local optimum (any widening/pipelining -> VGPR ~52 ->
// occupancy 64->34% -> slower). So: hot loops reverted to R18 EXACT, and
// instead we DELETE the 3 k_bn_stats kernels (each re-reads the 25.6MB
// ybuf k_agg just produced) by fusing stats into k_agg's y-write points:
// LDS lsum/lsum2[F] (1KB/block), LDS atomicAdd at output store, then one
// global atomicAdd per channel per block into 32 contention-spreading
// slots (12.5K blocks / 32 slots ~ 390 same-address atomics). k_bn_prep
// reduces the 32 slots. Early returns replaced by guarded block so all
// threads reach the 2 new barriers.
// gemm3/wconv3 (R16), CSR (R10) verbatim.
// ---------------------------------------------------------------------------

#define NSLOT 32

static __device__ __forceinline__ ushort bf16_rne(float x) {
    uint u = __float_as_uint(x);
    return (ushort)((u + 0x7fffu + ((u >> 16) & 1u)) >> 16);
}
static __device__ __forceinline__ float bf16_f(ushort h) {
    return __uint_as_float(((uint)h) << 16);
}

// ---------------- bucket-sort CSR build ----------------
__global__ __launch_bounds__(256) void k_bcount(const int* __restrict__ dst, int e,
                                                int* __restrict__ bcntp) {
    __shared__ int h[512];
    int tid = threadIdx.x;
    h[tid] = 0;
    h[tid + 256] = 0;
    __syncthreads();
    int stride = gridDim.x * 256;
    for (int i = blockIdx.x * 256 + tid; i < e; i += stride)
        atomicAdd(&h[dst[i] >> 7], 1);
    __syncthreads();
    if (h[tid]) atomicAdd(&bcntp[tid * 16], h[tid]);
    if (h[tid + 256]) atomicAdd(&bcntp[(tid + 256) * 16], h[tid + 256]);
}

__global__ __launch_bounds__(512) void k_bscan(const int* __restrict__ bcntp,
                                               int* __restrict__ bbase,
                                               int* __restrict__ bcurp, int nb, int n,
                                               int total, int* __restrict__ row_start) {
    __shared__ int s[512];
    int tid = threadIdx.x;
    int v = 0;
    if (tid < nb) v = bcntp[tid * 16] + min(128, n - (tid << 7));  // + self-loops
    s[tid] = v;
    __syncthreads();
    for (int off = 1; off < 512; off <<= 1) {
        int t = (tid >= off) ? s[tid - off] : 0;
        __syncthreads();
        s[tid] += t;
        __syncthreads();
    }
    if (tid < nb) {
        int excl = s[tid] - v;
        bbase[tid] = excl;
        bcurp[tid * 16] = excl;
    }
    if (tid == 0) {
        bbase[nb] = total;
        row_start[n] = total;
    }
}

// multisplit: chunk of 8192 items -> LDS bucket-sort -> coalesced copy-out
__global__ __launch_bounds__(512) void k_bscatter(const int* __restrict__ src,
                                                  const int* __restrict__ dst, int e, int n,
                                                  int* __restrict__ bcurp,
                                                  int* __restrict__ pk) {
    __shared__ int hcnt[512], bstart[512], bcursor[512], gbase[512];
    __shared__ int stage[8192];
    int tid = threadIdx.x;
    int total = e + n;
    int nchunk = (total + 8191) >> 13;
    for (int c = blockIdx.x; c < nchunk; c += gridDim.x) {
        int base = c << 13;
        int cnt = min(8192, total - base);
        hcnt[tid] = 0;
        __syncthreads();
        for (int j = tid; j < cnt; j += 512) {
            int i = base + j;
            int d = (i < e) ? dst[i] : (i - e);
            atomicAdd(&hcnt[d >> 7], 1);
        }
        __syncthreads();
        int v = hcnt[tid];
        bstart[tid] = v;
        __syncthreads();
        for (int off = 1; off < 512; off <<= 1) {  // inclusive scan in-place
            int t = (tid >= off) ? bstart[tid - off] : 0;
            __syncthreads();
            bstart[tid] += t;
            __syncthreads();
        }
        int excl = bstart[tid] - v;
        __syncthreads();
        bstart[tid] = excl;
        bcursor[tid] = excl;
        if (v) gbase[tid] = atomicAdd(&bcurp[tid * 16], v);
        __syncthreads();
        for (int j = tid; j < cnt; j += 512) {
            int i = base + j;
            int d, sv;
            if (i < e) { d = dst[i]; sv = src[i]; }
            else       { d = i - e; sv = d; }
            uint b = (uint)(d >> 7);
            int r = atomicAdd(&bcursor[b], 1);
            stage[r] = (int)((b << 23) | ((uint)(d & 127) << 16) | (uint)sv);
        }
        __syncthreads();
        for (int j = tid; j < cnt; j += 512) {
            int p = stage[j];
            int b = (int)(((uint)p) >> 23);
            pk[gbase[b] + (j - bstart[b])] = p;   // coalesced runs per bucket
        }
        __syncthreads();
    }
}

// one block per bucket: local CSR entirely in LDS, coalesced global I/O
__global__ __launch_bounds__(256) void k_bfill(const int* __restrict__ pk,
                                               const int* __restrict__ bbase, int n,
                                               int* __restrict__ row_start,
                                               int* __restrict__ col) {
    int b = blockIdx.x;
    int s0 = bbase[b], s1 = bbase[b + 1];
    int seg = s1 - s0;
    int node0 = b << 7;
    int nn = min(128, n - node0);
    int tid = threadIdx.x;
    __shared__ int cnt[128], scn[128];
    __shared__ int colst[4608];
    if (tid < 128) cnt[tid] = 0;
    __syncthreads();
    for (int j = tid; j < seg; j += 256)
        atomicAdd(&cnt[(pk[s0 + j] >> 16) & 127], 1);
    __syncthreads();
    int myc = 0;
    if (tid < 128) { myc = cnt[tid]; scn[tid] = myc; }
    __syncthreads();
    for (int off = 1; off < 128; off <<= 1) {
        int t = (tid >= off && tid < 128) ? scn[tid - off] : 0;
        __syncthreads();
        if (tid < 128) scn[tid] += t;
        __syncthreads();
    }
    int excl = 0;
    if (tid < 128) excl = scn[tid] - myc;
    if (tid < nn) row_start[node0 + tid] = s0 + excl;
    __syncthreads();
    if (tid < 128) cnt[tid] = excl;   // becomes cursor
    __syncthreads();
    bool big = seg > 4608;            // fallback guard (never expected)
    for (int j = tid; j < seg; j += 256) {
        int p = pk[s0 + j];
        int r = atomicAdd(&cnt[(p >> 16) & 127], 1);
        if (big) col[s0 + r] = p & 0xffff;
        else colst[r] = p & 0xffff;
    }
    if (!big) {
        __syncthreads();
        for (int j = tid; j < seg; j += 256) col[s0 + j] = colst[j];
    }
}

// ---------------- W pre-conversion: coalesced fragment blocks ---------------
typedef __attribute__((ext_vector_type(8))) short short8;
typedef __attribute__((ext_vector_type(4))) float float4v;

// W fp32 [128][F] -> whi/wlo in lane-major fragment blocks:
//   block (tg,ks): 64 lanes x short8; lane=quad*16+l15 holds
//   column n=tg*16+l15, k=ks*32+quad*8..+8.
// cvec[n] = sum_k sh[k]*W[k][n] (useBN) else 0. One wave per column.
template <int F>
__global__ __launch_bounds__(256) void k_wconv3(const float* __restrict__ W,
                                                const float* __restrict__ sc,
                                                const float* __restrict__ sh, int useBN,
                                                ushort* __restrict__ whi,
                                                ushort* __restrict__ wlo,
                                                float* __restrict__ cvec) {
    int n = (blockIdx.x * blockDim.x + threadIdx.x) >> 6;  // wave id = column
    int lane = threadIdx.x & 63;
    if (n >= F) return;
    float c = 0.f;
    if (useBN) {
#pragma unroll
        for (int i = 0; i < 2; i++) {
            int k = lane + i * 64;
            c = fmaf(sh[k], W[k * F + n], c);
        }
#pragma unroll
        for (int off = 32; off; off >>= 1) c += __shfl_xor(c, off);
    }
    if (lane == 0) cvec[n] = c;
    // fragment emit: lanes 0..15 each handle one (ks,quad) octet of column n
    if (lane < 16) {
        int ks = lane >> 2, quad = lane & 3;
        int tg = n >> 4, l15 = n & 15;
        long long off8 = ((long long)((tg * 4 + ks) * 64 + quad * 16 + l15)) * 8;
        short8 h8, l8;
#pragma unroll
        for (int j = 0; j < 8; j++) {
            int k = ks * 32 + quad * 8 + j;
            float w = W[k * F + n];
            float wsv = useBN ? w * sc[k] : w;
            ushort h = bf16_rne(wsv);
            h8[j] = (short)h;
            l8[j] = (short)bf16_rne(wsv - bf16_f(h));
        }
        *(short8*)(whi + off8) = h8;
        *(short8*)(wlo + off8) = l8;
    }
}

// ---- GEMM: A[M,128] @ Wfrag -> bf16 xwb + logits. No LDS/barriers. --------
static __device__ __forceinline__ void cvt8(const float4& f0, const float4& f1,
                                            short8& hi, short8& lo) {
#define CV8(i, val)                                        \
    {                                                      \
        ushort h_ = bf16_rne(val);                         \
        hi[i] = (short)h_;                                 \
        lo[i] = (short)bf16_rne((val)-bf16_f(h_));         \
    }
    CV8(0, f0.x) CV8(1, f0.y) CV8(2, f0.z) CV8(3, f0.w)
    CV8(4, f1.x) CV8(5, f1.y) CV8(6, f1.z) CV8(7, f1.w)
#undef CV8
}

template <int F, int H>
__global__ __launch_bounds__(256) void k_gemm3(const float* __restrict__ A,
                                               const ushort* __restrict__ whi,
                                               const ushort* __restrict__ wlo,
                                               const float* __restrict__ cvec,
                                               const float* __restrict__ asrc,
                                               const float* __restrict__ adst,
                                               ushort* __restrict__ xwb,
                                               float* __restrict__ al_s,
                                               float* __restrict__ al_d, int M) {
    constexpr bool SPLIT = (F == 128);          // split 8 col-tiles across wave pair
    constexpr int RPB = SPLIT ? 32 : 64;        // rows per block
    int tid = threadIdx.x;
    int wave = tid >> 6, lane = tid & 63;
    int quad = lane >> 4, l15 = lane & 15;
    int rg = SPLIT ? (wave >> 1) : wave;
    int half = SPLIT ? (wave & 1) : 0;
    int base = blockIdx.x * RPB + rg * 16;
    int coff = half * 64;                       // this wave's column offset
    int tgb = SPLIT ? half * 4 : 0;             // global tile base

    float4v acc[4];
#pragma unroll
    for (int t = 0; t < 4; t++) acc[t] = (float4v){0.f, 0.f, 0.f, 0.f};

    int arow = base + l15;
    bool aval = (arow < M);
    const float* Ap = A + (long long)arow * 128;

#pragma unroll
    for (int ks = 0; ks < 4; ks++) {
        float4 f0 = {0.f, 0.f, 0.f, 0.f}, f1 = {0.f, 0.f, 0.f, 0.f};
        if (aval) {
            f0 = *(const float4*)(Ap + ks * 32 + quad * 8);
            f1 = *(const float4*)(Ap + ks * 32 + quad * 8 + 4);
        }
        short8 ah, al;
        cvt8(f0, f1, ah, al);
#pragma unroll
        for (int t = 0; t < 4; t++) {
            // coalesced lane-major fragment block
            long long boff = ((long long)(((tgb + t) * 4 + ks) * 64 + lane)) * 8;
            short8 bh = *(const short8*)(whi + boff);
            short8 bl = *(const short8*)(wlo + boff);
            acc[t] = __builtin_amdgcn_mfma_f32_16x16x32_bf16(ah, bh, acc[t], 0, 0, 0);
            acc[t] = __builtin_amdgcn_mfma_f32_16x16x32_bf16(ah, bl, acc[t], 0, 0, 0);
            acc[t] = __builtin_amdgcn_mfma_f32_16x16x32_bf16(al, bh, acc[t], 0, 0, 0);
        }
    }

    // ---- epilogue: C[row=quad*4+r][col(tile)=l15], tile t -> col coff+t*16+l15
    float cv[4], asl[4], adl[4];
#pragma unroll
    for (int t = 0; t < 4; t++) {
        int n = coff + t * 16 + l15;
        cv[t] = cvec[n];
        asl[t] = asrc[n];
        adl[t] = adst[n];
    }
#pragma unroll
    for (int r = 0; r < 4; r++) {
        int grow = base + quad * 4 + r;
        float v0 = acc[0][r] + cv[0];
        float v1 = acc[1][r] + cv[1];
        float v2 = acc[2][r] + cv[2];
        float v3 = acc[3][r] + cv[3];
        if (grow < M) {
            ushort* xp = xwb + (long long)grow * F + coff + l15;
            xp[0] = bf16_rne(v0);
            xp[16] = bf16_rne(v1);
            xp[32] = bf16_rne(v2);
            xp[48] = bf16_rne(v3);
        }
        float ps = 0.f, pd = 0.f;
        ps = fmaf(v0, asl[0], ps); pd = fmaf(v0, adl[0], pd);
        ps = fmaf(v1, asl[1], ps); pd = fmaf(v1, adl[1], pd);
        ps = fmaf(v2, asl[2], ps); pd = fmaf(v2, adl[2], pd);
        ps = fmaf(v3, asl[3], ps); pd = fmaf(v3, adl[3], pd);
#pragma unroll
        for (int off = 1; off < 16; off <<= 1) {
            ps += __shfl_xor(ps, off);
            pd += __shfl_xor(pd, off);
        }
        if (l15 == 0 && grow < M) {
            al_s[grow * H + half] = ps;
            al_d[grow * H + half] = pd;
        }
    }
}

// ------- per-dst-wave softmax aggregation + fused BN stats (R20) -----------
// Hot loops identical to R18. Adds: LDS lsum/lsum2[F] accumulated at
// y-write points, flushed via global atomicAdd into NSLOT slots.
template <int F, int H>
__global__ __launch_bounds__(256) void k_agg(const uint* __restrict__ xwb,
                      const float* __restrict__ al_s,
                      const float* __restrict__ al_d, const int* __restrict__ row_start,
                      const int* __restrict__ col, const float* __restrict__ bias,
                      float* __restrict__ y, float* __restrict__ stats, int n) {
    __shared__ float lsum[F], lsum2[F];
    int tid = threadIdx.x;
    if (tid < F) {
        lsum[tid] = 0.f;
        lsum2[tid] = 0.f;
    }
    __syncthreads();

    int wid = (blockIdx.x * blockDim.x + tid) >> 6;  // one wave per dst
    int lane = tid & 63;

    if (wid < n) {
        int beg = row_start[wid], end = row_start[wid + 1];

        float ald[H];
#pragma unroll
        for (int h = 0; h < H; h++) ald[h] = al_d[wid * H + h];

        if (end - beg <= 64) {
            // ---------------- fast path: one lane = one edge ----------------
            int nb = end - beg;
            int s_c = 0;
            float ev0 = -1e30f, ev1 = -1e30f;
            if (lane < nb) {
                s_c = col[beg + lane];
                if (H == 2) {
                    float2 av = ((const float2*)al_s)[s_c];
                    float e0 = av.x + ald[0];
                    float e1 = av.y + ald[1];
                    ev0 = (e0 >= 0.f) ? e0 : 0.2f * e0;
                    ev1 = (e1 >= 0.f) ? e1 : 0.2f * e1;
                } else {
                    float e0 = al_s[s_c] + ald[0];
                    ev0 = (e0 >= 0.f) ? e0 : 0.2f * e0;
                }
            }
            // max butterfly
            float m0 = ev0, m1 = ev1;
#pragma unroll
            for (int off = 32; off; off >>= 1) {
                m0 = fmaxf(m0, __shfl_xor(m0, off));
                if (H == 2) m1 = fmaxf(m1, __shfl_xor(m1, off));
            }
            // exp once; sum butterfly; alpha free (0 for lanes >= nb)
            float x0 = (lane < nb) ? __expf(ev0 - m0) : 0.f;
            float x1 = (H == 2 && lane < nb) ? __expf(ev1 - m1) : 0.f;
            float l0 = x0, l1 = x1;
#pragma unroll
            for (int off = 32; off; off >>= 1) {
                l0 += __shfl_xor(l0, off);
                if (H == 2) l1 += __shfl_xor(l1, off);
            }
            float a0 = x0 / (l0 + 1e-16f);
            float a1 = (H == 2) ? x1 / (l1 + 1e-16f) : a0;

            // ---- accumulate: 8 uint2 loads (4KB) in flight ----
            float accv0 = 0.f, accv1 = 0.f, accv2 = 0.f, accv3 = 0.f;
            const uint2* xw2 = (const uint2*)xwb;

            if (F == 128) {
                // lane covers cols 4*li..4*li+3 of rows for half = lane>>5
                int li = lane & 31;
                int half = lane >> 5;
                bool head0 = (li < 16);           // col<64 <=> li<16
                for (int j = 0; j < nb; j += 16) {
                    int rr[8];
                    float alq[8];
#pragma unroll
                    for (int q = 0; q < 8; q++) {
                        int e = j + 2 * q + half;     // <= 63 since nb<=64
                        rr[q] = __shfl(s_c, e);
                        float aa = __shfl(a0, e);
                        float bb = __shfl(a1, e);
                        alq[q] = (H == 2) ? (head0 ? aa : bb) : aa;
                    }
                    uint2 uu[8];
#pragma unroll
                    for (int q = 0; q < 8; q++)
                        uu[q] = xw2[(rr[q] << 5) + li];
#pragma unroll
                    for (int q = 0; q < 8; q++) {
                        accv0 = fmaf(alq[q], __uint_as_float(uu[q].x << 16), accv0);
                        accv1 = fmaf(alq[q], __uint_as_float(uu[q].x & 0xffff0000u), accv1);
                        accv2 = fmaf(alq[q], __uint_as_float(uu[q].y << 16), accv2);
                        accv3 = fmaf(alq[q], __uint_as_float(uu[q].y & 0xffff0000u), accv3);
                    }
                }
                // cross-half reduce: lane l and l^32 hold same cols
                accv0 += __shfl_xor(accv0, 32);
                accv1 += __shfl_xor(accv1, 32);
                accv2 += __shfl_xor(accv2, 32);
                accv3 += __shfl_xor(accv3, 32);
                if (li == lane) {  // lane < 32
                    float4 o;
                    o.x = fmaxf(accv0 + bias[4 * li + 0], 0.f);
                    o.y = fmaxf(accv1 + bias[4 * li + 1], 0.f);
                    o.z = fmaxf(accv2 + bias[4 * li + 2], 0.f);
                    o.w = fmaxf(accv3 + bias[4 * li + 3], 0.f);
                    ((float4*)y)[(long long)wid * 32 + li] = o;
                    atomicAdd(&lsum[4 * li + 0], o.x);
                    atomicAdd(&lsum[4 * li + 1], o.y);
                    atomicAdd(&lsum[4 * li + 2], o.z);
                    atomicAdd(&lsum[4 * li + 3], o.w);
                    atomicAdd(&lsum2[4 * li + 0], o.x * o.x);
                    atomicAdd(&lsum2[4 * li + 1], o.y * o.y);
                    atomicAdd(&lsum2[4 * li + 2], o.z * o.z);
                    atomicAdd(&lsum2[4 * li + 3], o.w * o.w);
                }
            } else {
                // F=64, H=1: lane covers cols 4*li..4*li+3, group g = lane>>4
                int li = lane & 15;
                int g = lane >> 4;
                for (int j = 0; j < nb; j += 32) {
                    int rr[8];
                    float alq[8];
#pragma unroll
                    for (int q = 0; q < 8; q++) {
                        int e = j + 4 * q + g;        // <= 63 since nb<=64
                        rr[q] = __shfl(s_c, e);
                        alq[q] = __shfl(a0, e);
                    }
                    uint2 uu[8];
#pragma unroll
                    for (int q = 0; q < 8; q++)
                        uu[q] = xw2[(rr[q] << 4) + li];
#pragma unroll
                    for (int q = 0; q < 8; q++) {
                        accv0 = fmaf(alq[q], __uint_as_float(uu[q].x << 16), accv0);
                        accv1 = fmaf(alq[q], __uint_as_float(uu[q].x & 0xffff0000u), accv1);
                        accv2 = fmaf(alq[q], __uint_as_float(uu[q].y << 16), accv2);
                        accv3 = fmaf(alq[q], __uint_as_float(uu[q].y & 0xffff0000u), accv3);
                    }
                }
                // reduce across 4 groups (lanes sharing li)
                accv0 += __shfl_xor(accv0, 16); accv0 += __shfl_xor(accv0, 32);
                accv1 += __shfl_xor(accv1, 16); accv1 += __shfl_xor(accv1, 32);
                accv2 += __shfl_xor(accv2, 16); accv2 += __shfl_xor(accv2, 32);
                accv3 += __shfl_xor(accv3, 16); accv3 += __shfl_xor(accv3, 32);
                if (lane < 16) {
                    float4 o;
                    o.x = fmaxf(accv0 + bias[4 * li + 0], 0.f);
                    o.y = fmaxf(accv1 + bias[4 * li + 1], 0.f);
                    o.z = fmaxf(accv2 + bias[4 * li + 2], 0.f);
                    o.w = fmaxf(accv3 + bias[4 * li + 3], 0.f);
                    ((float4*)y)[(long long)wid * 16 + li] = o;
                    atomicAdd(&lsum[4 * li + 0], o.x);
                    atomicAdd(&lsum[4 * li + 1], o.y);
                    atomicAdd(&lsum[4 * li + 2], o.z);
                    atomicAdd(&lsum[4 * li + 3], o.w);
                    atomicAdd(&lsum2[4 * li + 0], o.x * o.x);
                    atomicAdd(&lsum2[4 * li + 1], o.y * o.y);
                    atomicAdd(&lsum2[4 * li + 2], o.z * o.z);
                    atomicAdd(&lsum2[4 * li + 3], o.w * o.w);
                }
            }
        } else {
            // ------------- generic path (deg > 64), original code -------------
            float acc0 = 0.f, acc1 = 0.f;
            {
                float m[H], l[H];
#pragma unroll
                for (int h = 0; h < H; h++) {
                    m[h] = -1e30f;
                    l[h] = 0.f;
                }
                for (int e = beg + lane; e < end; e += 64) {
                    int s = col[e];
#pragma unroll
                    for (int h = 0; h < H; h++) {
                        float ev = al_s[s * H + h] + ald[h];
                        ev = (ev >= 0.f) ? ev : 0.2f * ev;
                        if (ev > m[h]) {
                            l[h] = l[h] * __expf(m[h] - ev) + 1.f;
                            m[h] = ev;
                        } else {
                            l[h] += __expf(ev - m[h]);
                        }
                    }
                }
#pragma unroll
                for (int off = 32; off; off >>= 1) {
#pragma unroll
                    for (int h = 0; h < H; h++) {
                        float mo = __shfl_xor(m[h], off);
                        float lo = __shfl_xor(l[h], off);
                        float mn = fmaxf(m[h], mo);
                        l[h] = l[h] * __expf(m[h] - mn) + lo * __expf(mo - mn);
                        m[h] = mn;
                    }
                }
                float inv[H];
#pragma unroll
                for (int h = 0; h < H; h++) inv[h] = 1.f / (l[h] + 1e-16f);

                for (int base = beg; base < end; base += 64) {
                    int nb = min(64, end - base);
                    int ec = min(base + lane, end - 1);
                    int s = col[ec];
                    float a0, a1;
                    {
                        float av[H];
#pragma unroll
                        for (int h = 0; h < H; h++) {
                            float ev = al_s[s * H + h] + ald[h];
                            ev = (ev >= 0.f) ? ev : 0.2f * ev;
                            av[h] = __expf(ev - m[h]) * inv[h];
                        }
                        a0 = av[0];
                        a1 = av[H - 1];
                    }
                    int j = 0;
                    for (; j + 4 <= nb; j += 4) {
                        int s0 = __shfl(s, j + 0), s1 = __shfl(s, j + 1);
                        int s2 = __shfl(s, j + 2), s3 = __shfl(s, j + 3);
                        float q00 = __shfl(a0, j + 0), q01 = __shfl(a1, j + 0);
                        float q10 = __shfl(a0, j + 1), q11 = __shfl(a1, j + 1);
                        float q20 = __shfl(a0, j + 2), q21 = __shfl(a1, j + 2);
                        float q30 = __shfl(a0, j + 3), q31 = __shfl(a1, j + 3);
                        float p0, p1, p2, p3;
                        if (H == 2) {
                            p0 = (lane < 32) ? q00 : q01;
                            p1 = (lane < 32) ? q10 : q11;
                            p2 = (lane < 32) ? q20 : q21;
                            p3 = (lane < 32) ? q30 : q31;
                        } else {
                            p0 = q00; p1 = q10; p2 = q20; p3 = q30;
                        }
                        if (F == 128) {
                            uint u0 = xwb[(s0 << 6) + lane];
                            uint u1 = xwb[(s1 << 6) + lane];
                            uint u2 = xwb[(s2 << 6) + lane];
                            uint u3 = xwb[(s3 << 6) + lane];
                            acc0 = fmaf(p0, __uint_as_float(u0 << 16), acc0);
                            acc1 = fmaf(p0, __uint_as_float(u0 & 0xffff0000u), acc1);
                            acc0 = fmaf(p1, __uint_as_float(u1 << 16), acc0);
                            acc1 = fmaf(p1, __uint_as_float(u1 & 0xffff0000u), acc1);
                            acc0 = fmaf(p2, __uint_as_float(u2 << 16), acc0);
                            acc1 = fmaf(p2, __uint_as_float(u2 & 0xffff0000u), acc1);
                            acc0 = fmaf(p3, __uint_as_float(u3 << 16), acc0);
                            acc1 = fmaf(p3, __uint_as_float(u3 & 0xffff0000u), acc1);
                        } else {
                            int idx = lane >> 1;
                            bool hi = (lane & 1) != 0;
                            uint u0 = xwb[(s0 << 5) + idx];
                            uint u1 = xwb[(s1 << 5) + idx];
                            uint u2 = xwb[(s2 << 5) + idx];
                            uint u3 = xwb[(s3 << 5) + idx];
                            acc0 = fmaf(p0, __uint_as_float(hi ? (u0 & 0xffff0000u) : (u0 << 16)), acc0);
                            acc0 = fmaf(p1, __uint_as_float(hi ? (u1 & 0xffff0000u) : (u1 << 16)), acc0);
                            acc0 = fmaf(p2, __uint_as_float(hi ? (u2 & 0xffff0000u) : (u2 << 16)), acc0);
                            acc0 = fmaf(p3, __uint_as_float(hi ? (u3 & 0xffff0000u) : (u3 << 16)), acc0);
                        }
                    }
                    for (; j < nb; ++j) {
                        int sj = __shfl(s, j);
                        float q0 = __shfl(a0, j);
                        float q1 = __shfl(a1, j);
                        float alpha;
                        if (H == 2) {
                            alpha = (lane < 32) ? q0 : q1;
                        } else {
                            alpha = q0;
                        }
                        if (F == 128) {
                            uint u = xwb[(sj << 6) + lane];
                            acc0 = fmaf(alpha, __uint_as_float(u << 16), acc0);
                            acc1 = fmaf(alpha, __uint_as_float(u & 0xffff0000u), acc1);
                        } else {
                            uint u = xwb[(sj << 5) + (lane >> 1)];
                            acc0 = fmaf(alpha, __uint_as_float((lane & 1) ? (u & 0xffff0000u) : (u << 16)), acc0);
                        }
                    }
                }
            }

            if (F == 128) {
                float2 o;
                o.x = fmaxf(acc0 + bias[2 * lane], 0.f);
                o.y = fmaxf(acc1 + bias[2 * lane + 1], 0.f);
                ((float2*)y)[(long long)wid * 64 + lane] = o;
                atomicAdd(&lsum[2 * lane + 0], o.x);
                atomicAdd(&lsum[2 * lane + 1], o.y);
                atomicAdd(&lsum2[2 * lane + 0], o.x * o.x);
                atomicAdd(&lsum2[2 * lane + 1], o.y * o.y);
            } else {
                float o = fmaxf(acc0 + bias[lane], 0.f);
                y[(long long)wid * 64 + lane] = o;
                atomicAdd(&lsum[lane], o);
                atomicAdd(&lsum2[lane], o * o);
            }
        }
    }

    // ---- flush block stats into slot (spread contention over NSLOT) ----
    __syncthreads();
    float* sl = stats + (blockIdx.x & (NSLOT - 1)) * (2 * F);
    if (tid < F) {
        atomicAdd(&sl[tid], lsum[tid]);
        atomicAdd(&sl[F + tid], lsum2[tid]);
    }
}

// ---------------- BatchNorm prep (reduces NSLOT slots) ----------------
template <int F>
__global__ void k_bn_prep(const float* __restrict__ stats, const float* __restrict__ g,
                          const float* __restrict__ be, float* __restrict__ sc,
                          float* __restrict__ sh, float invN) {
    int ch = threadIdx.x;
    if (ch < F) {
        float s = 0.f, s2 = 0.f;
        for (int k = 0; k < NSLOT; k++) {
            s += stats[k * 2 * F + ch];
            s2 += stats[k * 2 * F + F + ch];
        }
        float mean = s * invN;
        float var = s2 * invN - mean * mean;
        float sv = g[ch] * rsqrtf(var + 1e-5f);
        sc[ch] = sv;
        sh[ch] = be[ch] - mean * sv;
    }
}

template <int F>
__global__ void k_bn_apply(const float* __restrict__ y, const float* __restrict__ sc,
                           const float* __restrict__ sh, float* __restrict__ outp, int n) {
    constexpr int C4 = F / 4;
    int t = blockIdx.x * blockDim.x + threadIdx.x;
    if (t >= n * C4) return;
    int node = t / C4, c4 = t % C4;
    float4 v = ((const float4*)y)[t];
    float4 o;
    o.x = v.x * sc[c4 * 4 + 0] + sh[c4 * 4 + 0];
    o.y = v.y * sc[c4 * 4 + 1] + sh[c4 * 4 + 1];
    o.z = v.z * sc[c4 * 4 + 2] + sh[c4 * 4 + 2];
    o.w = v.w * sc[c4 * 4 + 3] + sh[c4 * 4 + 3];
    ((float4*)(outp + (long long)node * 320))[c4] = o;
}

// ---------------------------------------------------------------------------
extern "C" void kernel_launch(void* const* d_in, const int* in_sizes, int n_in,
                              void* d_out, int out_size, void* d_ws, size_t ws_size,
                              hipStream_t stream) {
    const float* x   = (const float*)d_in[0];
    const int*   adj = (const int*)d_in[1];
    const float* W1  = (const float*)d_in[2];
    const float* as1 = (const float*)d_in[3];
    const float* ad1 = (const float*)d_in[4];
    const float* b1  = (const float*)d_in[5];
    const float* g1  = (const float*)d_in[6];
    const float* be1 = (const float*)d_in[7];
    const float* W2  = (const float*)d_in[8];
    const float* as2 = (const float*)d_in[9];
    const float* ad2 = (const float*)d_in[10];
    const float* b2  = (const float*)d_in[11];
    const float* g2  = (const float*)d_in[12];
    const float* be2 = (const float*)d_in[13];
    const float* W3  = (const float*)d_in[14];
    const float* as3 = (const float*)d_in[15];
    const float* ad3 = (const float*)d_in[16];
    const float* b3  = (const float*)d_in[17];
    const float* g3  = (const float*)d_in[18];
    const float* be3 = (const float*)d_in[19];
    float* out = (float*)d_out;

    const int N = in_sizes[0] / 128;
    const int E = in_sizes[1] / 2;

    // workspace
    float* ws    = (float*)d_ws;
    float* ybuf  = ws;                          // N*128
    float* al_s  = ybuf + (size_t)N * 128;      // N*2
    float* al_d  = al_s + (size_t)N * 2;        // N*2
    float* stats1 = al_d + (size_t)N * 2;       // NSLOT*256
    float* stats2 = stats1 + NSLOT * 256;       // NSLOT*256
    float* stats3 = stats2 + NSLOT * 256;       // NSLOT*256 (F=64 uses 128/slot)
    float* scb   = stats3 + NSLOT * 256;        // 128
    float* shb   = scb + 128;                   // 128
    uint* xwb    = (uint*)(shb + 128);          // N*64 uints (bf16x2)
    int* ibase     = (int*)(xwb + (size_t)N * 64);
    int* bcntp     = ibase;                     // 512*16 (line-padded counts)
    int* bcurp     = bcntp + 8192;              // 512*16 (line-padded cursors)
    int* bbase     = bcurp + 8192;              // 513
    int* row_start = ibase + N;                 // N+1
    int* btot      = row_start + (N + 1);       // 64 (unused, layout keep)
    int* col       = btot + 64;                 // E+N

    // pre-converted W (bf16 hi/lo fragment blocks) + folded-BN constants
    uintptr_t wp = (uintptr_t)(col + (E + N));
    wp = (wp + 63) & ~(uintptr_t)63;
    ushort* w1hi = (ushort*)wp;                 // 128*128
    ushort* w1lo = w1hi + 16384;
    ushort* w2hi = w1lo + 16384;
    ushort* w2lo = w2hi + 16384;
    ushort* w3hi = w2lo + 16384;                // 64*128
    ushort* w3lo = w3hi + 8192;
    float* c1 = (float*)(w3lo + 8192);          // 128
    float* c2 = c1 + 128;                       // 128
    float* c3 = c2 + 128;                       // 64

    // packed bucket-sorted edges alias ybuf (dead before k_agg L1 writes it)
    int* pk = (int*)ybuf;                       // E+N ints

    const int* esrc = adj;
    const int* edst = adj + E;

    const int B = 256;
    auto cdiv = [](int a, int b) { return (a + b - 1) / b; };

    // ---- one upfront memset for all 3 BN stats slot-arrays ----
    hipMemsetAsync(stats1, 0, (size_t)3 * NSLOT * 256 * sizeof(float), stream);

    // ---- W1 conversion (no BN): 1 wave per column ----
    k_wconv3<128><<<32, 256, 0, stream>>>(W1, nullptr, nullptr, 0, w1hi, w1lo, c1);

    // ---- CSR build: bucket counting sort ----
    const int NB = (N + 127) >> 7;              // buckets (needs N<=65536)
    hipMemsetAsync(bcntp, 0, 8192 * sizeof(int), stream);
    k_bcount<<<128, 256, 0, stream>>>(edst, E, bcntp);
    k_bscan<<<1, 512, 0, stream>>>(bcntp, bbase, bcurp, NB, N, E + N, row_start);
    int nchunk = (E + N + 8191) >> 13;
    k_bscatter<<<nchunk, 512, 0, stream>>>(esrc, edst, E, N, bcurp, pk);
    k_bfill<<<NB, 256, 0, stream>>>(pk, bbase, N, row_start, col);

    const float invN = 1.f / (float)N;
    ushort* xwb_us = (ushort*)xwb;

    // ---- layer 1: 128 -> 128 (H=2) ----
    k_gemm3<128, 2><<<cdiv(N, 32), B, 0, stream>>>(x, w1hi, w1lo, c1,
                                                   as1, ad1, xwb_us, al_s, al_d, N);
    k_agg<128, 2><<<cdiv(N, 4), B, 0, stream>>>(xwb, al_s, al_d, row_start, col, b1,
                                                ybuf, stats1, N);
    k_bn_prep<128><<<1, 128, 0, stream>>>(stats1, g1, be1, scb, shb, invN);
    k_wconv3<128><<<32, 256, 0, stream>>>(W2, scb, shb, 1, w2hi, w2lo, c2);
    k_bn_apply<128><<<cdiv(N * 32, B), B, 0, stream>>>(ybuf, scb, shb, out + 0, N);

    // ---- layer 2: 128 -> 128 (H=2), BN folded into W2 ----
    k_gemm3<128, 2><<<cdiv(N, 32), B, 0, stream>>>(ybuf, w2hi, w2lo, c2,
                                                   as2, ad2, xwb_us, al_s, al_d, N);
    k_agg<128, 2><<<cdiv(N, 4), B, 0, stream>>>(xwb, al_s, al_d, row_start, col, b2,
                                                ybuf, stats2, N);
    k_bn_prep<128><<<1, 128, 0, stream>>>(stats2, g2, be2, scb, shb, invN);
    k_wconv3<64><<<16, 256, 0, stream>>>(W3, scb, shb, 1, w3hi, w3lo, c3);
    k_bn_apply<128><<<cdiv(N * 32, B), B, 0, stream>>>(ybuf, scb, shb, out + 128, N);

    // ---- layer 3: 128 -> 64 (H=1), BN folded into W3 ----
    k_gemm3<64, 1><<<cdiv(N, 64), B, 0, stream>>>(ybuf, w3hi, w3lo, c3,
                                                  as3, ad3, xwb_us, al_s, al_d, N);
    k_agg<64, 1><<<cdiv(N, 4), B, 0, stream>>>(xwb, al_s, al_d, row_start, col, b3,
                                               ybuf, stats3, N);
    k_bn_prep<64><<<1, 64, 0, stream>>>(stats3, g3, be3, scb, shb, invN);
    k_bn_apply<64><<<cdiv(N * 16, B), B, 0, stream>>>(ybuf, scb, shb, out + 256, N);
}

// Round 13
// 437.011 us; speedup vs baseline: 1.1523x; 1.1523x over previous
//
#include <hip/hip_runtime.h>

typedef unsigned int uint;
typedef unsigned short ushort;

// ---------------------------------------------------------------------------
// GAT x3 + ReLU + BatchNorm, MI355X.
// R21: REVERT to R18 exactly (verified 434us). R20's fused BN-stats flush
// cost +66us: 3.2M global fp atomics into 8192 addrs (~390 same-address
// serialized each) + block-tail at the new barrier (occ 79% / VALU 21%).
// R17/R19/R20 all confirm: k_agg's per-dst-wave gather at VGPR 32 is a
// latency-bound local optimum -- occupancy IS the latency hiding; any
// register/sync addition regresses. Separate k_bn_stats restored.
// gemm3/wconv3 (R16), CSR (R10), one upfront stats memset (R18).
// ---------------------------------------------------------------------------

static __device__ __forceinline__ ushort bf16_rne(float x) {
    uint u = __float_as_uint(x);
    return (ushort)((u + 0x7fffu + ((u >> 16) & 1u)) >> 16);
}
static __device__ __forceinline__ float bf16_f(ushort h) {
    return __uint_as_float(((uint)h) << 16);
}

// ---------------- bucket-sort CSR build ----------------
__global__ __launch_bounds__(256) void k_bcount(const int* __restrict__ dst, int e,
                                                int* __restrict__ bcntp) {
    __shared__ int h[512];
    int tid = threadIdx.x;
    h[tid] = 0;
    h[tid + 256] = 0;
    __syncthreads();
    int stride = gridDim.x * 256;
    for (int i = blockIdx.x * 256 + tid; i < e; i += stride)
        atomicAdd(&h[dst[i] >> 7], 1);
    __syncthreads();
    if (h[tid]) atomicAdd(&bcntp[tid * 16], h[tid]);
    if (h[tid + 256]) atomicAdd(&bcntp[(tid + 256) * 16], h[tid + 256]);
}

__global__ __launch_bounds__(512) void k_bscan(const int* __restrict__ bcntp,
                                               int* __restrict__ bbase,
                                               int* __restrict__ bcurp, int nb, int n,
                                               int total, int* __restrict__ row_start) {
    __shared__ int s[512];
    int tid = threadIdx.x;
    int v = 0;
    if (tid < nb) v = bcntp[tid * 16] + min(128, n - (tid << 7));  // + self-loops
    s[tid] = v;
    __syncthreads();
    for (int off = 1; off < 512; off <<= 1) {
        int t = (tid >= off) ? s[tid - off] : 0;
        __syncthreads();
        s[tid] += t;
        __syncthreads();
    }
    if (tid < nb) {
        int excl = s[tid] - v;
        bbase[tid] = excl;
        bcurp[tid * 16] = excl;
    }
    if (tid == 0) {
        bbase[nb] = total;
        row_start[n] = total;
    }
}

// multisplit: chunk of 8192 items -> LDS bucket-sort -> coalesced copy-out
__global__ __launch_bounds__(512) void k_bscatter(const int* __restrict__ src,
                                                  const int* __restrict__ dst, int e, int n,
                                                  int* __restrict__ bcurp,
                                                  int* __restrict__ pk) {
    __shared__ int hcnt[512], bstart[512], bcursor[512], gbase[512];
    __shared__ int stage[8192];
    int tid = threadIdx.x;
    int total = e + n;
    int nchunk = (total + 8191) >> 13;
    for (int c = blockIdx.x; c < nchunk; c += gridDim.x) {
        int base = c << 13;
        int cnt = min(8192, total - base);
        hcnt[tid] = 0;
        __syncthreads();
        for (int j = tid; j < cnt; j += 512) {
            int i = base + j;
            int d = (i < e) ? dst[i] : (i - e);
            atomicAdd(&hcnt[d >> 7], 1);
        }
        __syncthreads();
        int v = hcnt[tid];
        bstart[tid] = v;
        __syncthreads();
        for (int off = 1; off < 512; off <<= 1) {  // inclusive scan in-place
            int t = (tid >= off) ? bstart[tid - off] : 0;
            __syncthreads();
            bstart[tid] += t;
            __syncthreads();
        }
        int excl = bstart[tid] - v;
        __syncthreads();
        bstart[tid] = excl;
        bcursor[tid] = excl;
        if (v) gbase[tid] = atomicAdd(&bcurp[tid * 16], v);
        __syncthreads();
        for (int j = tid; j < cnt; j += 512) {
            int i = base + j;
            int d, sv;
            if (i < e) { d = dst[i]; sv = src[i]; }
            else       { d = i - e; sv = d; }
            uint b = (uint)(d >> 7);
            int r = atomicAdd(&bcursor[b], 1);
            stage[r] = (int)((b << 23) | ((uint)(d & 127) << 16) | (uint)sv);
        }
        __syncthreads();
        for (int j = tid; j < cnt; j += 512) {
            int p = stage[j];
            int b = (int)(((uint)p) >> 23);
            pk[gbase[b] + (j - bstart[b])] = p;   // coalesced runs per bucket
        }
        __syncthreads();
    }
}

// one block per bucket: local CSR entirely in LDS, coalesced global I/O
__global__ __launch_bounds__(256) void k_bfill(const int* __restrict__ pk,
                                               const int* __restrict__ bbase, int n,
                                               int* __restrict__ row_start,
                                               int* __restrict__ col) {
    int b = blockIdx.x;
    int s0 = bbase[b], s1 = bbase[b + 1];
    int seg = s1 - s0;
    int node0 = b << 7;
    int nn = min(128, n - node0);
    int tid = threadIdx.x;
    __shared__ int cnt[128], scn[128];
    __shared__ int colst[4608];
    if (tid < 128) cnt[tid] = 0;
    __syncthreads();
    for (int j = tid; j < seg; j += 256)
        atomicAdd(&cnt[(pk[s0 + j] >> 16) & 127], 1);
    __syncthreads();
    int myc = 0;
    if (tid < 128) { myc = cnt[tid]; scn[tid] = myc; }
    __syncthreads();
    for (int off = 1; off < 128; off <<= 1) {
        int t = (tid >= off && tid < 128) ? scn[tid - off] : 0;
        __syncthreads();
        if (tid < 128) scn[tid] += t;
        __syncthreads();
    }
    int excl = 0;
    if (tid < 128) excl = scn[tid] - myc;
    if (tid < nn) row_start[node0 + tid] = s0 + excl;
    __syncthreads();
    if (tid < 128) cnt[tid] = excl;   // becomes cursor
    __syncthreads();
    bool big = seg > 4608;            // fallback guard (never expected)
    for (int j = tid; j < seg; j += 256) {
        int p = pk[s0 + j];
        int r = atomicAdd(&cnt[(p >> 16) & 127], 1);
        if (big) col[s0 + r] = p & 0xffff;
        else colst[r] = p & 0xffff;
    }
    if (!big) {
        __syncthreads();
        for (int j = tid; j < seg; j += 256) col[s0 + j] = colst[j];
    }
}

// ---------------- W pre-conversion: coalesced fragment blocks ---------------
typedef __attribute__((ext_vector_type(8))) short short8;
typedef __attribute__((ext_vector_type(4))) float float4v;

// W fp32 [128][F] -> whi/wlo in lane-major fragment blocks:
//   block (tg,ks): 64 lanes x short8; lane=quad*16+l15 holds
//   column n=tg*16+l15, k=ks*32+quad*8..+8.
// cvec[n] = sum_k sh[k]*W[k][n] (useBN) else 0. One wave per column.
template <int F>
__global__ __launch_bounds__(256) void k_wconv3(const float* __restrict__ W,
                                                const float* __restrict__ sc,
                                                const float* __restrict__ sh, int useBN,
                                                ushort* __restrict__ whi,
                                                ushort* __restrict__ wlo,
                                                float* __restrict__ cvec) {
    int n = (blockIdx.x * blockDim.x + threadIdx.x) >> 6;  // wave id = column
    int lane = threadIdx.x & 63;
    if (n >= F) return;
    float c = 0.f;
    if (useBN) {
#pragma unroll
        for (int i = 0; i < 2; i++) {
            int k = lane + i * 64;
            c = fmaf(sh[k], W[k * F + n], c);
        }
#pragma unroll
        for (int off = 32; off; off >>= 1) c += __shfl_xor(c, off);
    }
    if (lane == 0) cvec[n] = c;
    // fragment emit: lanes 0..15 each handle one (ks,quad) octet of column n
    if (lane < 16) {
        int ks = lane >> 2, quad = lane & 3;
        int tg = n >> 4, l15 = n & 15;
        long long off8 = ((long long)((tg * 4 + ks) * 64 + quad * 16 + l15)) * 8;
        short8 h8, l8;
#pragma unroll
        for (int j = 0; j < 8; j++) {
            int k = ks * 32 + quad * 8 + j;
            float w = W[k * F + n];
            float wsv = useBN ? w * sc[k] : w;
            ushort h = bf16_rne(wsv);
            h8[j] = (short)h;
            l8[j] = (short)bf16_rne(wsv - bf16_f(h));
        }
        *(short8*)(whi + off8) = h8;
        *(short8*)(wlo + off8) = l8;
    }
}

// ---- GEMM: A[M,128] @ Wfrag -> bf16 xwb + logits. No LDS/barriers. --------
static __device__ __forceinline__ void cvt8(const float4& f0, const float4& f1,
                                            short8& hi, short8& lo) {
#define CV8(i, val)                                        \
    {                                                      \
        ushort h_ = bf16_rne(val);                         \
        hi[i] = (short)h_;                                 \
        lo[i] = (short)bf16_rne((val)-bf16_f(h_));         \
    }
    CV8(0, f0.x) CV8(1, f0.y) CV8(2, f0.z) CV8(3, f0.w)
    CV8(4, f1.x) CV8(5, f1.y) CV8(6, f1.z) CV8(7, f1.w)
#undef CV8
}

template <int F, int H>
__global__ __launch_bounds__(256) void k_gemm3(const float* __restrict__ A,
                                               const ushort* __restrict__ whi,
                                               const ushort* __restrict__ wlo,
                                               const float* __restrict__ cvec,
                                               const float* __restrict__ asrc,
                                               const float* __restrict__ adst,
                                               ushort* __restrict__ xwb,
                                               float* __restrict__ al_s,
                                               float* __restrict__ al_d, int M) {
    constexpr bool SPLIT = (F == 128);          // split 8 col-tiles across wave pair
    constexpr int RPB = SPLIT ? 32 : 64;        // rows per block
    int tid = threadIdx.x;
    int wave = tid >> 6, lane = tid & 63;
    int quad = lane >> 4, l15 = lane & 15;
    int rg = SPLIT ? (wave >> 1) : wave;
    int half = SPLIT ? (wave & 1) : 0;
    int base = blockIdx.x * RPB + rg * 16;
    int coff = half * 64;                       // this wave's column offset
    int tgb = SPLIT ? half * 4 : 0;             // global tile base

    float4v acc[4];
#pragma unroll
    for (int t = 0; t < 4; t++) acc[t] = (float4v){0.f, 0.f, 0.f, 0.f};

    int arow = base + l15;
    bool aval = (arow < M);
    const float* Ap = A + (long long)arow * 128;

#pragma unroll
    for (int ks = 0; ks < 4; ks++) {
        float4 f0 = {0.f, 0.f, 0.f, 0.f}, f1 = {0.f, 0.f, 0.f, 0.f};
        if (aval) {
            f0 = *(const float4*)(Ap + ks * 32 + quad * 8);
            f1 = *(const float4*)(Ap + ks * 32 + quad * 8 + 4);
        }
        short8 ah, al;
        cvt8(f0, f1, ah, al);
#pragma unroll
        for (int t = 0; t < 4; t++) {
            // coalesced lane-major fragment block
            long long boff = ((long long)(((tgb + t) * 4 + ks) * 64 + lane)) * 8;
            short8 bh = *(const short8*)(whi + boff);
            short8 bl = *(const short8*)(wlo + boff);
            acc[t] = __builtin_amdgcn_mfma_f32_16x16x32_bf16(ah, bh, acc[t], 0, 0, 0);
            acc[t] = __builtin_amdgcn_mfma_f32_16x16x32_bf16(ah, bl, acc[t], 0, 0, 0);
            acc[t] = __builtin_amdgcn_mfma_f32_16x16x32_bf16(al, bh, acc[t], 0, 0, 0);
        }
    }

    // ---- epilogue: C[row=quad*4+r][col(tile)=l15], tile t -> col coff+t*16+l15
    float cv[4], asl[4], adl[4];
#pragma unroll
    for (int t = 0; t < 4; t++) {
        int n = coff + t * 16 + l15;
        cv[t] = cvec[n];
        asl[t] = asrc[n];
        adl[t] = adst[n];
    }
#pragma unroll
    for (int r = 0; r < 4; r++) {
        int grow = base + quad * 4 + r;
        float v0 = acc[0][r] + cv[0];
        float v1 = acc[1][r] + cv[1];
        float v2 = acc[2][r] + cv[2];
        float v3 = acc[3][r] + cv[3];
        if (grow < M) {
            ushort* xp = xwb + (long long)grow * F + coff + l15;
            xp[0] = bf16_rne(v0);
            xp[16] = bf16_rne(v1);
            xp[32] = bf16_rne(v2);
            xp[48] = bf16_rne(v3);
        }
        float ps = 0.f, pd = 0.f;
        ps = fmaf(v0, asl[0], ps); pd = fmaf(v0, adl[0], pd);
        ps = fmaf(v1, asl[1], ps); pd = fmaf(v1, adl[1], pd);
        ps = fmaf(v2, asl[2], ps); pd = fmaf(v2, adl[2], pd);
        ps = fmaf(v3, asl[3], ps); pd = fmaf(v3, adl[3], pd);
#pragma unroll
        for (int off = 1; off < 16; off <<= 1) {
            ps += __shfl_xor(ps, off);
            pd += __shfl_xor(pd, off);
        }
        if (l15 == 0 && grow < M) {
            al_s[grow * H + half] = ps;
            al_d[grow * H + half] = pd;
        }
    }
}

// ---------------- per-dst-wave softmax aggregation (R16/R12 verbatim) -------
template <int F, int H>
__global__ __launch_bounds__(256) void k_agg(const uint* __restrict__ xwb,
                      const float* __restrict__ al_s,
                      const float* __restrict__ al_d, const int* __restrict__ row_start,
                      const int* __restrict__ col, const float* __restrict__ bias,
                      float* __restrict__ y, int n) {
    int wid = (blockIdx.x * blockDim.x + threadIdx.x) >> 6;  // one wave per dst
    int lane = threadIdx.x & 63;
    if (wid >= n) return;
    int beg = row_start[wid], end = row_start[wid + 1];

    float ald[H];
#pragma unroll
    for (int h = 0; h < H; h++) ald[h] = al_d[wid * H + h];

    if (end - beg <= 64) {
        // ---------------- fast path: one lane = one edge ----------------
        int nb = end - beg;
        int s_c = 0;
        float ev0 = -1e30f, ev1 = -1e30f;
        if (lane < nb) {
            s_c = col[beg + lane];
            if (H == 2) {
                float2 av = ((const float2*)al_s)[s_c];
                float e0 = av.x + ald[0];
                float e1 = av.y + ald[1];
                ev0 = (e0 >= 0.f) ? e0 : 0.2f * e0;
                ev1 = (e1 >= 0.f) ? e1 : 0.2f * e1;
            } else {
                float e0 = al_s[s_c] + ald[0];
                ev0 = (e0 >= 0.f) ? e0 : 0.2f * e0;
            }
        }
        // max butterfly
        float m0 = ev0, m1 = ev1;
#pragma unroll
        for (int off = 32; off; off >>= 1) {
            m0 = fmaxf(m0, __shfl_xor(m0, off));
            if (H == 2) m1 = fmaxf(m1, __shfl_xor(m1, off));
        }
        // exp once; sum butterfly; alpha free (0 for lanes >= nb)
        float x0 = (lane < nb) ? __expf(ev0 - m0) : 0.f;
        float x1 = (H == 2 && lane < nb) ? __expf(ev1 - m1) : 0.f;
        float l0 = x0, l1 = x1;
#pragma unroll
        for (int off = 32; off; off >>= 1) {
            l0 += __shfl_xor(l0, off);
            if (H == 2) l1 += __shfl_xor(l1, off);
        }
        float a0 = x0 / (l0 + 1e-16f);
        float a1 = (H == 2) ? x1 / (l1 + 1e-16f) : a0;

        // ---- accumulate: wide rows-per-load, 8 loads (4KB) in flight ----
        float accv0 = 0.f, accv1 = 0.f, accv2 = 0.f, accv3 = 0.f;
        const uint2* xw2 = (const uint2*)xwb;

        if (F == 128) {
            // lane covers cols 4*li..4*li+3 of rows for half = lane>>5
            int li = lane & 31;
            int half = lane >> 5;
            bool head0 = (li < 16);           // col<64 <=> li<16
            for (int j = 0; j < nb; j += 16) {
                int rr[8];
                float alq[8];
#pragma unroll
                for (int q = 0; q < 8; q++) {
                    int e = j + 2 * q + half;     // <= 63 since nb<=64
                    rr[q] = __shfl(s_c, e);
                    float aa = __shfl(a0, e);
                    float bb = __shfl(a1, e);
                    alq[q] = (H == 2) ? (head0 ? aa : bb) : aa;
                }
                uint2 uu[8];
#pragma unroll
                for (int q = 0; q < 8; q++)
                    uu[q] = xw2[(rr[q] << 5) + li];
#pragma unroll
                for (int q = 0; q < 8; q++) {
                    accv0 = fmaf(alq[q], __uint_as_float(uu[q].x << 16), accv0);
                    accv1 = fmaf(alq[q], __uint_as_float(uu[q].x & 0xffff0000u), accv1);
                    accv2 = fmaf(alq[q], __uint_as_float(uu[q].y << 16), accv2);
                    accv3 = fmaf(alq[q], __uint_as_float(uu[q].y & 0xffff0000u), accv3);
                }
            }
            // cross-half reduce: lane l and l^32 hold same cols
            accv0 += __shfl_xor(accv0, 32);
            accv1 += __shfl_xor(accv1, 32);
            accv2 += __shfl_xor(accv2, 32);
            accv3 += __shfl_xor(accv3, 32);
            if (li == lane) {  // lane < 32
                float4 o;
                o.x = fmaxf(accv0 + bias[4 * li + 0], 0.f);
                o.y = fmaxf(accv1 + bias[4 * li + 1], 0.f);
                o.z = fmaxf(accv2 + bias[4 * li + 2], 0.f);
                o.w = fmaxf(accv3 + bias[4 * li + 3], 0.f);
                ((float4*)y)[(long long)wid * 32 + li] = o;
            }
        } else {
            // F=64, H=1: lane covers cols 4*li..4*li+3, group g = lane>>4
            int li = lane & 15;
            int g = lane >> 4;
            for (int j = 0; j < nb; j += 32) {
                int rr[8];
                float alq[8];
#pragma unroll
                for (int q = 0; q < 8; q++) {
                    int e = j + 4 * q + g;        // <= 63 since nb<=64
                    rr[q] = __shfl(s_c, e);
                    alq[q] = __shfl(a0, e);
                }
                uint2 uu[8];
#pragma unroll
                for (int q = 0; q < 8; q++)
                    uu[q] = xw2[(rr[q] << 4) + li];
#pragma unroll
                for (int q = 0; q < 8; q++) {
                    accv0 = fmaf(alq[q], __uint_as_float(uu[q].x << 16), accv0);
                    accv1 = fmaf(alq[q], __uint_as_float(uu[q].x & 0xffff0000u), accv1);
                    accv2 = fmaf(alq[q], __uint_as_float(uu[q].y << 16), accv2);
                    accv3 = fmaf(alq[q], __uint_as_float(uu[q].y & 0xffff0000u), accv3);
                }
            }
            // reduce across 4 groups (lanes sharing li)
            accv0 += __shfl_xor(accv0, 16); accv0 += __shfl_xor(accv0, 32);
            accv1 += __shfl_xor(accv1, 16); accv1 += __shfl_xor(accv1, 32);
            accv2 += __shfl_xor(accv2, 16); accv2 += __shfl_xor(accv2, 32);
            accv3 += __shfl_xor(accv3, 16); accv3 += __shfl_xor(accv3, 32);
            if (lane < 16) {
                float4 o;
                o.x = fmaxf(accv0 + bias[4 * li + 0], 0.f);
                o.y = fmaxf(accv1 + bias[4 * li + 1], 0.f);
                o.z = fmaxf(accv2 + bias[4 * li + 2], 0.f);
                o.w = fmaxf(accv3 + bias[4 * li + 3], 0.f);
                ((float4*)y)[(long long)wid * 16 + li] = o;
            }
        }
        return;
    }

    // ---------------- generic path (deg > 64), original code ----------------
    float acc0 = 0.f, acc1 = 0.f;
    {
        float m[H], l[H];
#pragma unroll
        for (int h = 0; h < H; h++) {
            m[h] = -1e30f;
            l[h] = 0.f;
        }
        for (int e = beg + lane; e < end; e += 64) {
            int s = col[e];
#pragma unroll
            for (int h = 0; h < H; h++) {
                float ev = al_s[s * H + h] + ald[h];
                ev = (ev >= 0.f) ? ev : 0.2f * ev;
                if (ev > m[h]) {
                    l[h] = l[h] * __expf(m[h] - ev) + 1.f;
                    m[h] = ev;
                } else {
                    l[h] += __expf(ev - m[h]);
                }
            }
        }
#pragma unroll
        for (int off = 32; off; off >>= 1) {
#pragma unroll
            for (int h = 0; h < H; h++) {
                float mo = __shfl_xor(m[h], off);
                float lo = __shfl_xor(l[h], off);
                float mn = fmaxf(m[h], mo);
                l[h] = l[h] * __expf(m[h] - mn) + lo * __expf(mo - mn);
                m[h] = mn;
            }
        }
        float inv[H];
#pragma unroll
        for (int h = 0; h < H; h++) inv[h] = 1.f / (l[h] + 1e-16f);

        for (int base = beg; base < end; base += 64) {
            int nb = min(64, end - base);
            int ec = min(base + lane, end - 1);
            int s = col[ec];
            float a0, a1;
            {
                float av[H];
#pragma unroll
                for (int h = 0; h < H; h++) {
                    float ev = al_s[s * H + h] + ald[h];
                    ev = (ev >= 0.f) ? ev : 0.2f * ev;
                    av[h] = __expf(ev - m[h]) * inv[h];
                }
                a0 = av[0];
                a1 = av[H - 1];
            }
            int j = 0;
            for (; j + 4 <= nb; j += 4) {
                int s0 = __shfl(s, j + 0), s1 = __shfl(s, j + 1);
                int s2 = __shfl(s, j + 2), s3 = __shfl(s, j + 3);
                float q00 = __shfl(a0, j + 0), q01 = __shfl(a1, j + 0);
                float q10 = __shfl(a0, j + 1), q11 = __shfl(a1, j + 1);
                float q20 = __shfl(a0, j + 2), q21 = __shfl(a1, j + 2);
                float q30 = __shfl(a0, j + 3), q31 = __shfl(a1, j + 3);
                float p0, p1, p2, p3;
                if (H == 2) {
                    p0 = (lane < 32) ? q00 : q01;
                    p1 = (lane < 32) ? q10 : q11;
                    p2 = (lane < 32) ? q20 : q21;
                    p3 = (lane < 32) ? q30 : q31;
                } else {
                    p0 = q00; p1 = q10; p2 = q20; p3 = q30;
                }
                if (F == 128) {
                    uint u0 = xwb[(s0 << 6) + lane];
                    uint u1 = xwb[(s1 << 6) + lane];
                    uint u2 = xwb[(s2 << 6) + lane];
                    uint u3 = xwb[(s3 << 6) + lane];
                    acc0 = fmaf(p0, __uint_as_float(u0 << 16), acc0);
                    acc1 = fmaf(p0, __uint_as_float(u0 & 0xffff0000u), acc1);
                    acc0 = fmaf(p1, __uint_as_float(u1 << 16), acc0);
                    acc1 = fmaf(p1, __uint_as_float(u1 & 0xffff0000u), acc1);
                    acc0 = fmaf(p2, __uint_as_float(u2 << 16), acc0);
                    acc1 = fmaf(p2, __uint_as_float(u2 & 0xffff0000u), acc1);
                    acc0 = fmaf(p3, __uint_as_float(u3 << 16), acc0);
                    acc1 = fmaf(p3, __uint_as_float(u3 & 0xffff0000u), acc1);
                } else {
                    int idx = lane >> 1;
                    bool hi = (lane & 1) != 0;
                    uint u0 = xwb[(s0 << 5) + idx];
                    uint u1 = xwb[(s1 << 5) + idx];
                    uint u2 = xwb[(s2 << 5) + idx];
                    uint u3 = xwb[(s3 << 5) + idx];
                    acc0 = fmaf(p0, __uint_as_float(hi ? (u0 & 0xffff0000u) : (u0 << 16)), acc0);
                    acc0 = fmaf(p1, __uint_as_float(hi ? (u1 & 0xffff0000u) : (u1 << 16)), acc0);
                    acc0 = fmaf(p2, __uint_as_float(hi ? (u2 & 0xffff0000u) : (u2 << 16)), acc0);
                    acc0 = fmaf(p3, __uint_as_float(hi ? (u3 & 0xffff0000u) : (u3 << 16)), acc0);
                }
            }
            for (; j < nb; ++j) {
                int sj = __shfl(s, j);
                float q0 = __shfl(a0, j);
                float q1 = __shfl(a1, j);
                float alpha;
                if (H == 2) {
                    alpha = (lane < 32) ? q0 : q1;
                } else {
                    alpha = q0;
                }
                if (F == 128) {
                    uint u = xwb[(sj << 6) + lane];
                    acc0 = fmaf(alpha, __uint_as_float(u << 16), acc0);
                    acc1 = fmaf(alpha, __uint_as_float(u & 0xffff0000u), acc1);
                } else {
                    uint u = xwb[(sj << 5) + (lane >> 1)];
                    acc0 = fmaf(alpha, __uint_as_float((lane & 1) ? (u & 0xffff0000u) : (u << 16)), acc0);
                }
            }
        }
    }

    if (F == 128) {
        float2 o;
        o.x = fmaxf(acc0 + bias[2 * lane], 0.f);
        o.y = fmaxf(acc1 + bias[2 * lane + 1], 0.f);
        ((float2*)y)[(long long)wid * 64 + lane] = o;
    } else {
        y[(long long)wid * 64 + lane] = fmaxf(acc0 + bias[lane], 0.f);
    }
}

// ---------------- BatchNorm ----------------
template <int F>
__global__ void k_bn_stats(const float* __restrict__ y, float* __restrict__ sums, int n) {
    constexpr int C4 = F / 4;
    constexpr int NPB = 256 / C4;
    int c4 = threadIdx.x % C4;
    int sub = threadIdx.x / C4;
    float4 s = {0, 0, 0, 0}, s2 = {0, 0, 0, 0};
    for (int node = blockIdx.x * NPB + sub; node < n; node += gridDim.x * NPB) {
        float4 v = ((const float4*)y)[node * C4 + c4];
        s.x += v.x; s.y += v.y; s.z += v.z; s.w += v.w;
        s2.x += v.x * v.x; s2.y += v.y * v.y; s2.z += v.z * v.z; s2.w += v.w * v.w;
    }
    __shared__ float4 ls[256], ls2[256];
    ls[threadIdx.x] = s;
    ls2[threadIdx.x] = s2;
    __syncthreads();
    if (sub == 0) {
#pragma unroll
        for (int k = 1; k < NPB; k++) {
            float4 t = ls[c4 + k * C4], t2 = ls2[c4 + k * C4];
            s.x += t.x; s.y += t.y; s.z += t.z; s.w += t.w;
            s2.x += t2.x; s2.y += t2.y; s2.z += t2.z; s2.w += t2.w;
        }
        atomicAdd(&sums[c4 * 4 + 0], s.x);
        atomicAdd(&sums[c4 * 4 + 1], s.y);
        atomicAdd(&sums[c4 * 4 + 2], s.z);
        atomicAdd(&sums[c4 * 4 + 3], s.w);
        atomicAdd(&sums[F + c4 * 4 + 0], s2.x);
        atomicAdd(&sums[F + c4 * 4 + 1], s2.y);
        atomicAdd(&sums[F + c4 * 4 + 2], s2.z);
        atomicAdd(&sums[F + c4 * 4 + 3], s2.w);
    }
}

template <int F>
__global__ void k_bn_prep(const float* __restrict__ sums, const float* __restrict__ g,
                          const float* __restrict__ be, float* __restrict__ sc,
                          float* __restrict__ sh, float invN) {
    int ch = threadIdx.x;
    if (ch < F) {
        float mean = sums[ch] * invN;
        float var = sums[F + ch] * invN - mean * mean;
        float s = g[ch] * rsqrtf(var + 1e-5f);
        sc[ch] = s;
        sh[ch] = be[ch] - mean * s;
    }
}

template <int F>
__global__ void k_bn_apply(const float* __restrict__ y, const float* __restrict__ sc,
                           const float* __restrict__ sh, float* __restrict__ outp, int n) {
    constexpr int C4 = F / 4;
    int t = blockIdx.x * blockDim.x + threadIdx.x;
    if (t >= n * C4) return;
    int node = t / C4, c4 = t % C4;
    float4 v = ((const float4*)y)[t];
    float4 o;
    o.x = v.x * sc[c4 * 4 + 0] + sh[c4 * 4 + 0];
    o.y = v.y * sc[c4 * 4 + 1] + sh[c4 * 4 + 1];
    o.z = v.z * sc[c4 * 4 + 2] + sh[c4 * 4 + 2];
    o.w = v.w * sc[c4 * 4 + 3] + sh[c4 * 4 + 3];
    ((float4*)(outp + (long long)node * 320))[c4] = o;
}

// ---------------------------------------------------------------------------
extern "C" void kernel_launch(void* const* d_in, const int* in_sizes, int n_in,
                              void* d_out, int out_size, void* d_ws, size_t ws_size,
                              hipStream_t stream) {
    const float* x   = (const float*)d_in[0];
    const int*   adj = (const int*)d_in[1];
    const float* W1  = (const float*)d_in[2];
    const float* as1 = (const float*)d_in[3];
    const float* ad1 = (const float*)d_in[4];
    const float* b1  = (const float*)d_in[5];
    const float* g1  = (const float*)d_in[6];
    const float* be1 = (const float*)d_in[7];
    const float* W2  = (const float*)d_in[8];
    const float* as2 = (const float*)d_in[9];
    const float* ad2 = (const float*)d_in[10];
    const float* b2  = (const float*)d_in[11];
    const float* g2  = (const float*)d_in[12];
    const float* be2 = (const float*)d_in[13];
    const float* W3  = (const float*)d_in[14];
    const float* as3 = (const float*)d_in[15];
    const float* ad3 = (const float*)d_in[16];
    const float* b3  = (const float*)d_in[17];
    const float* g3  = (const float*)d_in[18];
    const float* be3 = (const float*)d_in[19];
    float* out = (float*)d_out;

    const int N = in_sizes[0] / 128;
    const int E = in_sizes[1] / 2;

    // workspace
    float* ws    = (float*)d_ws;
    float* ybuf  = ws;                          // N*128
    float* al_s  = ybuf + (size_t)N * 128;      // N*2
    float* al_d  = al_s + (size_t)N * 2;        // N*2
    float* stats1 = al_d + (size_t)N * 2;       // 256
    float* stats2 = stats1 + 256;               // 256
    float* stats3 = stats2 + 256;               // 256
    float* scb   = stats3 + 256;                // 128
    float* shb   = scb + 128;                   // 128
    uint* xwb    = (uint*)(shb + 128);          // N*64 uints (bf16x2)
    int* ibase     = (int*)(xwb + (size_t)N * 64);
    int* bcntp     = ibase;                     // 512*16 (line-padded counts)
    int* bcurp     = bcntp + 8192;              // 512*16 (line-padded cursors)
    int* bbase     = bcurp + 8192;              // 513
    int* row_start = ibase + N;                 // N+1
    int* btot      = row_start + (N + 1);       // 64 (unused, layout keep)
    int* col       = btot + 64;                 // E+N

    // pre-converted W (bf16 hi/lo fragment blocks) + folded-BN constants
    uintptr_t wp = (uintptr_t)(col + (E + N));
    wp = (wp + 63) & ~(uintptr_t)63;
    ushort* w1hi = (ushort*)wp;                 // 128*128
    ushort* w1lo = w1hi + 16384;
    ushort* w2hi = w1lo + 16384;
    ushort* w2lo = w2hi + 16384;
    ushort* w3hi = w2lo + 16384;                // 64*128
    ushort* w3lo = w3hi + 8192;
    float* c1 = (float*)(w3lo + 8192);          // 128
    float* c2 = c1 + 128;                       // 128
    float* c3 = c2 + 128;                       // 64

    // packed bucket-sorted edges alias ybuf (dead before k_agg L1 writes it)
    int* pk = (int*)ybuf;                       // E+N ints

    const int* esrc = adj;
    const int* edst = adj + E;

    const int B = 256;
    auto cdiv = [](int a, int b) { return (a + b - 1) / b; };

    // ---- one upfront memset for all 3 BN stats buffers ----
    hipMemsetAsync(stats1, 0, 768 * sizeof(float), stream);

    // ---- W1 conversion (no BN): 1 wave per column ----
    k_wconv3<128><<<32, 256, 0, stream>>>(W1, nullptr, nullptr, 0, w1hi, w1lo, c1);

    // ---- CSR build: bucket counting sort ----
    const int NB = (N + 127) >> 7;              // buckets (needs N<=65536)
    hipMemsetAsync(bcntp, 0, 8192 * sizeof(int), stream);
    k_bcount<<<128, 256, 0, stream>>>(edst, E, bcntp);
    k_bscan<<<1, 512, 0, stream>>>(bcntp, bbase, bcurp, NB, N, E + N, row_start);
    int nchunk = (E + N + 8191) >> 13;
    k_bscatter<<<nchunk, 512, 0, stream>>>(esrc, edst, E, N, bcurp, pk);
    k_bfill<<<NB, 256, 0, stream>>>(pk, bbase, N, row_start, col);

    const float invN = 1.f / (float)N;
    ushort* xwb_us = (ushort*)xwb;

    // ---- layer 1: 128 -> 128 (H=2) ----
    k_gemm3<128, 2><<<cdiv(N, 32), B, 0, stream>>>(x, w1hi, w1lo, c1,
                                                   as1, ad1, xwb_us, al_s, al_d, N);
    k_agg<128, 2><<<cdiv(N, 4), B, 0, stream>>>(xwb, al_s, al_d, row_start, col, b1, ybuf, N);
    k_bn_stats<128><<<256, B, 0, stream>>>(ybuf, stats1, N);
    k_bn_prep<128><<<1, 128, 0, stream>>>(stats1, g1, be1, scb, shb, invN);
    k_wconv3<128><<<32, 256, 0, stream>>>(W2, scb, shb, 1, w2hi, w2lo, c2);
    k_bn_apply<128><<<cdiv(N * 32, B), B, 0, stream>>>(ybuf, scb, shb, out + 0, N);

    // ---- layer 2: 128 -> 128 (H=2), BN folded into W2 ----
    k_gemm3<128, 2><<<cdiv(N, 32), B, 0, stream>>>(ybuf, w2hi, w2lo, c2,
                                                   as2, ad2, xwb_us, al_s, al_d, N);
    k_agg<128, 2><<<cdiv(N, 4), B, 0, stream>>>(xwb, al_s, al_d, row_start, col, b2, ybuf, N);
    k_bn_stats<128><<<256, B, 0, stream>>>(ybuf, stats2, N);
    k_bn_prep<128><<<1, 128, 0, stream>>>(stats2, g2, be2, scb, shb, invN);
    k_wconv3<64><<<16, 256, 0, stream>>>(W3, scb, shb, 1, w3hi, w3lo, c3);
    k_bn_apply<128><<<cdiv(N * 32, B), B, 0, stream>>>(ybuf, scb, shb, out + 128, N);

    // ---- layer 3: 128 -> 64 (H=1), BN folded into W3 ----
    k_gemm3<64, 1><<<cdiv(N, 64), B, 0, stream>>>(ybuf, w3hi, w3lo, c3,
                                                  as3, ad3, xwb_us, al_s, al_d, N);
    k_agg<64, 1><<<cdiv(N, 4), B, 0, stream>>>(xwb, al_s, al_d, row_start, col, b3, ybuf, N);
    k_bn_stats<64><<<256, B, 0, stream>>>(ybuf, stats3, N);
    k_bn_prep<64><<<1, 64, 0, stream>>>(stats3, g3, be3, scb, shb, invN);
    k_bn_apply<64><<<cdiv(N * 16, B), B, 0, stream>>>(ybuf, scb, shb, out + 256, N);
}

// Round 14
// 431.061 us; speedup vs baseline: 1.1682x; 1.0138x over previous
//
#include <hip/hip_runtime.h>

typedef unsigned int uint;
typedef unsigned short ushort;

// ---------------------------------------------------------------------------
// GAT x3 + ReLU + BatchNorm, MI355X.
// R22 change (single theory): fuse BN-apply for layers 1,2 into the NEXT
// layer's k_gemm3 A-read. gemm3 already reads raw ybuf rows (BN folded in
// W); it now also emits out = ybuf*sc+sh (4 L1-resident float4 sc/sh loads
// + 2 coalesced float4 stores per lane per k-step, half==0 waves only so
// each row is written once). Deletes 2 k_bn_apply<128> dispatches and
// 51MB of redundant ybuf re-reads. k_agg (R18 local optimum) untouched;
// layer-3's bn_apply (out+256) kept. CSR (R10) / wconv3 (R16) verbatim.
// ---------------------------------------------------------------------------

static __device__ __forceinline__ ushort bf16_rne(float x) {
    uint u = __float_as_uint(x);
    return (ushort)((u + 0x7fffu + ((u >> 16) & 1u)) >> 16);
}
static __device__ __forceinline__ float bf16_f(ushort h) {
    return __uint_as_float(((uint)h) << 16);
}

// ---------------- bucket-sort CSR build ----------------
__global__ __launch_bounds__(256) void k_bcount(const int* __restrict__ dst, int e,
                                                int* __restrict__ bcntp) {
    __shared__ int h[512];
    int tid = threadIdx.x;
    h[tid] = 0;
    h[tid + 256] = 0;
    __syncthreads();
    int stride = gridDim.x * 256;
    for (int i = blockIdx.x * 256 + tid; i < e; i += stride)
        atomicAdd(&h[dst[i] >> 7], 1);
    __syncthreads();
    if (h[tid]) atomicAdd(&bcntp[tid * 16], h[tid]);
    if (h[tid + 256]) atomicAdd(&bcntp[(tid + 256) * 16], h[tid + 256]);
}

__global__ __launch_bounds__(512) void k_bscan(const int* __restrict__ bcntp,
                                               int* __restrict__ bbase,
                                               int* __restrict__ bcurp, int nb, int n,
                                               int total, int* __restrict__ row_start) {
    __shared__ int s[512];
    int tid = threadIdx.x;
    int v = 0;
    if (tid < nb) v = bcntp[tid * 16] + min(128, n - (tid << 7));  // + self-loops
    s[tid] = v;
    __syncthreads();
    for (int off = 1; off < 512; off <<= 1) {
        int t = (tid >= off) ? s[tid - off] : 0;
        __syncthreads();
        s[tid] += t;
        __syncthreads();
    }
    if (tid < nb) {
        int excl = s[tid] - v;
        bbase[tid] = excl;
        bcurp[tid * 16] = excl;
    }
    if (tid == 0) {
        bbase[nb] = total;
        row_start[n] = total;
    }
}

// multisplit: chunk of 8192 items -> LDS bucket-sort -> coalesced copy-out
__global__ __launch_bounds__(512) void k_bscatter(const int* __restrict__ src,
                                                  const int* __restrict__ dst, int e, int n,
                                                  int* __restrict__ bcurp,
                                                  int* __restrict__ pk) {
    __shared__ int hcnt[512], bstart[512], bcursor[512], gbase[512];
    __shared__ int stage[8192];
    int tid = threadIdx.x;
    int total = e + n;
    int nchunk = (total + 8191) >> 13;
    for (int c = blockIdx.x; c < nchunk; c += gridDim.x) {
        int base = c << 13;
        int cnt = min(8192, total - base);
        hcnt[tid] = 0;
        __syncthreads();
        for (int j = tid; j < cnt; j += 512) {
            int i = base + j;
            int d = (i < e) ? dst[i] : (i - e);
            atomicAdd(&hcnt[d >> 7], 1);
        }
        __syncthreads();
        int v = hcnt[tid];
        bstart[tid] = v;
        __syncthreads();
        for (int off = 1; off < 512; off <<= 1) {  // inclusive scan in-place
            int t = (tid >= off) ? bstart[tid - off] : 0;
            __syncthreads();
            bstart[tid] += t;
            __syncthreads();
        }
        int excl = bstart[tid] - v;
        __syncthreads();
        bstart[tid] = excl;
        bcursor[tid] = excl;
        if (v) gbase[tid] = atomicAdd(&bcurp[tid * 16], v);
        __syncthreads();
        for (int j = tid; j < cnt; j += 512) {
            int i = base + j;
            int d, sv;
            if (i < e) { d = dst[i]; sv = src[i]; }
            else       { d = i - e; sv = d; }
            uint b = (uint)(d >> 7);
            int r = atomicAdd(&bcursor[b], 1);
            stage[r] = (int)((b << 23) | ((uint)(d & 127) << 16) | (uint)sv);
        }
        __syncthreads();
        for (int j = tid; j < cnt; j += 512) {
            int p = stage[j];
            int b = (int)(((uint)p) >> 23);
            pk[gbase[b] + (j - bstart[b])] = p;   // coalesced runs per bucket
        }
        __syncthreads();
    }
}

// one block per bucket: local CSR entirely in LDS, coalesced global I/O
__global__ __launch_bounds__(256) void k_bfill(const int* __restrict__ pk,
                                               const int* __restrict__ bbase, int n,
                                               int* __restrict__ row_start,
                                               int* __restrict__ col) {
    int b = blockIdx.x;
    int s0 = bbase[b], s1 = bbase[b + 1];
    int seg = s1 - s0;
    int node0 = b << 7;
    int nn = min(128, n - node0);
    int tid = threadIdx.x;
    __shared__ int cnt[128], scn[128];
    __shared__ int colst[4608];
    if (tid < 128) cnt[tid] = 0;
    __syncthreads();
    for (int j = tid; j < seg; j += 256)
        atomicAdd(&cnt[(pk[s0 + j] >> 16) & 127], 1);
    __syncthreads();
    int myc = 0;
    if (tid < 128) { myc = cnt[tid]; scn[tid] = myc; }
    __syncthreads();
    for (int off = 1; off < 128; off <<= 1) {
        int t = (tid >= off && tid < 128) ? scn[tid - off] : 0;
        __syncthreads();
        if (tid < 128) scn[tid] += t;
        __syncthreads();
    }
    int excl = 0;
    if (tid < 128) excl = scn[tid] - myc;
    if (tid < nn) row_start[node0 + tid] = s0 + excl;
    __syncthreads();
    if (tid < 128) cnt[tid] = excl;   // becomes cursor
    __syncthreads();
    bool big = seg > 4608;            // fallback guard (never expected)
    for (int j = tid; j < seg; j += 256) {
        int p = pk[s0 + j];
        int r = atomicAdd(&cnt[(p >> 16) & 127], 1);
        if (big) col[s0 + r] = p & 0xffff;
        else colst[r] = p & 0xffff;
    }
    if (!big) {
        __syncthreads();
        for (int j = tid; j < seg; j += 256) col[s0 + j] = colst[j];
    }
}

// ---------------- W pre-conversion: coalesced fragment blocks ---------------
typedef __attribute__((ext_vector_type(8))) short short8;
typedef __attribute__((ext_vector_type(4))) float float4v;

// W fp32 [128][F] -> whi/wlo in lane-major fragment blocks:
//   block (tg,ks): 64 lanes x short8; lane=quad*16+l15 holds
//   column n=tg*16+l15, k=ks*32+quad*8..+8.
// cvec[n] = sum_k sh[k]*W[k][n] (useBN) else 0. One wave per column.
template <int F>
__global__ __launch_bounds__(256) void k_wconv3(const float* __restrict__ W,
                                                const float* __restrict__ sc,
                                                const float* __restrict__ sh, int useBN,
                                                ushort* __restrict__ whi,
                                                ushort* __restrict__ wlo,
                                                float* __restrict__ cvec) {
    int n = (blockIdx.x * blockDim.x + threadIdx.x) >> 6;  // wave id = column
    int lane = threadIdx.x & 63;
    if (n >= F) return;
    float c = 0.f;
    if (useBN) {
#pragma unroll
        for (int i = 0; i < 2; i++) {
            int k = lane + i * 64;
            c = fmaf(sh[k], W[k * F + n], c);
        }
#pragma unroll
        for (int off = 32; off; off >>= 1) c += __shfl_xor(c, off);
    }
    if (lane == 0) cvec[n] = c;
    // fragment emit: lanes 0..15 each handle one (ks,quad) octet of column n
    if (lane < 16) {
        int ks = lane >> 2, quad = lane & 3;
        int tg = n >> 4, l15 = n & 15;
        long long off8 = ((long long)((tg * 4 + ks) * 64 + quad * 16 + l15)) * 8;
        short8 h8, l8;
#pragma unroll
        for (int j = 0; j < 8; j++) {
            int k = ks * 32 + quad * 8 + j;
            float w = W[k * F + n];
            float wsv = useBN ? w * sc[k] : w;
            ushort h = bf16_rne(wsv);
            h8[j] = (short)h;
            l8[j] = (short)bf16_rne(wsv - bf16_f(h));
        }
        *(short8*)(whi + off8) = h8;
        *(short8*)(wlo + off8) = l8;
    }
}

// ---- GEMM: A[M,128] @ Wfrag -> bf16 xwb + logits. No LDS/barriers. --------
// OUTW: additionally emit outp[row*320 + k] = A[row][k]*bsc[k]+bsh[k]
// (fused BN-apply of the PREVIOUS layer; half==0 waves only, once per row).
static __device__ __forceinline__ void cvt8(const float4& f0, const float4& f1,
                                            short8& hi, short8& lo) {
#define CV8(i, val)                                        \
    {                                                      \
        ushort h_ = bf16_rne(val);                         \
        hi[i] = (short)h_;                                 \
        lo[i] = (short)bf16_rne((val)-bf16_f(h_));         \
    }
    CV8(0, f0.x) CV8(1, f0.y) CV8(2, f0.z) CV8(3, f0.w)
    CV8(4, f1.x) CV8(5, f1.y) CV8(6, f1.z) CV8(7, f1.w)
#undef CV8
}

template <int F, int H, bool OUTW>
__global__ __launch_bounds__(256) void k_gemm3(const float* __restrict__ A,
                                               const ushort* __restrict__ whi,
                                               const ushort* __restrict__ wlo,
                                               const float* __restrict__ cvec,
                                               const float* __restrict__ asrc,
                                               const float* __restrict__ adst,
                                               ushort* __restrict__ xwb,
                                               float* __restrict__ al_s,
                                               float* __restrict__ al_d,
                                               const float* __restrict__ bsc,
                                               const float* __restrict__ bsh,
                                               float* __restrict__ outp, int M) {
    constexpr bool SPLIT = (F == 128);          // split 8 col-tiles across wave pair
    constexpr int RPB = SPLIT ? 32 : 64;        // rows per block
    int tid = threadIdx.x;
    int wave = tid >> 6, lane = tid & 63;
    int quad = lane >> 4, l15 = lane & 15;
    int rg = SPLIT ? (wave >> 1) : wave;
    int half = SPLIT ? (wave & 1) : 0;
    int base = blockIdx.x * RPB + rg * 16;
    int coff = half * 64;                       // this wave's column offset
    int tgb = SPLIT ? half * 4 : 0;             // global tile base

    float4v acc[4];
#pragma unroll
    for (int t = 0; t < 4; t++) acc[t] = (float4v){0.f, 0.f, 0.f, 0.f};

    int arow = base + l15;
    bool aval = (arow < M);
    const float* Ap = A + (long long)arow * 128;

#pragma unroll
    for (int ks = 0; ks < 4; ks++) {
        float4 f0 = {0.f, 0.f, 0.f, 0.f}, f1 = {0.f, 0.f, 0.f, 0.f};
        if (aval) {
            f0 = *(const float4*)(Ap + ks * 32 + quad * 8);
            f1 = *(const float4*)(Ap + ks * 32 + quad * 8 + 4);
        }
        if (OUTW) {
            if (aval && half == 0) {
                int kk = ks * 32 + quad * 8;
                float4 s0 = *(const float4*)(bsc + kk);
                float4 s1 = *(const float4*)(bsc + kk + 4);
                float4 h0 = *(const float4*)(bsh + kk);
                float4 h1 = *(const float4*)(bsh + kk + 4);
                float4 o0, o1;
                o0.x = fmaf(f0.x, s0.x, h0.x);
                o0.y = fmaf(f0.y, s0.y, h0.y);
                o0.z = fmaf(f0.z, s0.z, h0.z);
                o0.w = fmaf(f0.w, s0.w, h0.w);
                o1.x = fmaf(f1.x, s1.x, h1.x);
                o1.y = fmaf(f1.y, s1.y, h1.y);
                o1.z = fmaf(f1.z, s1.z, h1.z);
                o1.w = fmaf(f1.w, s1.w, h1.w);
                float* op = outp + (long long)arow * 320 + kk;
                *(float4*)op = o0;
                *(float4*)(op + 4) = o1;
            }
        }
        short8 ah, al;
        cvt8(f0, f1, ah, al);
#pragma unroll
        for (int t = 0; t < 4; t++) {
            // coalesced lane-major fragment block
            long long boff = ((long long)(((tgb + t) * 4 + ks) * 64 + lane)) * 8;
            short8 bh = *(const short8*)(whi + boff);
            short8 bl = *(const short8*)(wlo + boff);
            acc[t] = __builtin_amdgcn_mfma_f32_16x16x32_bf16(ah, bh, acc[t], 0, 0, 0);
            acc[t] = __builtin_amdgcn_mfma_f32_16x16x32_bf16(ah, bl, acc[t], 0, 0, 0);
            acc[t] = __builtin_amdgcn_mfma_f32_16x16x32_bf16(al, bh, acc[t], 0, 0, 0);
        }
    }

    // ---- epilogue: C[row=quad*4+r][col(tile)=l15], tile t -> col coff+t*16+l15
    float cv[4], asl[4], adl[4];
#pragma unroll
    for (int t = 0; t < 4; t++) {
        int n = coff + t * 16 + l15;
        cv[t] = cvec[n];
        asl[t] = asrc[n];
        adl[t] = adst[n];
    }
#pragma unroll
    for (int r = 0; r < 4; r++) {
        int grow = base + quad * 4 + r;
        float v0 = acc[0][r] + cv[0];
        float v1 = acc[1][r] + cv[1];
        float v2 = acc[2][r] + cv[2];
        float v3 = acc[3][r] + cv[3];
        if (grow < M) {
            ushort* xp = xwb + (long long)grow * F + coff + l15;
            xp[0] = bf16_rne(v0);
            xp[16] = bf16_rne(v1);
            xp[32] = bf16_rne(v2);
            xp[48] = bf16_rne(v3);
        }
        float ps = 0.f, pd = 0.f;
        ps = fmaf(v0, asl[0], ps); pd = fmaf(v0, adl[0], pd);
        ps = fmaf(v1, asl[1], ps); pd = fmaf(v1, adl[1], pd);
        ps = fmaf(v2, asl[2], ps); pd = fmaf(v2, adl[2], pd);
        ps = fmaf(v3, asl[3], ps); pd = fmaf(v3, adl[3], pd);
#pragma unroll
        for (int off = 1; off < 16; off <<= 1) {
            ps += __shfl_xor(ps, off);
            pd += __shfl_xor(pd, off);
        }
        if (l15 == 0 && grow < M) {
            al_s[grow * H + half] = ps;
            al_d[grow * H + half] = pd;
        }
    }
}

// ---------------- per-dst-wave softmax aggregation (R18 verbatim) -----------
template <int F, int H>
__global__ __launch_bounds__(256) void k_agg(const uint* __restrict__ xwb,
                      const float* __restrict__ al_s,
                      const float* __restrict__ al_d, const int* __restrict__ row_start,
                      const int* __restrict__ col, const float* __restrict__ bias,
                      float* __restrict__ y, int n) {
    int wid = (blockIdx.x * blockDim.x + threadIdx.x) >> 6;  // one wave per dst
    int lane = threadIdx.x & 63;
    if (wid >= n) return;
    int beg = row_start[wid], end = row_start[wid + 1];

    float ald[H];
#pragma unroll
    for (int h = 0; h < H; h++) ald[h] = al_d[wid * H + h];

    if (end - beg <= 64) {
        // ---------------- fast path: one lane = one edge ----------------
        int nb = end - beg;
        int s_c = 0;
        float ev0 = -1e30f, ev1 = -1e30f;
        if (lane < nb) {
            s_c = col[beg + lane];
            if (H == 2) {
                float2 av = ((const float2*)al_s)[s_c];
                float e0 = av.x + ald[0];
                float e1 = av.y + ald[1];
                ev0 = (e0 >= 0.f) ? e0 : 0.2f * e0;
                ev1 = (e1 >= 0.f) ? e1 : 0.2f * e1;
            } else {
                float e0 = al_s[s_c] + ald[0];
                ev0 = (e0 >= 0.f) ? e0 : 0.2f * e0;
            }
        }
        // max butterfly
        float m0 = ev0, m1 = ev1;
#pragma unroll
        for (int off = 32; off; off >>= 1) {
            m0 = fmaxf(m0, __shfl_xor(m0, off));
            if (H == 2) m1 = fmaxf(m1, __shfl_xor(m1, off));
        }
        // exp once; sum butterfly; alpha free (0 for lanes >= nb)
        float x0 = (lane < nb) ? __expf(ev0 - m0) : 0.f;
        float x1 = (H == 2 && lane < nb) ? __expf(ev1 - m1) : 0.f;
        float l0 = x0, l1 = x1;
#pragma unroll
        for (int off = 32; off; off >>= 1) {
            l0 += __shfl_xor(l0, off);
            if (H == 2) l1 += __shfl_xor(l1, off);
        }
        float a0 = x0 / (l0 + 1e-16f);
        float a1 = (H == 2) ? x1 / (l1 + 1e-16f) : a0;

        // ---- accumulate: wide rows-per-load, 8 loads (4KB) in flight ----
        float accv0 = 0.f, accv1 = 0.f, accv2 = 0.f, accv3 = 0.f;
        const uint2* xw2 = (const uint2*)xwb;

        if (F == 128) {
            // lane covers cols 4*li..4*li+3 of rows for half = lane>>5
            int li = lane & 31;
            int half = lane >> 5;
            bool head0 = (li < 16);           // col<64 <=> li<16
            for (int j = 0; j < nb; j += 16) {
                int rr[8];
                float alq[8];
#pragma unroll
                for (int q = 0; q < 8; q++) {
                    int e = j + 2 * q + half;     // <= 63 since nb<=64
                    rr[q] = __shfl(s_c, e);
                    float aa = __shfl(a0, e);
                    float bb = __shfl(a1, e);
                    alq[q] = (H == 2) ? (head0 ? aa : bb) : aa;
                }
                uint2 uu[8];
#pragma unroll
                for (int q = 0; q < 8; q++)
                    uu[q] = xw2[(rr[q] << 5) + li];
#pragma unroll
                for (int q = 0; q < 8; q++) {
                    accv0 = fmaf(alq[q], __uint_as_float(uu[q].x << 16), accv0);
                    accv1 = fmaf(alq[q], __uint_as_float(uu[q].x & 0xffff0000u), accv1);
                    accv2 = fmaf(alq[q], __uint_as_float(uu[q].y << 16), accv2);
                    accv3 = fmaf(alq[q], __uint_as_float(uu[q].y & 0xffff0000u), accv3);
                }
            }
            // cross-half reduce: lane l and l^32 hold same cols
            accv0 += __shfl_xor(accv0, 32);
            accv1 += __shfl_xor(accv1, 32);
            accv2 += __shfl_xor(accv2, 32);
            accv3 += __shfl_xor(accv3, 32);
            if (li == lane) {  // lane < 32
                float4 o;
                o.x = fmaxf(accv0 + bias[4 * li + 0], 0.f);
                o.y = fmaxf(accv1 + bias[4 * li + 1], 0.f);
                o.z = fmaxf(accv2 + bias[4 * li + 2], 0.f);
                o.w = fmaxf(accv3 + bias[4 * li + 3], 0.f);
                ((float4*)y)[(long long)wid * 32 + li] = o;
            }
        } else {
            // F=64, H=1: lane covers cols 4*li..4*li+3, group g = lane>>4
            int li = lane & 15;
            int g = lane >> 4;
            for (int j = 0; j < nb; j += 32) {
                int rr[8];
                float alq[8];
#pragma unroll
                for (int q = 0; q < 8; q++) {
                    int e = j + 4 * q + g;        // <= 63 since nb<=64
                    rr[q] = __shfl(s_c, e);
                    alq[q] = __shfl(a0, e);
                }
                uint2 uu[8];
#pragma unroll
                for (int q = 0; q < 8; q++)
                    uu[q] = xw2[(rr[q] << 4) + li];
#pragma unroll
                for (int q = 0; q < 8; q++) {
                    accv0 = fmaf(alq[q], __uint_as_float(uu[q].x << 16), accv0);
                    accv1 = fmaf(alq[q], __uint_as_float(uu[q].x & 0xffff0000u), accv1);
                    accv2 = fmaf(alq[q], __uint_as_float(uu[q].y << 16), accv2);
                    accv3 = fmaf(alq[q], __uint_as_float(uu[q].y & 0xffff0000u), accv3);
                }
            }
            // reduce across 4 groups (lanes sharing li)
            accv0 += __shfl_xor(accv0, 16); accv0 += __shfl_xor(accv0, 32);
            accv1 += __shfl_xor(accv1, 16); accv1 += __shfl_xor(accv1, 32);
            accv2 += __shfl_xor(accv2, 16); accv2 += __shfl_xor(accv2, 32);
            accv3 += __shfl_xor(accv3, 16); accv3 += __shfl_xor(accv3, 32);
            if (lane < 16) {
                float4 o;
                o.x = fmaxf(accv0 + bias[4 * li + 0], 0.f);
                o.y = fmaxf(accv1 + bias[4 * li + 1], 0.f);
                o.z = fmaxf(accv2 + bias[4 * li + 2], 0.f);
                o.w = fmaxf(accv3 + bias[4 * li + 3], 0.f);
                ((float4*)y)[(long long)wid * 16 + li] = o;
            }
        }
        return;
    }

    // ---------------- generic path (deg > 64), original code ----------------
    float acc0 = 0.f, acc1 = 0.f;
    {
        float m[H], l[H];
#pragma unroll
        for (int h = 0; h < H; h++) {
            m[h] = -1e30f;
            l[h] = 0.f;
        }
        for (int e = beg + lane; e < end; e += 64) {
            int s = col[e];
#pragma unroll
            for (int h = 0; h < H; h++) {
                float ev = al_s[s * H + h] + ald[h];
                ev = (ev >= 0.f) ? ev : 0.2f * ev;
                if (ev > m[h]) {
                    l[h] = l[h] * __expf(m[h] - ev) + 1.f;
                    m[h] = ev;
                } else {
                    l[h] += __expf(ev - m[h]);
                }
            }
        }
#pragma unroll
        for (int off = 32; off; off >>= 1) {
#pragma unroll
            for (int h = 0; h < H; h++) {
                float mo = __shfl_xor(m[h], off);
                float lo = __shfl_xor(l[h], off);
                float mn = fmaxf(m[h], mo);
                l[h] = l[h] * __expf(m[h] - mn) + lo * __expf(mo - mn);
                m[h] = mn;
            }
        }
        float inv[H];
#pragma unroll
        for (int h = 0; h < H; h++) inv[h] = 1.f / (l[h] + 1e-16f);

        for (int base = beg; base < end; base += 64) {
            int nb = min(64, end - base);
            int ec = min(base + lane, end - 1);
            int s = col[ec];
            float a0, a1;
            {
                float av[H];
#pragma unroll
                for (int h = 0; h < H; h++) {
                    float ev = al_s[s * H + h] + ald[h];
                    ev = (ev >= 0.f) ? ev : 0.2f * ev;
                    av[h] = __expf(ev - m[h]) * inv[h];
                }
                a0 = av[0];
                a1 = av[H - 1];
            }
            int j = 0;
            for (; j + 4 <= nb; j += 4) {
                int s0 = __shfl(s, j + 0), s1 = __shfl(s, j + 1);
                int s2 = __shfl(s, j + 2), s3 = __shfl(s, j + 3);
                float q00 = __shfl(a0, j + 0), q01 = __shfl(a1, j + 0);
                float q10 = __shfl(a0, j + 1), q11 = __shfl(a1, j + 1);
                float q20 = __shfl(a0, j + 2), q21 = __shfl(a1, j + 2);
                float q30 = __shfl(a0, j + 3), q31 = __shfl(a1, j + 3);
                float p0, p1, p2, p3;
                if (H == 2) {
                    p0 = (lane < 32) ? q00 : q01;
                    p1 = (lane < 32) ? q10 : q11;
                    p2 = (lane < 32) ? q20 : q21;
                    p3 = (lane < 32) ? q30 : q31;
                } else {
                    p0 = q00; p1 = q10; p2 = q20; p3 = q30;
                }
                if (F == 128) {
                    uint u0 = xwb[(s0 << 6) + lane];
                    uint u1 = xwb[(s1 << 6) + lane];
                    uint u2 = xwb[(s2 << 6) + lane];
                    uint u3 = xwb[(s3 << 6) + lane];
                    acc0 = fmaf(p0, __uint_as_float(u0 << 16), acc0);
                    acc1 = fmaf(p0, __uint_as_float(u0 & 0xffff0000u), acc1);
                    acc0 = fmaf(p1, __uint_as_float(u1 << 16), acc0);
                    acc1 = fmaf(p1, __uint_as_float(u1 & 0xffff0000u), acc1);
                    acc0 = fmaf(p2, __uint_as_float(u2 << 16), acc0);
                    acc1 = fmaf(p2, __uint_as_float(u2 & 0xffff0000u), acc1);
                    acc0 = fmaf(p3, __uint_as_float(u3 << 16), acc0);
                    acc1 = fmaf(p3, __uint_as_float(u3 & 0xffff0000u), acc1);
                } else {
                    int idx = lane >> 1;
                    bool hi = (lane & 1) != 0;
                    uint u0 = xwb[(s0 << 5) + idx];
                    uint u1 = xwb[(s1 << 5) + idx];
                    uint u2 = xwb[(s2 << 5) + idx];
                    uint u3 = xwb[(s3 << 5) + idx];
                    acc0 = fmaf(p0, __uint_as_float(hi ? (u0 & 0xffff0000u) : (u0 << 16)), acc0);
                    acc0 = fmaf(p1, __uint_as_float(hi ? (u1 & 0xffff0000u) : (u1 << 16)), acc0);
                    acc0 = fmaf(p2, __uint_as_float(hi ? (u2 & 0xffff0000u) : (u2 << 16)), acc0);
                    acc0 = fmaf(p3, __uint_as_float(hi ? (u3 & 0xffff0000u) : (u3 << 16)), acc0);
                }
            }
            for (; j < nb; ++j) {
                int sj = __shfl(s, j);
                float q0 = __shfl(a0, j);
                float q1 = __shfl(a1, j);
                float alpha;
                if (H == 2) {
                    alpha = (lane < 32) ? q0 : q1;
                } else {
                    alpha = q0;
                }
                if (F == 128) {
                    uint u = xwb[(sj << 6) + lane];
                    acc0 = fmaf(alpha, __uint_as_float(u << 16), acc0);
                    acc1 = fmaf(alpha, __uint_as_float(u & 0xffff0000u), acc1);
                } else {
                    uint u = xwb[(sj << 5) + (lane >> 1)];
                    acc0 = fmaf(alpha, __uint_as_float((lane & 1) ? (u & 0xffff0000u) : (u << 16)), acc0);
                }
            }
        }
    }

    if (F == 128) {
        float2 o;
        o.x = fmaxf(acc0 + bias[2 * lane], 0.f);
        o.y = fmaxf(acc1 + bias[2 * lane + 1], 0.f);
        ((float2*)y)[(long long)wid * 64 + lane] = o;
    } else {
        y[(long long)wid * 64 + lane] = fmaxf(acc0 + bias[lane], 0.f);
    }
}

// ---------------- BatchNorm ----------------
template <int F>
__global__ void k_bn_stats(const float* __restrict__ y, float* __restrict__ sums, int n) {
    constexpr int C4 = F / 4;
    constexpr int NPB = 256 / C4;
    int c4 = threadIdx.x % C4;
    int sub = threadIdx.x / C4;
    float4 s = {0, 0, 0, 0}, s2 = {0, 0, 0, 0};
    for (int node = blockIdx.x * NPB + sub; node < n; node += gridDim.x * NPB) {
        float4 v = ((const float4*)y)[node * C4 + c4];
        s.x += v.x; s.y += v.y; s.z += v.z; s.w += v.w;
        s2.x += v.x * v.x; s2.y += v.y * v.y; s2.z += v.z * v.z; s2.w += v.w * v.w;
    }
    __shared__ float4 ls[256], ls2[256];
    ls[threadIdx.x] = s;
    ls2[threadIdx.x] = s2;
    __syncthreads();
    if (sub == 0) {
#pragma unroll
        for (int k = 1; k < NPB; k++) {
            float4 t = ls[c4 + k * C4], t2 = ls2[c4 + k * C4];
            s.x += t.x; s.y += t.y; s.z += t.z; s.w += t.w;
            s2.x += t2.x; s2.y += t2.y; s2.z += t2.z; s2.w += t2.w;
        }
        atomicAdd(&sums[c4 * 4 + 0], s.x);
        atomicAdd(&sums[c4 * 4 + 1], s.y);
        atomicAdd(&sums[c4 * 4 + 2], s.z);
        atomicAdd(&sums[c4 * 4 + 3], s.w);
        atomicAdd(&sums[F + c4 * 4 + 0], s2.x);
        atomicAdd(&sums[F + c4 * 4 + 1], s2.y);
        atomicAdd(&sums[F + c4 * 4 + 2], s2.z);
        atomicAdd(&sums[F + c4 * 4 + 3], s2.w);
    }
}

template <int F>
__global__ void k_bn_prep(const float* __restrict__ sums, const float* __restrict__ g,
                          const float* __restrict__ be, float* __restrict__ sc,
                          float* __restrict__ sh, float invN) {
    int ch = threadIdx.x;
    if (ch < F) {
        float mean = sums[ch] * invN;
        float var = sums[F + ch] * invN - mean * mean;
        float s = g[ch] * rsqrtf(var + 1e-5f);
        sc[ch] = s;
        sh[ch] = be[ch] - mean * s;
    }
}

template <int F>
__global__ void k_bn_apply(const float* __restrict__ y, const float* __restrict__ sc,
                           const float* __restrict__ sh, float* __restrict__ outp, int n) {
    constexpr int C4 = F / 4;
    int t = blockIdx.x * blockDim.x + threadIdx.x;
    if (t >= n * C4) return;
    int node = t / C4, c4 = t % C4;
    float4 v = ((const float4*)y)[t];
    float4 o;
    o.x = v.x * sc[c4 * 4 + 0] + sh[c4 * 4 + 0];
    o.y = v.y * sc[c4 * 4 + 1] + sh[c4 * 4 + 1];
    o.z = v.z * sc[c4 * 4 + 2] + sh[c4 * 4 + 2];
    o.w = v.w * sc[c4 * 4 + 3] + sh[c4 * 4 + 3];
    ((float4*)(outp + (long long)node * 320))[c4] = o;
}

// ---------------------------------------------------------------------------
extern "C" void kernel_launch(void* const* d_in, const int* in_sizes, int n_in,
                              void* d_out, int out_size, void* d_ws, size_t ws_size,
                              hipStream_t stream) {
    const float* x   = (const float*)d_in[0];
    const int*   adj = (const int*)d_in[1];
    const float* W1  = (const float*)d_in[2];
    const float* as1 = (const float*)d_in[3];
    const float* ad1 = (const float*)d_in[4];
    const float* b1  = (const float*)d_in[5];
    const float* g1  = (const float*)d_in[6];
    const float* be1 = (const float*)d_in[7];
    const float* W2  = (const float*)d_in[8];
    const float* as2 = (const float*)d_in[9];
    const float* ad2 = (const float*)d_in[10];
    const float* b2  = (const float*)d_in[11];
    const float* g2  = (const float*)d_in[12];
    const float* be2 = (const float*)d_in[13];
    const float* W3  = (const float*)d_in[14];
    const float* as3 = (const float*)d_in[15];
    const float* ad3 = (const float*)d_in[16];
    const float* b3  = (const float*)d_in[17];
    const float* g3  = (const float*)d_in[18];
    const float* be3 = (const float*)d_in[19];
    float* out = (float*)d_out;

    const int N = in_sizes[0] / 128;
    const int E = in_sizes[1] / 2;

    // workspace
    float* ws    = (float*)d_ws;
    float* ybuf  = ws;                          // N*128
    float* al_s  = ybuf + (size_t)N * 128;      // N*2
    float* al_d  = al_s + (size_t)N * 2;        // N*2
    float* stats1 = al_d + (size_t)N * 2;       // 256
    float* stats2 = stats1 + 256;               // 256
    float* stats3 = stats2 + 256;               // 256
    float* scb   = stats3 + 256;                // 128
    float* shb   = scb + 128;                   // 128
    uint* xwb    = (uint*)(shb + 128);          // N*64 uints (bf16x2)
    int* ibase     = (int*)(xwb + (size_t)N * 64);
    int* bcntp     = ibase;                     // 512*16 (line-padded counts)
    int* bcurp     = bcntp + 8192;              // 512*16 (line-padded cursors)
    int* bbase     = bcurp + 8192;              // 513
    int* row_start = ibase + N;                 // N+1
    int* btot      = row_start + (N + 1);       // 64 (unused, layout keep)
    int* col       = btot + 64;                 // E+N

    // pre-converted W (bf16 hi/lo fragment blocks) + folded-BN constants
    uintptr_t wp = (uintptr_t)(col + (E + N));
    wp = (wp + 63) & ~(uintptr_t)63;
    ushort* w1hi = (ushort*)wp;                 // 128*128
    ushort* w1lo = w1hi + 16384;
    ushort* w2hi = w1lo + 16384;
    ushort* w2lo = w2hi + 16384;
    ushort* w3hi = w2lo + 16384;                // 64*128
    ushort* w3lo = w3hi + 8192;
    float* c1 = (float*)(w3lo + 8192);          // 128
    float* c2 = c1 + 128;                       // 128
    float* c3 = c2 + 128;                       // 64

    // packed bucket-sorted edges alias ybuf (dead before k_agg L1 writes it)
    int* pk = (int*)ybuf;                       // E+N ints

    const int* esrc = adj;
    const int* edst = adj + E;

    const int B = 256;
    auto cdiv = [](int a, int b) { return (a + b - 1) / b; };

    // ---- one upfront memset for all 3 BN stats buffers ----
    hipMemsetAsync(stats1, 0, 768 * sizeof(float), stream);

    // ---- W1 conversion (no BN): 1 wave per column ----
    k_wconv3<128><<<32, 256, 0, stream>>>(W1, nullptr, nullptr, 0, w1hi, w1lo, c1);

    // ---- CSR build: bucket counting sort ----
    const int NB = (N + 127) >> 7;              // buckets (needs N<=65536)
    hipMemsetAsync(bcntp, 0, 8192 * sizeof(int), stream);
    k_bcount<<<128, 256, 0, stream>>>(edst, E, bcntp);
    k_bscan<<<1, 512, 0, stream>>>(bcntp, bbase, bcurp, NB, N, E + N, row_start);
    int nchunk = (E + N + 8191) >> 13;
    k_bscatter<<<nchunk, 512, 0, stream>>>(esrc, edst, E, N, bcurp, pk);
    k_bfill<<<NB, 256, 0, stream>>>(pk, bbase, N, row_start, col);

    const float invN = 1.f / (float)N;
    ushort* xwb_us = (ushort*)xwb;

    // ---- layer 1: 128 -> 128 (H=2) ----
    k_gemm3<128, 2, false><<<cdiv(N, 32), B, 0, stream>>>(x, w1hi, w1lo, c1,
                                                          as1, ad1, xwb_us, al_s, al_d,
                                                          nullptr, nullptr, nullptr, N);
    k_agg<128, 2><<<cdiv(N, 4), B, 0, stream>>>(xwb, al_s, al_d, row_start, col, b1, ybuf, N);
    k_bn_stats<128><<<256, B, 0, stream>>>(ybuf, stats1, N);
    k_bn_prep<128><<<1, 128, 0, stream>>>(stats1, g1, be1, scb, shb, invN);
    k_wconv3<128><<<32, 256, 0, stream>>>(W2, scb, shb, 1, w2hi, w2lo, c2);

    // ---- layer 2: 128 -> 128 (H=2), BN1 folded into W2; gemm also emits
    //      out+0 = BN1(ybuf) (fused bn_apply of layer 1) ----
    k_gemm3<128, 2, true><<<cdiv(N, 32), B, 0, stream>>>(ybuf, w2hi, w2lo, c2,
                                                         as2, ad2, xwb_us, al_s, al_d,
                                                         scb, shb, out + 0, N);
    k_agg<128, 2><<<cdiv(N, 4), B, 0, stream>>>(xwb, al_s, al_d, row_start, col, b2, ybuf, N);
    k_bn_stats<128><<<256, B, 0, stream>>>(ybuf, stats2, N);
    k_bn_prep<128><<<1, 128, 0, stream>>>(stats2, g2, be2, scb, shb, invN);
    k_wconv3<64><<<16, 256, 0, stream>>>(W3, scb, shb, 1, w3hi, w3lo, c3);

    // ---- layer 3: 128 -> 64 (H=1), BN2 folded into W3; gemm also emits
    //      out+128 = BN2(ybuf) (fused bn_apply of layer 2) ----
    k_gemm3<64, 1, true><<<cdiv(N, 64), B, 0, stream>>>(ybuf, w3hi, w3lo, c3,
                                                        as3, ad3, xwb_us, al_s, al_d,
                                                        scb, shb, out + 128, N);
    k_agg<64, 1><<<cdiv(N, 4), B, 0, stream>>>(xwb, al_s, al_d, row_start, col, b3, ybuf, N);
    k_bn_stats<64><<<256, B, 0, stream>>>(ybuf, stats3, N);
    k_bn_prep<64><<<1, 64, 0, stream>>>(stats3, g3, be3, scb, shb, invN);
    k_bn_apply<64><<<cdiv(N * 16, B), B, 0, stream>>>(ybuf, scb, shb, out + 256, N);
}

// Round 15
// 427.386 us; speedup vs baseline: 1.1783x; 1.0086x over previous
//
#include <hip/hip_runtime.h>

typedef unsigned int uint;
typedef unsigned short ushort;

// ---------------------------------------------------------------------------
// GAT x3 + ReLU + BatchNorm, MI355X.
// R23 change (single theory): delete all 3 one-block k_bn_prep launches by
// computing sc/sh redundantly in the consumers:
//  - k_wconv3p: computes sc/sh from stats at kernel start (LDS; block 0
//    also writes scb/shb globally for gemm3's fused BN-apply path).
//  - k_bn_apply64p: computes its 4 channels' sc/sh directly from stats3.
// 25 -> 22 dispatches; k_agg / gemm3 / CSR / bn_stats byte-identical to
// R22 (431us verified best).
// ---------------------------------------------------------------------------

static __device__ __forceinline__ ushort bf16_rne(float x) {
    uint u = __float_as_uint(x);
    return (ushort)((u + 0x7fffu + ((u >> 16) & 1u)) >> 16);
}
static __device__ __forceinline__ float bf16_f(ushort h) {
    return __uint_as_float(((uint)h) << 16);
}

// ---------------- bucket-sort CSR build ----------------
__global__ __launch_bounds__(256) void k_bcount(const int* __restrict__ dst, int e,
                                                int* __restrict__ bcntp) {
    __shared__ int h[512];
    int tid = threadIdx.x;
    h[tid] = 0;
    h[tid + 256] = 0;
    __syncthreads();
    int stride = gridDim.x * 256;
    for (int i = blockIdx.x * 256 + tid; i < e; i += stride)
        atomicAdd(&h[dst[i] >> 7], 1);
    __syncthreads();
    if (h[tid]) atomicAdd(&bcntp[tid * 16], h[tid]);
    if (h[tid + 256]) atomicAdd(&bcntp[(tid + 256) * 16], h[tid + 256]);
}

__global__ __launch_bounds__(512) void k_bscan(const int* __restrict__ bcntp,
                                               int* __restrict__ bbase,
                                               int* __restrict__ bcurp, int nb, int n,
                                               int total, int* __restrict__ row_start) {
    __shared__ int s[512];
    int tid = threadIdx.x;
    int v = 0;
    if (tid < nb) v = bcntp[tid * 16] + min(128, n - (tid << 7));  // + self-loops
    s[tid] = v;
    __syncthreads();
    for (int off = 1; off < 512; off <<= 1) {
        int t = (tid >= off) ? s[tid - off] : 0;
        __syncthreads();
        s[tid] += t;
        __syncthreads();
    }
    if (tid < nb) {
        int excl = s[tid] - v;
        bbase[tid] = excl;
        bcurp[tid * 16] = excl;
    }
    if (tid == 0) {
        bbase[nb] = total;
        row_start[n] = total;
    }
}

// multisplit: chunk of 8192 items -> LDS bucket-sort -> coalesced copy-out
__global__ __launch_bounds__(512) void k_bscatter(const int* __restrict__ src,
                                                  const int* __restrict__ dst, int e, int n,
                                                  int* __restrict__ bcurp,
                                                  int* __restrict__ pk) {
    __shared__ int hcnt[512], bstart[512], bcursor[512], gbase[512];
    __shared__ int stage[8192];
    int tid = threadIdx.x;
    int total = e + n;
    int nchunk = (total + 8191) >> 13;
    for (int c = blockIdx.x; c < nchunk; c += gridDim.x) {
        int base = c << 13;
        int cnt = min(8192, total - base);
        hcnt[tid] = 0;
        __syncthreads();
        for (int j = tid; j < cnt; j += 512) {
            int i = base + j;
            int d = (i < e) ? dst[i] : (i - e);
            atomicAdd(&hcnt[d >> 7], 1);
        }
        __syncthreads();
        int v = hcnt[tid];
        bstart[tid] = v;
        __syncthreads();
        for (int off = 1; off < 512; off <<= 1) {  // inclusive scan in-place
            int t = (tid >= off) ? bstart[tid - off] : 0;
            __syncthreads();
            bstart[tid] += t;
            __syncthreads();
        }
        int excl = bstart[tid] - v;
        __syncthreads();
        bstart[tid] = excl;
        bcursor[tid] = excl;
        if (v) gbase[tid] = atomicAdd(&bcurp[tid * 16], v);
        __syncthreads();
        for (int j = tid; j < cnt; j += 512) {
            int i = base + j;
            int d, sv;
            if (i < e) { d = dst[i]; sv = src[i]; }
            else       { d = i - e; sv = d; }
            uint b = (uint)(d >> 7);
            int r = atomicAdd(&bcursor[b], 1);
            stage[r] = (int)((b << 23) | ((uint)(d & 127) << 16) | (uint)sv);
        }
        __syncthreads();
        for (int j = tid; j < cnt; j += 512) {
            int p = stage[j];
            int b = (int)(((uint)p) >> 23);
            pk[gbase[b] + (j - bstart[b])] = p;   // coalesced runs per bucket
        }
        __syncthreads();
    }
}

// one block per bucket: local CSR entirely in LDS, coalesced global I/O
__global__ __launch_bounds__(256) void k_bfill(const int* __restrict__ pk,
                                               const int* __restrict__ bbase, int n,
                                               int* __restrict__ row_start,
                                               int* __restrict__ col) {
    int b = blockIdx.x;
    int s0 = bbase[b], s1 = bbase[b + 1];
    int seg = s1 - s0;
    int node0 = b << 7;
    int nn = min(128, n - node0);
    int tid = threadIdx.x;
    __shared__ int cnt[128], scn[128];
    __shared__ int colst[4608];
    if (tid < 128) cnt[tid] = 0;
    __syncthreads();
    for (int j = tid; j < seg; j += 256)
        atomicAdd(&cnt[(pk[s0 + j] >> 16) & 127], 1);
    __syncthreads();
    int myc = 0;
    if (tid < 128) { myc = cnt[tid]; scn[tid] = myc; }
    __syncthreads();
    for (int off = 1; off < 128; off <<= 1) {
        int t = (tid >= off && tid < 128) ? scn[tid - off] : 0;
        __syncthreads();
        if (tid < 128) scn[tid] += t;
        __syncthreads();
    }
    int excl = 0;
    if (tid < 128) excl = scn[tid] - myc;
    if (tid < nn) row_start[node0 + tid] = s0 + excl;
    __syncthreads();
    if (tid < 128) cnt[tid] = excl;   // becomes cursor
    __syncthreads();
    bool big = seg > 4608;            // fallback guard (never expected)
    for (int j = tid; j < seg; j += 256) {
        int p = pk[s0 + j];
        int r = atomicAdd(&cnt[(p >> 16) & 127], 1);
        if (big) col[s0 + r] = p & 0xffff;
        else colst[r] = p & 0xffff;
    }
    if (!big) {
        __syncthreads();
        for (int j = tid; j < seg; j += 256) col[s0 + j] = colst[j];
    }
}

// ---------------- W pre-conversion: coalesced fragment blocks ---------------
typedef __attribute__((ext_vector_type(8))) short short8;
typedef __attribute__((ext_vector_type(4))) float float4v;

// W fp32 [128][F] -> whi/wlo in lane-major fragment blocks (R16 layout).
// useBN: sc/sh computed IN-KERNEL from stats (sum/sumsq) + g/be; block 0
// also writes scb/shb globally (consumed by gemm3's fused BN-apply).
template <int F>
__global__ __launch_bounds__(256) void k_wconv3p(const float* __restrict__ W,
                                                 const float* __restrict__ stats,
                                                 const float* __restrict__ g,
                                                 const float* __restrict__ be,
                                                 float invN, int useBN,
                                                 float* __restrict__ scb,
                                                 float* __restrict__ shb,
                                                 ushort* __restrict__ whi,
                                                 ushort* __restrict__ wlo,
                                                 float* __restrict__ cvec) {
    __shared__ float lsc[128], lsh[128];
    int tid = threadIdx.x;
    if (useBN) {
        if (tid < 128) {
            float mean = stats[tid] * invN;
            float var = stats[128 + tid] * invN - mean * mean;
            float s = g[tid] * rsqrtf(var + 1e-5f);
            lsc[tid] = s;
            lsh[tid] = be[tid] - mean * s;
            if (blockIdx.x == 0) {
                scb[tid] = s;
                shb[tid] = lsh[tid];
            }
        }
        __syncthreads();
    }
    int n = (blockIdx.x * blockDim.x + tid) >> 6;  // wave id = column
    int lane = tid & 63;
    if (n >= F) return;
    float c = 0.f;
    if (useBN) {
#pragma unroll
        for (int i = 0; i < 2; i++) {
            int k = lane + i * 64;
            c = fmaf(lsh[k], W[k * F + n], c);
        }
#pragma unroll
        for (int off = 32; off; off >>= 1) c += __shfl_xor(c, off);
    }
    if (lane == 0) cvec[n] = c;
    // fragment emit: lanes 0..15 each handle one (ks,quad) octet of column n
    if (lane < 16) {
        int ks = lane >> 2, quad = lane & 3;
        int tg = n >> 4, l15 = n & 15;
        long long off8 = ((long long)((tg * 4 + ks) * 64 + quad * 16 + l15)) * 8;
        short8 h8, l8;
#pragma unroll
        for (int j = 0; j < 8; j++) {
            int k = ks * 32 + quad * 8 + j;
            float w = W[k * F + n];
            float wsv = useBN ? w * lsc[k] : w;
            ushort h = bf16_rne(wsv);
            h8[j] = (short)h;
            l8[j] = (short)bf16_rne(wsv - bf16_f(h));
        }
        *(short8*)(whi + off8) = h8;
        *(short8*)(wlo + off8) = l8;
    }
}

// ---- GEMM: A[M,128] @ Wfrag -> bf16 xwb + logits. No LDS/barriers. --------
// OUTW: additionally emit outp[row*320 + k] = A[row][k]*bsc[k]+bsh[k]
// (fused BN-apply of the PREVIOUS layer; half==0 waves only, once per row).
static __device__ __forceinline__ void cvt8(const float4& f0, const float4& f1,
                                            short8& hi, short8& lo) {
#define CV8(i, val)                                        \
    {                                                      \
        ushort h_ = bf16_rne(val);                         \
        hi[i] = (short)h_;                                 \
        lo[i] = (short)bf16_rne((val)-bf16_f(h_));         \
    }
    CV8(0, f0.x) CV8(1, f0.y) CV8(2, f0.z) CV8(3, f0.w)
    CV8(4, f1.x) CV8(5, f1.y) CV8(6, f1.z) CV8(7, f1.w)
#undef CV8
}

template <int F, int H, bool OUTW>
__global__ __launch_bounds__(256) void k_gemm3(const float* __restrict__ A,
                                               const ushort* __restrict__ whi,
                                               const ushort* __restrict__ wlo,
                                               const float* __restrict__ cvec,
                                               const float* __restrict__ asrc,
                                               const float* __restrict__ adst,
                                               ushort* __restrict__ xwb,
                                               float* __restrict__ al_s,
                                               float* __restrict__ al_d,
                                               const float* __restrict__ bsc,
                                               const float* __restrict__ bsh,
                                               float* __restrict__ outp, int M) {
    constexpr bool SPLIT = (F == 128);          // split 8 col-tiles across wave pair
    constexpr int RPB = SPLIT ? 32 : 64;        // rows per block
    int tid = threadIdx.x;
    int wave = tid >> 6, lane = tid & 63;
    int quad = lane >> 4, l15 = lane & 15;
    int rg = SPLIT ? (wave >> 1) : wave;
    int half = SPLIT ? (wave & 1) : 0;
    int base = blockIdx.x * RPB + rg * 16;
    int coff = half * 64;                       // this wave's column offset
    int tgb = SPLIT ? half * 4 : 0;             // global tile base

    float4v acc[4];
#pragma unroll
    for (int t = 0; t < 4; t++) acc[t] = (float4v){0.f, 0.f, 0.f, 0.f};

    int arow = base + l15;
    bool aval = (arow < M);
    const float* Ap = A + (long long)arow * 128;

#pragma unroll
    for (int ks = 0; ks < 4; ks++) {
        float4 f0 = {0.f, 0.f, 0.f, 0.f}, f1 = {0.f, 0.f, 0.f, 0.f};
        if (aval) {
            f0 = *(const float4*)(Ap + ks * 32 + quad * 8);
            f1 = *(const float4*)(Ap + ks * 32 + quad * 8 + 4);
        }
        if (OUTW) {
            if (aval && half == 0) {
                int kk = ks * 32 + quad * 8;
                float4 s0 = *(const float4*)(bsc + kk);
                float4 s1 = *(const float4*)(bsc + kk + 4);
                float4 h0 = *(const float4*)(bsh + kk);
                float4 h1 = *(const float4*)(bsh + kk + 4);
                float4 o0, o1;
                o0.x = fmaf(f0.x, s0.x, h0.x);
                o0.y = fmaf(f0.y, s0.y, h0.y);
                o0.z = fmaf(f0.z, s0.z, h0.z);
                o0.w = fmaf(f0.w, s0.w, h0.w);
                o1.x = fmaf(f1.x, s1.x, h1.x);
                o1.y = fmaf(f1.y, s1.y, h1.y);
                o1.z = fmaf(f1.z, s1.z, h1.z);
                o1.w = fmaf(f1.w, s1.w, h1.w);
                float* op = outp + (long long)arow * 320 + kk;
                *(float4*)op = o0;
                *(float4*)(op + 4) = o1;
            }
        }
        short8 ah, al;
        cvt8(f0, f1, ah, al);
#pragma unroll
        for (int t = 0; t < 4; t++) {
            // coalesced lane-major fragment block
            long long boff = ((long long)(((tgb + t) * 4 + ks) * 64 + lane)) * 8;
            short8 bh = *(const short8*)(whi + boff);
            short8 bl = *(const short8*)(wlo + boff);
            acc[t] = __builtin_amdgcn_mfma_f32_16x16x32_bf16(ah, bh, acc[t], 0, 0, 0);
            acc[t] = __builtin_amdgcn_mfma_f32_16x16x32_bf16(ah, bl, acc[t], 0, 0, 0);
            acc[t] = __builtin_amdgcn_mfma_f32_16x16x32_bf16(al, bh, acc[t], 0, 0, 0);
        }
    }

    // ---- epilogue: C[row=quad*4+r][col(tile)=l15], tile t -> col coff+t*16+l15
    float cv[4], asl[4], adl[4];
#pragma unroll
    for (int t = 0; t < 4; t++) {
        int n = coff + t * 16 + l15;
        cv[t] = cvec[n];
        asl[t] = asrc[n];
        adl[t] = adst[n];
    }
#pragma unroll
    for (int r = 0; r < 4; r++) {
        int grow = base + quad * 4 + r;
        float v0 = acc[0][r] + cv[0];
        float v1 = acc[1][r] + cv[1];
        float v2 = acc[2][r] + cv[2];
        float v3 = acc[3][r] + cv[3];
        if (grow < M) {
            ushort* xp = xwb + (long long)grow * F + coff + l15;
            xp[0] = bf16_rne(v0);
            xp[16] = bf16_rne(v1);
            xp[32] = bf16_rne(v2);
            xp[48] = bf16_rne(v3);
        }
        float ps = 0.f, pd = 0.f;
        ps = fmaf(v0, asl[0], ps); pd = fmaf(v0, adl[0], pd);
        ps = fmaf(v1, asl[1], ps); pd = fmaf(v1, adl[1], pd);
        ps = fmaf(v2, asl[2], ps); pd = fmaf(v2, adl[2], pd);
        ps = fmaf(v3, asl[3], ps); pd = fmaf(v3, adl[3], pd);
#pragma unroll
        for (int off = 1; off < 16; off <<= 1) {
            ps += __shfl_xor(ps, off);
            pd += __shfl_xor(pd, off);
        }
        if (l15 == 0 && grow < M) {
            al_s[grow * H + half] = ps;
            al_d[grow * H + half] = pd;
        }
    }
}

// ---------------- per-dst-wave softmax aggregation (R18 verbatim) -----------
template <int F, int H>
__global__ __launch_bounds__(256) void k_agg(const uint* __restrict__ xwb,
                      const float* __restrict__ al_s,
                      const float* __restrict__ al_d, const int* __restrict__ row_start,
                      const int* __restrict__ col, const float* __restrict__ bias,
                      float* __restrict__ y, int n) {
    int wid = (blockIdx.x * blockDim.x + threadIdx.x) >> 6;  // one wave per dst
    int lane = threadIdx.x & 63;
    if (wid >= n) return;
    int beg = row_start[wid], end = row_start[wid + 1];

    float ald[H];
#pragma unroll
    for (int h = 0; h < H; h++) ald[h] = al_d[wid * H + h];

    if (end - beg <= 64) {
        // ---------------- fast path: one lane = one edge ----------------
        int nb = end - beg;
        int s_c = 0;
        float ev0 = -1e30f, ev1 = -1e30f;
        if (lane < nb) {
            s_c = col[beg + lane];
            if (H == 2) {
                float2 av = ((const float2*)al_s)[s_c];
                float e0 = av.x + ald[0];
                float e1 = av.y + ald[1];
                ev0 = (e0 >= 0.f) ? e0 : 0.2f * e0;
                ev1 = (e1 >= 0.f) ? e1 : 0.2f * e1;
            } else {
                float e0 = al_s[s_c] + ald[0];
                ev0 = (e0 >= 0.f) ? e0 : 0.2f * e0;
            }
        }
        // max butterfly
        float m0 = ev0, m1 = ev1;
#pragma unroll
        for (int off = 32; off; off >>= 1) {
            m0 = fmaxf(m0, __shfl_xor(m0, off));
            if (H == 2) m1 = fmaxf(m1, __shfl_xor(m1, off));
        }
        // exp once; sum butterfly; alpha free (0 for lanes >= nb)
        float x0 = (lane < nb) ? __expf(ev0 - m0) : 0.f;
        float x1 = (H == 2 && lane < nb) ? __expf(ev1 - m1) : 0.f;
        float l0 = x0, l1 = x1;
#pragma unroll
        for (int off = 32; off; off >>= 1) {
            l0 += __shfl_xor(l0, off);
            if (H == 2) l1 += __shfl_xor(l1, off);
        }
        float a0 = x0 / (l0 + 1e-16f);
        float a1 = (H == 2) ? x1 / (l1 + 1e-16f) : a0;

        // ---- accumulate: wide rows-per-load, 8 loads (4KB) in flight ----
        float accv0 = 0.f, accv1 = 0.f, accv2 = 0.f, accv3 = 0.f;
        const uint2* xw2 = (const uint2*)xwb;

        if (F == 128) {
            // lane covers cols 4*li..4*li+3 of rows for half = lane>>5
            int li = lane & 31;
            int half = lane >> 5;
            bool head0 = (li < 16);           // col<64 <=> li<16
            for (int j = 0; j < nb; j += 16) {
                int rr[8];
                float alq[8];
#pragma unroll
                for (int q = 0; q < 8; q++) {
                    int e = j + 2 * q + half;     // <= 63 since nb<=64
                    rr[q] = __shfl(s_c, e);
                    float aa = __shfl(a0, e);
                    float bb = __shfl(a1, e);
                    alq[q] = (H == 2) ? (head0 ? aa : bb) : aa;
                }
                uint2 uu[8];
#pragma unroll
                for (int q = 0; q < 8; q++)
                    uu[q] = xw2[(rr[q] << 5) + li];
#pragma unroll
                for (int q = 0; q < 8; q++) {
                    accv0 = fmaf(alq[q], __uint_as_float(uu[q].x << 16), accv0);
                    accv1 = fmaf(alq[q], __uint_as_float(uu[q].x & 0xffff0000u), accv1);
                    accv2 = fmaf(alq[q], __uint_as_float(uu[q].y << 16), accv2);
                    accv3 = fmaf(alq[q], __uint_as_float(uu[q].y & 0xffff0000u), accv3);
                }
            }
            // cross-half reduce: lane l and l^32 hold same cols
            accv0 += __shfl_xor(accv0, 32);
            accv1 += __shfl_xor(accv1, 32);
            accv2 += __shfl_xor(accv2, 32);
            accv3 += __shfl_xor(accv3, 32);
            if (li == lane) {  // lane < 32
                float4 o;
                o.x = fmaxf(accv0 + bias[4 * li + 0], 0.f);
                o.y = fmaxf(accv1 + bias[4 * li + 1], 0.f);
                o.z = fmaxf(accv2 + bias[4 * li + 2], 0.f);
                o.w = fmaxf(accv3 + bias[4 * li + 3], 0.f);
                ((float4*)y)[(long long)wid * 32 + li] = o;
            }
        } else {
            // F=64, H=1: lane covers cols 4*li..4*li+3, group g = lane>>4
            int li = lane & 15;
            int g = lane >> 4;
            for (int j = 0; j < nb; j += 32) {
                int rr[8];
                float alq[8];
#pragma unroll
                for (int q = 0; q < 8; q++) {
                    int e = j + 4 * q + g;        // <= 63 since nb<=64
                    rr[q] = __shfl(s_c, e);
                    alq[q] = __shfl(a0, e);
                }
                uint2 uu[8];
#pragma unroll
                for (int q = 0; q < 8; q++)
                    uu[q] = xw2[(rr[q] << 4) + li];
#pragma unroll
                for (int q = 0; q < 8; q++) {
                    accv0 = fmaf(alq[q], __uint_as_float(uu[q].x << 16), accv0);
                    accv1 = fmaf(alq[q], __uint_as_float(uu[q].x & 0xffff0000u), accv1);
                    accv2 = fmaf(alq[q], __uint_as_float(uu[q].y << 16), accv2);
                    accv3 = fmaf(alq[q], __uint_as_float(uu[q].y & 0xffff0000u), accv3);
                }
            }
            // reduce across 4 groups (lanes sharing li)
            accv0 += __shfl_xor(accv0, 16); accv0 += __shfl_xor(accv0, 32);
            accv1 += __shfl_xor(accv1, 16); accv1 += __shfl_xor(accv1, 32);
            accv2 += __shfl_xor(accv2, 16); accv2 += __shfl_xor(accv2, 32);
            accv3 += __shfl_xor(accv3, 16); accv3 += __shfl_xor(accv3, 32);
            if (lane < 16) {
                float4 o;
                o.x = fmaxf(accv0 + bias[4 * li + 0], 0.f);
                o.y = fmaxf(accv1 + bias[4 * li + 1], 0.f);
                o.z = fmaxf(accv2 + bias[4 * li + 2], 0.f);
                o.w = fmaxf(accv3 + bias[4 * li + 3], 0.f);
                ((float4*)y)[(long long)wid * 16 + li] = o;
            }
        }
        return;
    }

    // ---------------- generic path (deg > 64), original code ----------------
    float acc0 = 0.f, acc1 = 0.f;
    {
        float m[H], l[H];
#pragma unroll
        for (int h = 0; h < H; h++) {
            m[h] = -1e30f;
            l[h] = 0.f;
        }
        for (int e = beg + lane; e < end; e += 64) {
            int s = col[e];
#pragma unroll
            for (int h = 0; h < H; h++) {
                float ev = al_s[s * H + h] + ald[h];
                ev = (ev >= 0.f) ? ev : 0.2f * ev;
                if (ev > m[h]) {
                    l[h] = l[h] * __expf(m[h] - ev) + 1.f;
                    m[h] = ev;
                } else {
                    l[h] += __expf(ev - m[h]);
                }
            }
        }
#pragma unroll
        for (int off = 32; off; off >>= 1) {
#pragma unroll
            for (int h = 0; h < H; h++) {
                float mo = __shfl_xor(m[h], off);
                float lo = __shfl_xor(l[h], off);
                float mn = fmaxf(m[h], mo);
                l[h] = l[h] * __expf(m[h] - mn) + lo * __expf(mo - mn);
                m[h] = mn;
            }
        }
        float inv[H];
#pragma unroll
        for (int h = 0; h < H; h++) inv[h] = 1.f / (l[h] + 1e-16f);

        for (int base = beg; base < end; base += 64) {
            int nb = min(64, end - base);
            int ec = min(base + lane, end - 1);
            int s = col[ec];
            float a0, a1;
            {
                float av[H];
#pragma unroll
                for (int h = 0; h < H; h++) {
                    float ev = al_s[s * H + h] + ald[h];
                    ev = (ev >= 0.f) ? ev : 0.2f * ev;
                    av[h] = __expf(ev - m[h]) * inv[h];
                }
                a0 = av[0];
                a1 = av[H - 1];
            }
            int j = 0;
            for (; j + 4 <= nb; j += 4) {
                int s0 = __shfl(s, j + 0), s1 = __shfl(s, j + 1);
                int s2 = __shfl(s, j + 2), s3 = __shfl(s, j + 3);
                float q00 = __shfl(a0, j + 0), q01 = __shfl(a1, j + 0);
                float q10 = __shfl(a0, j + 1), q11 = __shfl(a1, j + 1);
                float q20 = __shfl(a0, j + 2), q21 = __shfl(a1, j + 2);
                float q30 = __shfl(a0, j + 3), q31 = __shfl(a1, j + 3);
                float p0, p1, p2, p3;
                if (H == 2) {
                    p0 = (lane < 32) ? q00 : q01;
                    p1 = (lane < 32) ? q10 : q11;
                    p2 = (lane < 32) ? q20 : q21;
                    p3 = (lane < 32) ? q30 : q31;
                } else {
                    p0 = q00; p1 = q10; p2 = q20; p3 = q30;
                }
                if (F == 128) {
                    uint u0 = xwb[(s0 << 6) + lane];
                    uint u1 = xwb[(s1 << 6) + lane];
                    uint u2 = xwb[(s2 << 6) + lane];
                    uint u3 = xwb[(s3 << 6) + lane];
                    acc0 = fmaf(p0, __uint_as_float(u0 << 16), acc0);
                    acc1 = fmaf(p0, __uint_as_float(u0 & 0xffff0000u), acc1);
                    acc0 = fmaf(p1, __uint_as_float(u1 << 16), acc0);
                    acc1 = fmaf(p1, __uint_as_float(u1 & 0xffff0000u), acc1);
                    acc0 = fmaf(p2, __uint_as_float(u2 << 16), acc0);
                    acc1 = fmaf(p2, __uint_as_float(u2 & 0xffff0000u), acc1);
                    acc0 = fmaf(p3, __uint_as_float(u3 << 16), acc0);
                    acc1 = fmaf(p3, __uint_as_float(u3 & 0xffff0000u), acc1);
                } else {
                    int idx = lane >> 1;
                    bool hi = (lane & 1) != 0;
                    uint u0 = xwb[(s0 << 5) + idx];
                    uint u1 = xwb[(s1 << 5) + idx];
                    uint u2 = xwb[(s2 << 5) + idx];
                    uint u3 = xwb[(s3 << 5) + idx];
                    acc0 = fmaf(p0, __uint_as_float(hi ? (u0 & 0xffff0000u) : (u0 << 16)), acc0);
                    acc0 = fmaf(p1, __uint_as_float(hi ? (u1 & 0xffff0000u) : (u1 << 16)), acc0);
                    acc0 = fmaf(p2, __uint_as_float(hi ? (u2 & 0xffff0000u) : (u2 << 16)), acc0);
                    acc0 = fmaf(p3, __uint_as_float(hi ? (u3 & 0xffff0000u) : (u3 << 16)), acc0);
                }
            }
            for (; j < nb; ++j) {
                int sj = __shfl(s, j);
                float q0 = __shfl(a0, j);
                float q1 = __shfl(a1, j);
                float alpha;
                if (H == 2) {
                    alpha = (lane < 32) ? q0 : q1;
                } else {
                    alpha = q0;
                }
                if (F == 128) {
                    uint u = xwb[(sj << 6) + lane];
                    acc0 = fmaf(alpha, __uint_as_float(u << 16), acc0);
                    acc1 = fmaf(alpha, __uint_as_float(u & 0xffff0000u), acc1);
                } else {
                    uint u = xwb[(sj << 5) + (lane >> 1)];
                    acc0 = fmaf(alpha, __uint_as_float((lane & 1) ? (u & 0xffff0000u) : (u << 16)), acc0);
                }
            }
        }
    }

    if (F == 128) {
        float2 o;
        o.x = fmaxf(acc0 + bias[2 * lane], 0.f);
        o.y = fmaxf(acc1 + bias[2 * lane + 1], 0.f);
        ((float2*)y)[(long long)wid * 64 + lane] = o;
    } else {
        y[(long long)wid * 64 + lane] = fmaxf(acc0 + bias[lane], 0.f);
    }
}

// ---------------- BatchNorm ----------------
template <int F>
__global__ void k_bn_stats(const float* __restrict__ y, float* __restrict__ sums, int n) {
    constexpr int C4 = F / 4;
    constexpr int NPB = 256 / C4;
    int c4 = threadIdx.x % C4;
    int sub = threadIdx.x / C4;
    float4 s = {0, 0, 0, 0}, s2 = {0, 0, 0, 0};
    for (int node = blockIdx.x * NPB + sub; node < n; node += gridDim.x * NPB) {
        float4 v = ((const float4*)y)[node * C4 + c4];
        s.x += v.x; s.y += v.y; s.z += v.z; s.w += v.w;
        s2.x += v.x * v.x; s2.y += v.y * v.y; s2.z += v.z * v.z; s2.w += v.w * v.w;
    }
    __shared__ float4 ls[256], ls2[256];
    ls[threadIdx.x] = s;
    ls2[threadIdx.x] = s2;
    __syncthreads();
    if (sub == 0) {
#pragma unroll
        for (int k = 1; k < NPB; k++) {
            float4 t = ls[c4 + k * C4], t2 = ls2[c4 + k * C4];
            s.x += t.x; s.y += t.y; s.z += t.z; s.w += t.w;
            s2.x += t2.x; s2.y += t2.y; s2.z += t2.z; s2.w += t2.w;
        }
        atomicAdd(&sums[c4 * 4 + 0], s.x);
        atomicAdd(&sums[c4 * 4 + 1], s.y);
        atomicAdd(&sums[c4 * 4 + 2], s.z);
        atomicAdd(&sums[c4 * 4 + 3], s.w);
        atomicAdd(&sums[F + c4 * 4 + 0], s2.x);
        atomicAdd(&sums[F + c4 * 4 + 1], s2.y);
        atomicAdd(&sums[F + c4 * 4 + 2], s2.z);
        atomicAdd(&sums[F + c4 * 4 + 3], s2.w);
    }
}

// BN apply for F=64 with in-kernel prep (reads stats directly)
__global__ void k_bn_apply64p(const float* __restrict__ y, const float* __restrict__ stats,
                              const float* __restrict__ g, const float* __restrict__ be,
                              float invN, float* __restrict__ outp, int n) {
    constexpr int C4 = 16;
    int t = blockIdx.x * blockDim.x + threadIdx.x;
    if (t >= n * C4) return;
    int node = t / C4, c4 = t % C4;
    float4 v = ((const float4*)y)[t];
    float4 o;
#pragma unroll
    for (int i = 0; i < 4; i++) {
        int ch = c4 * 4 + i;
        float mean = stats[ch] * invN;
        float var = stats[64 + ch] * invN - mean * mean;
        float s = g[ch] * rsqrtf(var + 1e-5f);
        float sh = be[ch] - mean * s;
        float vi = (i == 0) ? v.x : (i == 1) ? v.y : (i == 2) ? v.z : v.w;
        float oi = vi * s + sh;
        if (i == 0) o.x = oi;
        else if (i == 1) o.y = oi;
        else if (i == 2) o.z = oi;
        else o.w = oi;
    }
    ((float4*)(outp + (long long)node * 320))[c4] = o;
}

// ---------------------------------------------------------------------------
extern "C" void kernel_launch(void* const* d_in, const int* in_sizes, int n_in,
                              void* d_out, int out_size, void* d_ws, size_t ws_size,
                              hipStream_t stream) {
    const float* x   = (const float*)d_in[0];
    const int*   adj = (const int*)d_in[1];
    const float* W1  = (const float*)d_in[2];
    const float* as1 = (const float*)d_in[3];
    const float* ad1 = (const float*)d_in[4];
    const float* b1  = (const float*)d_in[5];
    const float* g1  = (const float*)d_in[6];
    const float* be1 = (const float*)d_in[7];
    const float* W2  = (const float*)d_in[8];
    const float* as2 = (const float*)d_in[9];
    const float* ad2 = (const float*)d_in[10];
    const float* b2  = (const float*)d_in[11];
    const float* g2  = (const float*)d_in[12];
    const float* be2 = (const float*)d_in[13];
    const float* W3  = (const float*)d_in[14];
    const float* as3 = (const float*)d_in[15];
    const float* ad3 = (const float*)d_in[16];
    const float* b3  = (const float*)d_in[17];
    const float* g3  = (const float*)d_in[18];
    const float* be3 = (const float*)d_in[19];
    float* out = (float*)d_out;

    const int N = in_sizes[0] / 128;
    const int E = in_sizes[1] / 2;

    // workspace
    float* ws    = (float*)d_ws;
    float* ybuf  = ws;                          // N*128
    float* al_s  = ybuf + (size_t)N * 128;      // N*2
    float* al_d  = al_s + (size_t)N * 2;        // N*2
    float* stats1 = al_d + (size_t)N * 2;       // 256
    float* stats2 = stats1 + 256;               // 256
    float* stats3 = stats2 + 256;               // 256
    float* scb   = stats3 + 256;                // 128
    float* shb   = scb + 128;                   // 128
    uint* xwb    = (uint*)(shb + 128);          // N*64 uints (bf16x2)
    int* ibase     = (int*)(xwb + (size_t)N * 64);
    int* bcntp     = ibase;                     // 512*16 (line-padded counts)
    int* bcurp     = bcntp + 8192;              // 512*16 (line-padded cursors)
    int* bbase     = bcurp + 8192;              // 513
    int* row_start = ibase + N;                 // N+1
    int* btot      = row_start + (N + 1);       // 64 (unused, layout keep)
    int* col       = btot + 64;                 // E+N

    // pre-converted W (bf16 hi/lo fragment blocks) + folded-BN constants
    uintptr_t wp = (uintptr_t)(col + (E + N));
    wp = (wp + 63) & ~(uintptr_t)63;
    ushort* w1hi = (ushort*)wp;                 // 128*128
    ushort* w1lo = w1hi + 16384;
    ushort* w2hi = w1lo + 16384;
    ushort* w2lo = w2hi + 16384;
    ushort* w3hi = w2lo + 16384;                // 64*128
    ushort* w3lo = w3hi + 8192;
    float* c1 = (float*)(w3lo + 8192);          // 128
    float* c2 = c1 + 128;                       // 128
    float* c3 = c2 + 128;                       // 64

    // packed bucket-sorted edges alias ybuf (dead before k_agg L1 writes it)
    int* pk = (int*)ybuf;                       // E+N ints

    const int* esrc = adj;
    const int* edst = adj + E;

    const int B = 256;
    auto cdiv = [](int a, int b) { return (a + b - 1) / b; };

    // ---- one upfront memset for all 3 BN stats buffers ----
    hipMemsetAsync(stats1, 0, 768 * sizeof(float), stream);

    // ---- W1 conversion (no BN): 1 wave per column ----
    k_wconv3p<128><<<32, 256, 0, stream>>>(W1, nullptr, nullptr, nullptr, 0.f, 0,
                                           nullptr, nullptr, w1hi, w1lo, c1);

    // ---- CSR build: bucket counting sort ----
    const int NB = (N + 127) >> 7;              // buckets (needs N<=65536)
    hipMemsetAsync(bcntp, 0, 8192 * sizeof(int), stream);
    k_bcount<<<128, 256, 0, stream>>>(edst, E, bcntp);
    k_bscan<<<1, 512, 0, stream>>>(bcntp, bbase, bcurp, NB, N, E + N, row_start);
    int nchunk = (E + N + 8191) >> 13;
    k_bscatter<<<nchunk, 512, 0, stream>>>(esrc, edst, E, N, bcurp, pk);
    k_bfill<<<NB, 256, 0, stream>>>(pk, bbase, N, row_start, col);

    const float invN = 1.f / (float)N;
    ushort* xwb_us = (ushort*)xwb;

    // ---- layer 1: 128 -> 128 (H=2) ----
    k_gemm3<128, 2, false><<<cdiv(N, 32), B, 0, stream>>>(x, w1hi, w1lo, c1,
                                                          as1, ad1, xwb_us, al_s, al_d,
                                                          nullptr, nullptr, nullptr, N);
    k_agg<128, 2><<<cdiv(N, 4), B, 0, stream>>>(xwb, al_s, al_d, row_start, col, b1, ybuf, N);
    k_bn_stats<128><<<256, B, 0, stream>>>(ybuf, stats1, N);
    k_wconv3p<128><<<32, 256, 0, stream>>>(W2, stats1, g1, be1, invN, 1,
                                           scb, shb, w2hi, w2lo, c2);

    // ---- layer 2: 128 -> 128 (H=2), BN1 folded into W2; gemm also emits
    //      out+0 = BN1(ybuf) (fused bn_apply of layer 1) ----
    k_gemm3<128, 2, true><<<cdiv(N, 32), B, 0, stream>>>(ybuf, w2hi, w2lo, c2,
                                                         as2, ad2, xwb_us, al_s, al_d,
                                                         scb, shb, out + 0, N);
    k_agg<128, 2><<<cdiv(N, 4), B, 0, stream>>>(xwb, al_s, al_d, row_start, col, b2, ybuf, N);
    k_bn_stats<128><<<256, B, 0, stream>>>(ybuf, stats2, N);
    k_wconv3p<64><<<16, 256, 0, stream>>>(W3, stats2, g2, be2, invN, 1,
                                          scb, shb, w3hi, w3lo, c3);

    // ---- layer 3: 128 -> 64 (H=1), BN2 folded into W3; gemm also emits
    //      out+128 = BN2(ybuf) (fused bn_apply of layer 2) ----
    k_gemm3<64, 1, true><<<cdiv(N, 64), B, 0, stream>>>(ybuf, w3hi, w3lo, c3,
                                                        as3, ad3, xwb_us, al_s, al_d,
                                                        scb, shb, out + 128, N);
    k_agg<64, 1><<<cdiv(N, 4), B, 0, stream>>>(xwb, al_s, al_d, row_start, col, b3, ybuf, N);
    k_bn_stats<64><<<256, B, 0, stream>>>(ybuf, stats3, N);
    k_bn_apply64p<<<cdiv(N * 16, B), B, 0, stream>>>(ybuf, stats3, g3, be3, invN,
                                                     out + 256, N);
}

// Round 16
// 426.897 us; speedup vs baseline: 1.1796x; 1.0011x over previous
//
#include <hip/hip_runtime.h>

typedef unsigned int uint;
typedef unsigned short ushort;

// ---------------------------------------------------------------------------
// GAT x3 + ReLU + BatchNorm, MI355X.
// R24 change (single theory): move BN from W-fold to the GEMM A-SIDE.
//  - k_gemm4<BNA>: 128-thread LDS prologue computes sc/sh from raw stats
//    (g,be,invN); per k-step applies b=a*sc+sh BEFORE the bf16 hi/lo split;
//    the fused out-store reuses these BN'd values (old OUTW fmas deleted);
//    cvec epilogue term deleted (no fold residue).
//  - W conversion is now stats-independent: ALL 3 wconv merge into ONE
//    upfront k_wconvAll (80 blocks, pure format conversion).
//  - layout: stats(768f) and bcntp(8192i) contiguous -> ONE memset.
// Serial chain per layer: stats -> gemm (wconv/prep stages gone).
// Dispatches 22 -> 16. k_agg (R18 local optimum) / bn_stats / CSR /
// apply64p byte-identical to R23 (427us verified best).
// ---------------------------------------------------------------------------

static __device__ __forceinline__ ushort bf16_rne(float x) {
    uint u = __float_as_uint(x);
    return (ushort)((u + 0x7fffu + ((u >> 16) & 1u)) >> 16);
}
static __device__ __forceinline__ float bf16_f(ushort h) {
    return __uint_as_float(((uint)h) << 16);
}

// ---------------- bucket-sort CSR build ----------------
__global__ __launch_bounds__(256) void k_bcount(const int* __restrict__ dst, int e,
                                                int* __restrict__ bcntp) {
    __shared__ int h[512];
    int tid = threadIdx.x;
    h[tid] = 0;
    h[tid + 256] = 0;
    __syncthreads();
    int stride = gridDim.x * 256;
    for (int i = blockIdx.x * 256 + tid; i < e; i += stride)
        atomicAdd(&h[dst[i] >> 7], 1);
    __syncthreads();
    if (h[tid]) atomicAdd(&bcntp[tid * 16], h[tid]);
    if (h[tid + 256]) atomicAdd(&bcntp[(tid + 256) * 16], h[tid + 256]);
}

__global__ __launch_bounds__(512) void k_bscan(const int* __restrict__ bcntp,
                                               int* __restrict__ bbase,
                                               int* __restrict__ bcurp, int nb, int n,
                                               int total, int* __restrict__ row_start) {
    __shared__ int s[512];
    int tid = threadIdx.x;
    int v = 0;
    if (tid < nb) v = bcntp[tid * 16] + min(128, n - (tid << 7));  // + self-loops
    s[tid] = v;
    __syncthreads();
    for (int off = 1; off < 512; off <<= 1) {
        int t = (tid >= off) ? s[tid - off] : 0;
        __syncthreads();
        s[tid] += t;
        __syncthreads();
    }
    if (tid < nb) {
        int excl = s[tid] - v;
        bbase[tid] = excl;
        bcurp[tid * 16] = excl;
    }
    if (tid == 0) {
        bbase[nb] = total;
        row_start[n] = total;
    }
}

// multisplit: chunk of 8192 items -> LDS bucket-sort -> coalesced copy-out
__global__ __launch_bounds__(512) void k_bscatter(const int* __restrict__ src,
                                                  const int* __restrict__ dst, int e, int n,
                                                  int* __restrict__ bcurp,
                                                  int* __restrict__ pk) {
    __shared__ int hcnt[512], bstart[512], bcursor[512], gbase[512];
    __shared__ int stage[8192];
    int tid = threadIdx.x;
    int total = e + n;
    int nchunk = (total + 8191) >> 13;
    for (int c = blockIdx.x; c < nchunk; c += gridDim.x) {
        int base = c << 13;
        int cnt = min(8192, total - base);
        hcnt[tid] = 0;
        __syncthreads();
        for (int j = tid; j < cnt; j += 512) {
            int i = base + j;
            int d = (i < e) ? dst[i] : (i - e);
            atomicAdd(&hcnt[d >> 7], 1);
        }
        __syncthreads();
        int v = hcnt[tid];
        bstart[tid] = v;
        __syncthreads();
        for (int off = 1; off < 512; off <<= 1) {  // inclusive scan in-place
            int t = (tid >= off) ? bstart[tid - off] : 0;
            __syncthreads();
            bstart[tid] += t;
            __syncthreads();
        }
        int excl = bstart[tid] - v;
        __syncthreads();
        bstart[tid] = excl;
        bcursor[tid] = excl;
        if (v) gbase[tid] = atomicAdd(&bcurp[tid * 16], v);
        __syncthreads();
        for (int j = tid; j < cnt; j += 512) {
            int i = base + j;
            int d, sv;
            if (i < e) { d = dst[i]; sv = src[i]; }
            else       { d = i - e; sv = d; }
            uint b = (uint)(d >> 7);
            int r = atomicAdd(&bcursor[b], 1);
            stage[r] = (int)((b << 23) | ((uint)(d & 127) << 16) | (uint)sv);
        }
        __syncthreads();
        for (int j = tid; j < cnt; j += 512) {
            int p = stage[j];
            int b = (int)(((uint)p) >> 23);
            pk[gbase[b] + (j - bstart[b])] = p;   // coalesced runs per bucket
        }
        __syncthreads();
    }
}

// one block per bucket: local CSR entirely in LDS, coalesced global I/O
__global__ __launch_bounds__(256) void k_bfill(const int* __restrict__ pk,
                                               const int* __restrict__ bbase, int n,
                                               int* __restrict__ row_start,
                                               int* __restrict__ col) {
    int b = blockIdx.x;
    int s0 = bbase[b], s1 = bbase[b + 1];
    int seg = s1 - s0;
    int node0 = b << 7;
    int nn = min(128, n - node0);
    int tid = threadIdx.x;
    __shared__ int cnt[128], scn[128];
    __shared__ int colst[4608];
    if (tid < 128) cnt[tid] = 0;
    __syncthreads();
    for (int j = tid; j < seg; j += 256)
        atomicAdd(&cnt[(pk[s0 + j] >> 16) & 127], 1);
    __syncthreads();
    int myc = 0;
    if (tid < 128) { myc = cnt[tid]; scn[tid] = myc; }
    __syncthreads();
    for (int off = 1; off < 128; off <<= 1) {
        int t = (tid >= off && tid < 128) ? scn[tid - off] : 0;
        __syncthreads();
        if (tid < 128) scn[tid] += t;
        __syncthreads();
    }
    int excl = 0;
    if (tid < 128) excl = scn[tid] - myc;
    if (tid < nn) row_start[node0 + tid] = s0 + excl;
    __syncthreads();
    if (tid < 128) cnt[tid] = excl;   // becomes cursor
    __syncthreads();
    bool big = seg > 4608;            // fallback guard (never expected)
    for (int j = tid; j < seg; j += 256) {
        int p = pk[s0 + j];
        int r = atomicAdd(&cnt[(p >> 16) & 127], 1);
        if (big) col[s0 + r] = p & 0xffff;
        else colst[r] = p & 0xffff;
    }
    if (!big) {
        __syncthreads();
        for (int j = tid; j < seg; j += 256) col[s0 + j] = colst[j];
    }
}

// ---------------- W pre-conversion: all 3 layers in ONE launch --------------
typedef __attribute__((ext_vector_type(8))) short short8;
typedef __attribute__((ext_vector_type(4))) float float4v;

// Emit W fp32 [128][F] as bf16 hi/lo lane-major fragment blocks (R16 layout):
//   block (tg,ks): 64 lanes x short8; lane=quad*16+l15 holds column
//   n=tg*16+l15, k=ks*32+quad*8..+8. Pure conversion (no BN fold).
template <int F>
static __device__ __forceinline__ void wconv_emit(const float* __restrict__ W, int bb,
                                                  int tid, ushort* __restrict__ whi,
                                                  ushort* __restrict__ wlo) {
    int n = (bb * 256 + tid) >> 6;
    int lane = tid & 63;
    if (n >= F || lane >= 16) return;
    int ks = lane >> 2, quad = lane & 3;
    int tg = n >> 4, l15 = n & 15;
    long long off8 = ((long long)((tg * 4 + ks) * 64 + quad * 16 + l15)) * 8;
    short8 h8, l8;
#pragma unroll
    for (int j = 0; j < 8; j++) {
        int k = ks * 32 + quad * 8 + j;
        float w = W[k * F + n];
        ushort h = bf16_rne(w);
        h8[j] = (short)h;
        l8[j] = (short)bf16_rne(w - bf16_f(h));
    }
    *(short8*)(whi + off8) = h8;
    *(short8*)(wlo + off8) = l8;
}

__global__ __launch_bounds__(256) void k_wconvAll(const float* __restrict__ W1,
                                                  const float* __restrict__ W2,
                                                  const float* __restrict__ W3,
                                                  ushort* __restrict__ w1hi,
                                                  ushort* __restrict__ w1lo,
                                                  ushort* __restrict__ w2hi,
                                                  ushort* __restrict__ w2lo,
                                                  ushort* __restrict__ w3hi,
                                                  ushort* __restrict__ w3lo) {
    int b = blockIdx.x;
    int tid = threadIdx.x;
    if (b < 32) wconv_emit<128>(W1, b, tid, w1hi, w1lo);
    else if (b < 64) wconv_emit<128>(W2, b - 32, tid, w2hi, w2lo);
    else wconv_emit<64>(W3, b - 64, tid, w3hi, w3lo);
}

// ---- GEMM: BN_A(A)[M,128] @ Wfrag -> bf16 xwb + logits. -------------------
// BNA: LDS prologue computes sc/sh from raw stats (128ch sums/sumsq) + g/be;
// per k-step b = a*sc+sh applied BEFORE the bf16 split; BN'd values also
// stored to outp (half==0 waves, once per row) -- this IS the layer output.
static __device__ __forceinline__ void cvt8(const float4& f0, const float4& f1,
                                            short8& hi, short8& lo) {
#define CV8(i, val)                                        \
    {                                                      \
        ushort h_ = bf16_rne(val);                         \
        hi[i] = (short)h_;                                 \
        lo[i] = (short)bf16_rne((val)-bf16_f(h_));         \
    }
    CV8(0, f0.x) CV8(1, f0.y) CV8(2, f0.z) CV8(3, f0.w)
    CV8(4, f1.x) CV8(5, f1.y) CV8(6, f1.z) CV8(7, f1.w)
#undef CV8
}

template <int F, int H, bool BNA>
__global__ __launch_bounds__(256) void k_gemm4(const float* __restrict__ A,
                                               const ushort* __restrict__ whi,
                                               const ushort* __restrict__ wlo,
                                               const float* __restrict__ asrc,
                                               const float* __restrict__ adst,
                                               ushort* __restrict__ xwb,
                                               float* __restrict__ al_s,
                                               float* __restrict__ al_d,
                                               const float* __restrict__ stats,
                                               const float* __restrict__ g,
                                               const float* __restrict__ be,
                                               float invN,
                                               float* __restrict__ outp, int M) {
    constexpr bool SPLIT = (F == 128);          // split 8 col-tiles across wave pair
    constexpr int RPB = SPLIT ? 32 : 64;        // rows per block
    __shared__ float lsc[128], lsh[128];
    int tid = threadIdx.x;
    if (BNA) {
        if (tid < 128) {
            float mean = stats[tid] * invN;
            float var = stats[128 + tid] * invN - mean * mean;
            float s = g[tid] * rsqrtf(var + 1e-5f);
            lsc[tid] = s;
            lsh[tid] = be[tid] - mean * s;
        }
        __syncthreads();
    }
    int wave = tid >> 6, lane = tid & 63;
    int quad = lane >> 4, l15 = lane & 15;
    int rg = SPLIT ? (wave >> 1) : wave;
    int half = SPLIT ? (wave & 1) : 0;
    int base = blockIdx.x * RPB + rg * 16;
    int coff = half * 64;                       // this wave's column offset
    int tgb = SPLIT ? half * 4 : 0;             // global tile base

    float4v acc[4];
#pragma unroll
    for (int t = 0; t < 4; t++) acc[t] = (float4v){0.f, 0.f, 0.f, 0.f};

    int arow = base + l15;
    bool aval = (arow < M);
    const float* Ap = A + (long long)arow * 128;

#pragma unroll
    for (int ks = 0; ks < 4; ks++) {
        float4 f0 = {0.f, 0.f, 0.f, 0.f}, f1 = {0.f, 0.f, 0.f, 0.f};
        if (aval) {
            f0 = *(const float4*)(Ap + ks * 32 + quad * 8);
            f1 = *(const float4*)(Ap + ks * 32 + quad * 8 + 4);
        }
        if (BNA) {
            int kk = ks * 32 + quad * 8;
            f0.x = fmaf(f0.x, lsc[kk + 0], lsh[kk + 0]);
            f0.y = fmaf(f0.y, lsc[kk + 1], lsh[kk + 1]);
            f0.z = fmaf(f0.z, lsc[kk + 2], lsh[kk + 2]);
            f0.w = fmaf(f0.w, lsc[kk + 3], lsh[kk + 3]);
            f1.x = fmaf(f1.x, lsc[kk + 4], lsh[kk + 4]);
            f1.y = fmaf(f1.y, lsc[kk + 5], lsh[kk + 5]);
            f1.z = fmaf(f1.z, lsc[kk + 6], lsh[kk + 6]);
            f1.w = fmaf(f1.w, lsc[kk + 7], lsh[kk + 7]);
            if (aval && half == 0) {
                float* op = outp + (long long)arow * 320 + kk;
                *(float4*)op = f0;
                *(float4*)(op + 4) = f1;
            }
        }
        short8 ah, al;
        cvt8(f0, f1, ah, al);
#pragma unroll
        for (int t = 0; t < 4; t++) {
            // coalesced lane-major fragment block
            long long boff = ((long long)(((tgb + t) * 4 + ks) * 64 + lane)) * 8;
            short8 bh = *(const short8*)(whi + boff);
            short8 bl = *(const short8*)(wlo + boff);
            acc[t] = __builtin_amdgcn_mfma_f32_16x16x32_bf16(ah, bh, acc[t], 0, 0, 0);
            acc[t] = __builtin_amdgcn_mfma_f32_16x16x32_bf16(ah, bl, acc[t], 0, 0, 0);
            acc[t] = __builtin_amdgcn_mfma_f32_16x16x32_bf16(al, bh, acc[t], 0, 0, 0);
        }
    }

    // ---- epilogue: C[row=quad*4+r][col(tile)=l15], tile t -> col coff+t*16+l15
    float asl[4], adl[4];
#pragma unroll
    for (int t = 0; t < 4; t++) {
        int n = coff + t * 16 + l15;
        asl[t] = asrc[n];
        adl[t] = adst[n];
    }
#pragma unroll
    for (int r = 0; r < 4; r++) {
        int grow = base + quad * 4 + r;
        float v0 = acc[0][r];
        float v1 = acc[1][r];
        float v2 = acc[2][r];
        float v3 = acc[3][r];
        if (grow < M) {
            ushort* xp = xwb + (long long)grow * F + coff + l15;
            xp[0] = bf16_rne(v0);
            xp[16] = bf16_rne(v1);
            xp[32] = bf16_rne(v2);
            xp[48] = bf16_rne(v3);
        }
        float ps = 0.f, pd = 0.f;
        ps = fmaf(v0, asl[0], ps); pd = fmaf(v0, adl[0], pd);
        ps = fmaf(v1, asl[1], ps); pd = fmaf(v1, adl[1], pd);
        ps = fmaf(v2, asl[2], ps); pd = fmaf(v2, adl[2], pd);
        ps = fmaf(v3, asl[3], ps); pd = fmaf(v3, adl[3], pd);
#pragma unroll
        for (int off = 1; off < 16; off <<= 1) {
            ps += __shfl_xor(ps, off);
            pd += __shfl_xor(pd, off);
        }
        if (l15 == 0 && grow < M) {
            al_s[grow * H + half] = ps;
            al_d[grow * H + half] = pd;
        }
    }
}

// ---------------- per-dst-wave softmax aggregation (R18 verbatim) -----------
template <int F, int H>
__global__ __launch_bounds__(256) void k_agg(const uint* __restrict__ xwb,
                      const float* __restrict__ al_s,
                      const float* __restrict__ al_d, const int* __restrict__ row_start,
                      const int* __restrict__ col, const float* __restrict__ bias,
                      float* __restrict__ y, int n) {
    int wid = (blockIdx.x * blockDim.x + threadIdx.x) >> 6;  // one wave per dst
    int lane = threadIdx.x & 63;
    if (wid >= n) return;
    int beg = row_start[wid], end = row_start[wid + 1];

    float ald[H];
#pragma unroll
    for (int h = 0; h < H; h++) ald[h] = al_d[wid * H + h];

    if (end - beg <= 64) {
        // ---------------- fast path: one lane = one edge ----------------
        int nb = end - beg;
        int s_c = 0;
        float ev0 = -1e30f, ev1 = -1e30f;
        if (lane < nb) {
            s_c = col[beg + lane];
            if (H == 2) {
                float2 av = ((const float2*)al_s)[s_c];
                float e0 = av.x + ald[0];
                float e1 = av.y + ald[1];
                ev0 = (e0 >= 0.f) ? e0 : 0.2f * e0;
                ev1 = (e1 >= 0.f) ? e1 : 0.2f * e1;
            } else {
                float e0 = al_s[s_c] + ald[0];
                ev0 = (e0 >= 0.f) ? e0 : 0.2f * e0;
            }
        }
        // max butterfly
        float m0 = ev0, m1 = ev1;
#pragma unroll
        for (int off = 32; off; off >>= 1) {
            m0 = fmaxf(m0, __shfl_xor(m0, off));
            if (H == 2) m1 = fmaxf(m1, __shfl_xor(m1, off));
        }
        // exp once; sum butterfly; alpha free (0 for lanes >= nb)
        float x0 = (lane < nb) ? __expf(ev0 - m0) : 0.f;
        float x1 = (H == 2 && lane < nb) ? __expf(ev1 - m1) : 0.f;
        float l0 = x0, l1 = x1;
#pragma unroll
        for (int off = 32; off; off >>= 1) {
            l0 += __shfl_xor(l0, off);
            if (H == 2) l1 += __shfl_xor(l1, off);
        }
        float a0 = x0 / (l0 + 1e-16f);
        float a1 = (H == 2) ? x1 / (l1 + 1e-16f) : a0;

        // ---- accumulate: wide rows-per-load, 8 loads (4KB) in flight ----
        float accv0 = 0.f, accv1 = 0.f, accv2 = 0.f, accv3 = 0.f;
        const uint2* xw2 = (const uint2*)xwb;

        if (F == 128) {
            // lane covers cols 4*li..4*li+3 of rows for half = lane>>5
            int li = lane & 31;
            int half = lane >> 5;
            bool head0 = (li < 16);           // col<64 <=> li<16
            for (int j = 0; j < nb; j += 16) {
                int rr[8];
                float alq[8];
#pragma unroll
                for (int q = 0; q < 8; q++) {
                    int e = j + 2 * q + half;     // <= 63 since nb<=64
                    rr[q] = __shfl(s_c, e);
                    float aa = __shfl(a0, e);
                    float bb = __shfl(a1, e);
                    alq[q] = (H == 2) ? (head0 ? aa : bb) : aa;
                }
                uint2 uu[8];
#pragma unroll
                for (int q = 0; q < 8; q++)
                    uu[q] = xw2[(rr[q] << 5) + li];
#pragma unroll
                for (int q = 0; q < 8; q++) {
                    accv0 = fmaf(alq[q], __uint_as_float(uu[q].x << 16), accv0);
                    accv1 = fmaf(alq[q], __uint_as_float(uu[q].x & 0xffff0000u), accv1);
                    accv2 = fmaf(alq[q], __uint_as_float(uu[q].y << 16), accv2);
                    accv3 = fmaf(alq[q], __uint_as_float(uu[q].y & 0xffff0000u), accv3);
                }
            }
            // cross-half reduce: lane l and l^32 hold same cols
            accv0 += __shfl_xor(accv0, 32);
            accv1 += __shfl_xor(accv1, 32);
            accv2 += __shfl_xor(accv2, 32);
            accv3 += __shfl_xor(accv3, 32);
            if (li == lane) {  // lane < 32
                float4 o;
                o.x = fmaxf(accv0 + bias[4 * li + 0], 0.f);
                o.y = fmaxf(accv1 + bias[4 * li + 1], 0.f);
                o.z = fmaxf(accv2 + bias[4 * li + 2], 0.f);
                o.w = fmaxf(accv3 + bias[4 * li + 3], 0.f);
                ((float4*)y)[(long long)wid * 32 + li] = o;
            }
        } else {
            // F=64, H=1: lane covers cols 4*li..4*li+3, group g = lane>>4
            int li = lane & 15;
            int g = lane >> 4;
            for (int j = 0; j < nb; j += 32) {
                int rr[8];
                float alq[8];
#pragma unroll
                for (int q = 0; q < 8; q++) {
                    int e = j + 4 * q + g;        // <= 63 since nb<=64
                    rr[q] = __shfl(s_c, e);
                    alq[q] = __shfl(a0, e);
                }
                uint2 uu[8];
#pragma unroll
                for (int q = 0; q < 8; q++)
                    uu[q] = xw2[(rr[q] << 4) + li];
#pragma unroll
                for (int q = 0; q < 8; q++) {
                    accv0 = fmaf(alq[q], __uint_as_float(uu[q].x << 16), accv0);
                    accv1 = fmaf(alq[q], __uint_as_float(uu[q].x & 0xffff0000u), accv1);
                    accv2 = fmaf(alq[q], __uint_as_float(uu[q].y << 16), accv2);
                    accv3 = fmaf(alq[q], __uint_as_float(uu[q].y & 0xffff0000u), accv3);
                }
            }
            // reduce across 4 groups (lanes sharing li)
            accv0 += __shfl_xor(accv0, 16); accv0 += __shfl_xor(accv0, 32);
            accv1 += __shfl_xor(accv1, 16); accv1 += __shfl_xor(accv1, 32);
            accv2 += __shfl_xor(accv2, 16); accv2 += __shfl_xor(accv2, 32);
            accv3 += __shfl_xor(accv3, 16); accv3 += __shfl_xor(accv3, 32);
            if (lane < 16) {
                float4 o;
                o.x = fmaxf(accv0 + bias[4 * li + 0], 0.f);
                o.y = fmaxf(accv1 + bias[4 * li + 1], 0.f);
                o.z = fmaxf(accv2 + bias[4 * li + 2], 0.f);
                o.w = fmaxf(accv3 + bias[4 * li + 3], 0.f);
                ((float4*)y)[(long long)wid * 16 + li] = o;
            }
        }
        return;
    }

    // ---------------- generic path (deg > 64), original code ----------------
    float acc0 = 0.f, acc1 = 0.f;
    {
        float m[H], l[H];
#pragma unroll
        for (int h = 0; h < H; h++) {
            m[h] = -1e30f;
            l[h] = 0.f;
        }
        for (int e = beg + lane; e < end; e += 64) {
            int s = col[e];
#pragma unroll
            for (int h = 0; h < H; h++) {
                float ev = al_s[s * H + h] + ald[h];
                ev = (ev >= 0.f) ? ev : 0.2f * ev;
                if (ev > m[h]) {
                    l[h] = l[h] * __expf(m[h] - ev) + 1.f;
                    m[h] = ev;
                } else {
                    l[h] += __expf(ev - m[h]);
                }
            }
        }
#pragma unroll
        for (int off = 32; off; off >>= 1) {
#pragma unroll
            for (int h = 0; h < H; h++) {
                float mo = __shfl_xor(m[h], off);
                float lo = __shfl_xor(l[h], off);
                float mn = fmaxf(m[h], mo);
                l[h] = l[h] * __expf(m[h] - mn) + lo * __expf(mo - mn);
                m[h] = mn;
            }
        }
        float inv[H];
#pragma unroll
        for (int h = 0; h < H; h++) inv[h] = 1.f / (l[h] + 1e-16f);

        for (int base = beg; base < end; base += 64) {
            int nb = min(64, end - base);
            int ec = min(base + lane, end - 1);
            int s = col[ec];
            float a0, a1;
            {
                float av[H];
#pragma unroll
                for (int h = 0; h < H; h++) {
                    float ev = al_s[s * H + h] + ald[h];
                    ev = (ev >= 0.f) ? ev : 0.2f * ev;
                    av[h] = __expf(ev - m[h]) * inv[h];
                }
                a0 = av[0];
                a1 = av[H - 1];
            }
            int j = 0;
            for (; j + 4 <= nb; j += 4) {
                int s0 = __shfl(s, j + 0), s1 = __shfl(s, j + 1);
                int s2 = __shfl(s, j + 2), s3 = __shfl(s, j + 3);
                float q00 = __shfl(a0, j + 0), q01 = __shfl(a1, j + 0);
                float q10 = __shfl(a0, j + 1), q11 = __shfl(a1, j + 1);
                float q20 = __shfl(a0, j + 2), q21 = __shfl(a1, j + 2);
                float q30 = __shfl(a0, j + 3), q31 = __shfl(a1, j + 3);
                float p0, p1, p2, p3;
                if (H == 2) {
                    p0 = (lane < 32) ? q00 : q01;
                    p1 = (lane < 32) ? q10 : q11;
                    p2 = (lane < 32) ? q20 : q21;
                    p3 = (lane < 32) ? q30 : q31;
                } else {
                    p0 = q00; p1 = q10; p2 = q20; p3 = q30;
                }
                if (F == 128) {
                    uint u0 = xwb[(s0 << 6) + lane];
                    uint u1 = xwb[(s1 << 6) + lane];
                    uint u2 = xwb[(s2 << 6) + lane];
                    uint u3 = xwb[(s3 << 6) + lane];
                    acc0 = fmaf(p0, __uint_as_float(u0 << 16), acc0);
                    acc1 = fmaf(p0, __uint_as_float(u0 & 0xffff0000u), acc1);
                    acc0 = fmaf(p1, __uint_as_float(u1 << 16), acc0);
                    acc1 = fmaf(p1, __uint_as_float(u1 & 0xffff0000u), acc1);
                    acc0 = fmaf(p2, __uint_as_float(u2 << 16), acc0);
                    acc1 = fmaf(p2, __uint_as_float(u2 & 0xffff0000u), acc1);
                    acc0 = fmaf(p3, __uint_as_float(u3 << 16), acc0);
                    acc1 = fmaf(p3, __uint_as_float(u3 & 0xffff0000u), acc1);
                } else {
                    int idx = lane >> 1;
                    bool hi = (lane & 1) != 0;
                    uint u0 = xwb[(s0 << 5) + idx];
                    uint u1 = xwb[(s1 << 5) + idx];
                    uint u2 = xwb[(s2 << 5) + idx];
                    uint u3 = xwb[(s3 << 5) + idx];
                    acc0 = fmaf(p0, __uint_as_float(hi ? (u0 & 0xffff0000u) : (u0 << 16)), acc0);
                    acc0 = fmaf(p1, __uint_as_float(hi ? (u1 & 0xffff0000u) : (u1 << 16)), acc0);
                    acc0 = fmaf(p2, __uint_as_float(hi ? (u2 & 0xffff0000u) : (u2 << 16)), acc0);
                    acc0 = fmaf(p3, __uint_as_float(hi ? (u3 & 0xffff0000u) : (u3 << 16)), acc0);
                }
            }
            for (; j < nb; ++j) {
                int sj = __shfl(s, j);
                float q0 = __shfl(a0, j);
                float q1 = __shfl(a1, j);
                float alpha;
                if (H == 2) {
                    alpha = (lane < 32) ? q0 : q1;
                } else {
                    alpha = q0;
                }
                if (F == 128) {
                    uint u = xwb[(sj << 6) + lane];
                    acc0 = fmaf(alpha, __uint_as_float(u << 16), acc0);
                    acc1 = fmaf(alpha, __uint_as_float(u & 0xffff0000u), acc1);
                } else {
                    uint u = xwb[(sj << 5) + (lane >> 1)];
                    acc0 = fmaf(alpha, __uint_as_float((lane & 1) ? (u & 0xffff0000u) : (u << 16)), acc0);
                }
            }
        }
    }

    if (F == 128) {
        float2 o;
        o.x = fmaxf(acc0 + bias[2 * lane], 0.f);
        o.y = fmaxf(acc1 + bias[2 * lane + 1], 0.f);
        ((float2*)y)[(long long)wid * 64 + lane] = o;
    } else {
        y[(long long)wid * 64 + lane] = fmaxf(acc0 + bias[lane], 0.f);
    }
}

// ---------------- BatchNorm ----------------
template <int F>
__global__ void k_bn_stats(const float* __restrict__ y, float* __restrict__ sums, int n) {
    constexpr int C4 = F / 4;
    constexpr int NPB = 256 / C4;
    int c4 = threadIdx.x % C4;
    int sub = threadIdx.x / C4;
    float4 s = {0, 0, 0, 0}, s2 = {0, 0, 0, 0};
    for (int node = blockIdx.x * NPB + sub; node < n; node += gridDim.x * NPB) {
        float4 v = ((const float4*)y)[node * C4 + c4];
        s.x += v.x; s.y += v.y; s.z += v.z; s.w += v.w;
        s2.x += v.x * v.x; s2.y += v.y * v.y; s2.z += v.z * v.z; s2.w += v.w * v.w;
    }
    __shared__ float4 ls[256], ls2[256];
    ls[threadIdx.x] = s;
    ls2[threadIdx.x] = s2;
    __syncthreads();
    if (sub == 0) {
#pragma unroll
        for (int k = 1; k < NPB; k++) {
            float4 t = ls[c4 + k * C4], t2 = ls2[c4 + k * C4];
            s.x += t.x; s.y += t.y; s.z += t.z; s.w += t.w;
            s2.x += t2.x; s2.y += t2.y; s2.z += t2.z; s2.w += t2.w;
        }
        atomicAdd(&sums[c4 * 4 + 0], s.x);
        atomicAdd(&sums[c4 * 4 + 1], s.y);
        atomicAdd(&sums[c4 * 4 + 2], s.z);
        atomicAdd(&sums[c4 * 4 + 3], s.w);
        atomicAdd(&sums[F + c4 * 4 + 0], s2.x);
        atomicAdd(&sums[F + c4 * 4 + 1], s2.y);
        atomicAdd(&sums[F + c4 * 4 + 2], s2.z);
        atomicAdd(&sums[F + c4 * 4 + 3], s2.w);
    }
}

// BN apply for F=64 with in-kernel prep (reads stats directly)
__global__ void k_bn_apply64p(const float* __restrict__ y, const float* __restrict__ stats,
                              const float* __restrict__ g, const float* __restrict__ be,
                              float invN, float* __restrict__ outp, int n) {
    constexpr int C4 = 16;
    int t = blockIdx.x * blockDim.x + threadIdx.x;
    if (t >= n * C4) return;
    int node = t / C4, c4 = t % C4;
    float4 v = ((const float4*)y)[t];
    float4 o;
#pragma unroll
    for (int i = 0; i < 4; i++) {
        int ch = c4 * 4 + i;
        float mean = stats[ch] * invN;
        float var = stats[64 + ch] * invN - mean * mean;
        float s = g[ch] * rsqrtf(var + 1e-5f);
        float sh = be[ch] - mean * s;
        float vi = (i == 0) ? v.x : (i == 1) ? v.y : (i == 2) ? v.z : v.w;
        float oi = vi * s + sh;
        if (i == 0) o.x = oi;
        else if (i == 1) o.y = oi;
        else if (i == 2) o.z = oi;
        else o.w = oi;
    }
    ((float4*)(outp + (long long)node * 320))[c4] = o;
}

// ---------------------------------------------------------------------------
extern "C" void kernel_launch(void* const* d_in, const int* in_sizes, int n_in,
                              void* d_out, int out_size, void* d_ws, size_t ws_size,
                              hipStream_t stream) {
    const float* x   = (const float*)d_in[0];
    const int*   adj = (const int*)d_in[1];
    const float* W1  = (const float*)d_in[2];
    const float* as1 = (const float*)d_in[3];
    const float* ad1 = (const float*)d_in[4];
    const float* b1  = (const float*)d_in[5];
    const float* g1  = (const float*)d_in[6];
    const float* be1 = (const float*)d_in[7];
    const float* W2  = (const float*)d_in[8];
    const float* as2 = (const float*)d_in[9];
    const float* ad2 = (const float*)d_in[10];
    const float* b2  = (const float*)d_in[11];
    const float* g2  = (const float*)d_in[12];
    const float* be2 = (const float*)d_in[13];
    const float* W3  = (const float*)d_in[14];
    const float* as3 = (const float*)d_in[15];
    const float* ad3 = (const float*)d_in[16];
    const float* b3  = (const float*)d_in[17];
    const float* g3  = (const float*)d_in[18];
    const float* be3 = (const float*)d_in[19];
    float* out = (float*)d_out;

    const int N = in_sizes[0] / 128;
    const int E = in_sizes[1] / 2;

    // workspace (stats and bcntp contiguous -> one memset)
    float* ws    = (float*)d_ws;
    float* ybuf  = ws;                          // N*128
    float* al_s  = ybuf + (size_t)N * 128;      // N*2
    float* al_d  = al_s + (size_t)N * 2;        // N*2
    float* stats1 = al_d + (size_t)N * 2;       // 256
    float* stats2 = stats1 + 256;               // 256
    float* stats3 = stats2 + 256;               // 256
    int* bcntp     = (int*)(stats3 + 256);      // 512*16 (line-padded counts)
    int* bcurp     = bcntp + 8192;              // 512*16 (line-padded cursors)
    int* bbase     = bcurp + 8192;              // 513
    int* row_start = bbase + 513;               // N+1
    int* col       = row_start + (N + 1);       // E+N
    uint* xwb      = (uint*)(col + (E + N));    // N*64 uints (bf16x2)

    // pre-converted W (bf16 hi/lo fragment blocks)
    uintptr_t wp = (uintptr_t)(xwb + (size_t)N * 64);
    wp = (wp + 63) & ~(uintptr_t)63;
    ushort* w1hi = (ushort*)wp;                 // 128*128
    ushort* w1lo = w1hi + 16384;
    ushort* w2hi = w1lo + 16384;
    ushort* w2lo = w2hi + 16384;
    ushort* w3hi = w2lo + 16384;                // 64*128
    ushort* w3lo = w3hi + 8192;

    // packed bucket-sorted edges alias ybuf (dead before k_agg L1 writes it)
    int* pk = (int*)ybuf;                       // E+N ints

    const int* esrc = adj;
    const int* edst = adj + E;

    const int B = 256;
    auto cdiv = [](int a, int b) { return (a + b - 1) / b; };

    // ---- ONE memset: stats (768 floats) + bcntp (8192 ints) contiguous ----
    hipMemsetAsync(stats1, 0, 768 * sizeof(float) + 8192 * sizeof(int), stream);

    // ---- all W conversions in one launch (stats-independent now) ----
    k_wconvAll<<<80, 256, 0, stream>>>(W1, W2, W3, w1hi, w1lo, w2hi, w2lo, w3hi, w3lo);

    // ---- CSR build: bucket counting sort ----
    const int NB = (N + 127) >> 7;              // buckets (needs N<=65536)
    k_bcount<<<128, 256, 0, stream>>>(edst, E, bcntp);
    k_bscan<<<1, 512, 0, stream>>>(bcntp, bbase, bcurp, NB, N, E + N, row_start);
    int nchunk = (E + N + 8191) >> 13;
    k_bscatter<<<nchunk, 512, 0, stream>>>(esrc, edst, E, N, bcurp, pk);
    k_bfill<<<NB, 256, 0, stream>>>(pk, bbase, N, row_start, col);

    const float invN = 1.f / (float)N;
    ushort* xwb_us = (ushort*)xwb;

    // ---- layer 1: 128 -> 128 (H=2), raw A ----
    k_gemm4<128, 2, false><<<cdiv(N, 32), B, 0, stream>>>(
        x, w1hi, w1lo, as1, ad1, xwb_us, al_s, al_d,
        nullptr, nullptr, nullptr, 0.f, nullptr, N);
    k_agg<128, 2><<<cdiv(N, 4), B, 0, stream>>>(xwb, al_s, al_d, row_start, col, b1, ybuf, N);
    k_bn_stats<128><<<256, B, 0, stream>>>(ybuf, stats1, N);

    // ---- layer 2: A-side BN1; gemm also emits out+0 = BN1(ybuf) ----
    k_gemm4<128, 2, true><<<cdiv(N, 32), B, 0, stream>>>(
        ybuf, w2hi, w2lo, as2, ad2, xwb_us, al_s, al_d,
        stats1, g1, be1, invN, out + 0, N);
    k_agg<128, 2><<<cdiv(N, 4), B, 0, stream>>>(xwb, al_s, al_d, row_start, col, b2, ybuf, N);
    k_bn_stats<128><<<256, B, 0, stream>>>(ybuf, stats2, N);

    // ---- layer 3: A-side BN2; gemm also emits out+128 = BN2(ybuf) ----
    k_gemm4<64, 1, true><<<cdiv(N, 64), B, 0, stream>>>(
        ybuf, w3hi, w3lo, as3, ad3, xwb_us, al_s, al_d,
        stats2, g2, be2, invN, out + 128, N);
    k_agg<64, 1><<<cdiv(N, 4), B, 0, stream>>>(xwb, al_s, al_d, row_start, col, b3, ybuf, N);
    k_bn_stats<64><<<256, B, 0, stream>>>(ybuf, stats3, N);
    k_bn_apply64p<<<cdiv(N * 16, B), B, 0, stream>>>(ybuf, stats3, g3, be3, invN,
                                                     out + 256, N);
}

// Round 17
// 413.437 us; speedup vs baseline: 1.2180x; 1.0326x over previous
//
#include <hip/hip_runtime.h>

typedef unsigned int uint;
typedef unsigned short ushort;

// ---------------------------------------------------------------------------
// GAT x3 + ReLU + BatchNorm, MI355X.
// R25 change (single fix): R24's layout left xwb at offset 8 (mod 64) --
// every 256B message row straddled 5 cache lines instead of 4, which is
// exactly the observed k_agg FETCH_SIZE jump 88->122MB (+25% lines) and
// dur 43.2->45.4us. Fix: align xwb to 256B. Everything else byte-identical
// to R24 (16-dispatch graph, A-side BN in gemm4, single wconvAll, one
// memset).
// ---------------------------------------------------------------------------

static __device__ __forceinline__ ushort bf16_rne(float x) {
    uint u = __float_as_uint(x);
    return (ushort)((u + 0x7fffu + ((u >> 16) & 1u)) >> 16);
}
static __device__ __forceinline__ float bf16_f(ushort h) {
    return __uint_as_float(((uint)h) << 16);
}

// ---------------- bucket-sort CSR build ----------------
__global__ __launch_bounds__(256) void k_bcount(const int* __restrict__ dst, int e,
                                                int* __restrict__ bcntp) {
    __shared__ int h[512];
    int tid = threadIdx.x;
    h[tid] = 0;
    h[tid + 256] = 0;
    __syncthreads();
    int stride = gridDim.x * 256;
    for (int i = blockIdx.x * 256 + tid; i < e; i += stride)
        atomicAdd(&h[dst[i] >> 7], 1);
    __syncthreads();
    if (h[tid]) atomicAdd(&bcntp[tid * 16], h[tid]);
    if (h[tid + 256]) atomicAdd(&bcntp[(tid + 256) * 16], h[tid + 256]);
}

__global__ __launch_bounds__(512) void k_bscan(const int* __restrict__ bcntp,
                                               int* __restrict__ bbase,
                                               int* __restrict__ bcurp, int nb, int n,
                                               int total, int* __restrict__ row_start) {
    __shared__ int s[512];
    int tid = threadIdx.x;
    int v = 0;
    if (tid < nb) v = bcntp[tid * 16] + min(128, n - (tid << 7));  // + self-loops
    s[tid] = v;
    __syncthreads();
    for (int off = 1; off < 512; off <<= 1) {
        int t = (tid >= off) ? s[tid - off] : 0;
        __syncthreads();
        s[tid] += t;
        __syncthreads();
    }
    if (tid < nb) {
        int excl = s[tid] - v;
        bbase[tid] = excl;
        bcurp[tid * 16] = excl;
    }
    if (tid == 0) {
        bbase[nb] = total;
        row_start[n] = total;
    }
}

// multisplit: chunk of 8192 items -> LDS bucket-sort -> coalesced copy-out
__global__ __launch_bounds__(512) void k_bscatter(const int* __restrict__ src,
                                                  const int* __restrict__ dst, int e, int n,
                                                  int* __restrict__ bcurp,
                                                  int* __restrict__ pk) {
    __shared__ int hcnt[512], bstart[512], bcursor[512], gbase[512];
    __shared__ int stage[8192];
    int tid = threadIdx.x;
    int total = e + n;
    int nchunk = (total + 8191) >> 13;
    for (int c = blockIdx.x; c < nchunk; c += gridDim.x) {
        int base = c << 13;
        int cnt = min(8192, total - base);
        hcnt[tid] = 0;
        __syncthreads();
        for (int j = tid; j < cnt; j += 512) {
            int i = base + j;
            int d = (i < e) ? dst[i] : (i - e);
            atomicAdd(&hcnt[d >> 7], 1);
        }
        __syncthreads();
        int v = hcnt[tid];
        bstart[tid] = v;
        __syncthreads();
        for (int off = 1; off < 512; off <<= 1) {  // inclusive scan in-place
            int t = (tid >= off) ? bstart[tid - off] : 0;
            __syncthreads();
            bstart[tid] += t;
            __syncthreads();
        }
        int excl = bstart[tid] - v;
        __syncthreads();
        bstart[tid] = excl;
        bcursor[tid] = excl;
        if (v) gbase[tid] = atomicAdd(&bcurp[tid * 16], v);
        __syncthreads();
        for (int j = tid; j < cnt; j += 512) {
            int i = base + j;
            int d, sv;
            if (i < e) { d = dst[i]; sv = src[i]; }
            else       { d = i - e; sv = d; }
            uint b = (uint)(d >> 7);
            int r = atomicAdd(&bcursor[b], 1);
            stage[r] = (int)((b << 23) | ((uint)(d & 127) << 16) | (uint)sv);
        }
        __syncthreads();
        for (int j = tid; j < cnt; j += 512) {
            int p = stage[j];
            int b = (int)(((uint)p) >> 23);
            pk[gbase[b] + (j - bstart[b])] = p;   // coalesced runs per bucket
        }
        __syncthreads();
    }
}

// one block per bucket: local CSR entirely in LDS, coalesced global I/O
__global__ __launch_bounds__(256) void k_bfill(const int* __restrict__ pk,
                                               const int* __restrict__ bbase, int n,
                                               int* __restrict__ row_start,
                                               int* __restrict__ col) {
    int b = blockIdx.x;
    int s0 = bbase[b], s1 = bbase[b + 1];
    int seg = s1 - s0;
    int node0 = b << 7;
    int nn = min(128, n - node0);
    int tid = threadIdx.x;
    __shared__ int cnt[128], scn[128];
    __shared__ int colst[4608];
    if (tid < 128) cnt[tid] = 0;
    __syncthreads();
    for (int j = tid; j < seg; j += 256)
        atomicAdd(&cnt[(pk[s0 + j] >> 16) & 127], 1);
    __syncthreads();
    int myc = 0;
    if (tid < 128) { myc = cnt[tid]; scn[tid] = myc; }
    __syncthreads();
    for (int off = 1; off < 128; off <<= 1) {
        int t = (tid >= off && tid < 128) ? scn[tid - off] : 0;
        __syncthreads();
        if (tid < 128) scn[tid] += t;
        __syncthreads();
    }
    int excl = 0;
    if (tid < 128) excl = scn[tid] - myc;
    if (tid < nn) row_start[node0 + tid] = s0 + excl;
    __syncthreads();
    if (tid < 128) cnt[tid] = excl;   // becomes cursor
    __syncthreads();
    bool big = seg > 4608;            // fallback guard (never expected)
    for (int j = tid; j < seg; j += 256) {
        int p = pk[s0 + j];
        int r = atomicAdd(&cnt[(p >> 16) & 127], 1);
        if (big) col[s0 + r] = p & 0xffff;
        else colst[r] = p & 0xffff;
    }
    if (!big) {
        __syncthreads();
        for (int j = tid; j < seg; j += 256) col[s0 + j] = colst[j];
    }
}

// ---------------- W pre-conversion: all 3 layers in ONE launch --------------
typedef __attribute__((ext_vector_type(8))) short short8;
typedef __attribute__((ext_vector_type(4))) float float4v;

// Emit W fp32 [128][F] as bf16 hi/lo lane-major fragment blocks (R16 layout):
//   block (tg,ks): 64 lanes x short8; lane=quad*16+l15 holds column
//   n=tg*16+l15, k=ks*32+quad*8..+8. Pure conversion (no BN fold).
template <int F>
static __device__ __forceinline__ void wconv_emit(const float* __restrict__ W, int bb,
                                                  int tid, ushort* __restrict__ whi,
                                                  ushort* __restrict__ wlo) {
    int n = (bb * 256 + tid) >> 6;
    int lane = tid & 63;
    if (n >= F || lane >= 16) return;
    int ks = lane >> 2, quad = lane & 3;
    int tg = n >> 4, l15 = n & 15;
    long long off8 = ((long long)((tg * 4 + ks) * 64 + quad * 16 + l15)) * 8;
    short8 h8, l8;
#pragma unroll
    for (int j = 0; j < 8; j++) {
        int k = ks * 32 + quad * 8 + j;
        float w = W[k * F + n];
        ushort h = bf16_rne(w);
        h8[j] = (short)h;
        l8[j] = (short)bf16_rne(w - bf16_f(h));
    }
    *(short8*)(whi + off8) = h8;
    *(short8*)(wlo + off8) = l8;
}

__global__ __launch_bounds__(256) void k_wconvAll(const float* __restrict__ W1,
                                                  const float* __restrict__ W2,
                                                  const float* __restrict__ W3,
                                                  ushort* __restrict__ w1hi,
                                                  ushort* __restrict__ w1lo,
                                                  ushort* __restrict__ w2hi,
                                                  ushort* __restrict__ w2lo,
                                                  ushort* __restrict__ w3hi,
                                                  ushort* __restrict__ w3lo) {
    int b = blockIdx.x;
    int tid = threadIdx.x;
    if (b < 32) wconv_emit<128>(W1, b, tid, w1hi, w1lo);
    else if (b < 64) wconv_emit<128>(W2, b - 32, tid, w2hi, w2lo);
    else wconv_emit<64>(W3, b - 64, tid, w3hi, w3lo);
}

// ---- GEMM: BN_A(A)[M,128] @ Wfrag -> bf16 xwb + logits. -------------------
// BNA: LDS prologue computes sc/sh from raw stats (128ch sums/sumsq) + g/be;
// per k-step b = a*sc+sh applied BEFORE the bf16 split; BN'd values also
// stored to outp (half==0 waves, once per row) -- this IS the layer output.
static __device__ __forceinline__ void cvt8(const float4& f0, const float4& f1,
                                            short8& hi, short8& lo) {
#define CV8(i, val)                                        \
    {                                                      \
        ushort h_ = bf16_rne(val);                         \
        hi[i] = (short)h_;                                 \
        lo[i] = (short)bf16_rne((val)-bf16_f(h_));         \
    }
    CV8(0, f0.x) CV8(1, f0.y) CV8(2, f0.z) CV8(3, f0.w)
    CV8(4, f1.x) CV8(5, f1.y) CV8(6, f1.z) CV8(7, f1.w)
#undef CV8
}

template <int F, int H, bool BNA>
__global__ __launch_bounds__(256) void k_gemm4(const float* __restrict__ A,
                                               const ushort* __restrict__ whi,
                                               const ushort* __restrict__ wlo,
                                               const float* __restrict__ asrc,
                                               const float* __restrict__ adst,
                                               ushort* __restrict__ xwb,
                                               float* __restrict__ al_s,
                                               float* __restrict__ al_d,
                                               const float* __restrict__ stats,
                                               const float* __restrict__ g,
                                               const float* __restrict__ be,
                                               float invN,
                                               float* __restrict__ outp, int M) {
    constexpr bool SPLIT = (F == 128);          // split 8 col-tiles across wave pair
    constexpr int RPB = SPLIT ? 32 : 64;        // rows per block
    __shared__ float lsc[128], lsh[128];
    int tid = threadIdx.x;
    if (BNA) {
        if (tid < 128) {
            float mean = stats[tid] * invN;
            float var = stats[128 + tid] * invN - mean * mean;
            float s = g[tid] * rsqrtf(var + 1e-5f);
            lsc[tid] = s;
            lsh[tid] = be[tid] - mean * s;
        }
        __syncthreads();
    }
    int wave = tid >> 6, lane = tid & 63;
    int quad = lane >> 4, l15 = lane & 15;
    int rg = SPLIT ? (wave >> 1) : wave;
    int half = SPLIT ? (wave & 1) : 0;
    int base = blockIdx.x * RPB + rg * 16;
    int coff = half * 64;                       // this wave's column offset
    int tgb = SPLIT ? half * 4 : 0;             // global tile base

    float4v acc[4];
#pragma unroll
    for (int t = 0; t < 4; t++) acc[t] = (float4v){0.f, 0.f, 0.f, 0.f};

    int arow = base + l15;
    bool aval = (arow < M);
    const float* Ap = A + (long long)arow * 128;

#pragma unroll
    for (int ks = 0; ks < 4; ks++) {
        float4 f0 = {0.f, 0.f, 0.f, 0.f}, f1 = {0.f, 0.f, 0.f, 0.f};
        if (aval) {
            f0 = *(const float4*)(Ap + ks * 32 + quad * 8);
            f1 = *(const float4*)(Ap + ks * 32 + quad * 8 + 4);
        }
        if (BNA) {
            int kk = ks * 32 + quad * 8;
            f0.x = fmaf(f0.x, lsc[kk + 0], lsh[kk + 0]);
            f0.y = fmaf(f0.y, lsc[kk + 1], lsh[kk + 1]);
            f0.z = fmaf(f0.z, lsc[kk + 2], lsh[kk + 2]);
            f0.w = fmaf(f0.w, lsc[kk + 3], lsh[kk + 3]);
            f1.x = fmaf(f1.x, lsc[kk + 4], lsh[kk + 4]);
            f1.y = fmaf(f1.y, lsc[kk + 5], lsh[kk + 5]);
            f1.z = fmaf(f1.z, lsc[kk + 6], lsh[kk + 6]);
            f1.w = fmaf(f1.w, lsc[kk + 7], lsh[kk + 7]);
            if (aval && half == 0) {
                float* op = outp + (long long)arow * 320 + kk;
                *(float4*)op = f0;
                *(float4*)(op + 4) = f1;
            }
        }
        short8 ah, al;
        cvt8(f0, f1, ah, al);
#pragma unroll
        for (int t = 0; t < 4; t++) {
            // coalesced lane-major fragment block
            long long boff = ((long long)(((tgb + t) * 4 + ks) * 64 + lane)) * 8;
            short8 bh = *(const short8*)(whi + boff);
            short8 bl = *(const short8*)(wlo + boff);
            acc[t] = __builtin_amdgcn_mfma_f32_16x16x32_bf16(ah, bh, acc[t], 0, 0, 0);
            acc[t] = __builtin_amdgcn_mfma_f32_16x16x32_bf16(ah, bl, acc[t], 0, 0, 0);
            acc[t] = __builtin_amdgcn_mfma_f32_16x16x32_bf16(al, bh, acc[t], 0, 0, 0);
        }
    }

    // ---- epilogue: C[row=quad*4+r][col(tile)=l15], tile t -> col coff+t*16+l15
    float asl[4], adl[4];
#pragma unroll
    for (int t = 0; t < 4; t++) {
        int n = coff + t * 16 + l15;
        asl[t] = asrc[n];
        adl[t] = adst[n];
    }
#pragma unroll
    for (int r = 0; r < 4; r++) {
        int grow = base + quad * 4 + r;
        float v0 = acc[0][r];
        float v1 = acc[1][r];
        float v2 = acc[2][r];
        float v3 = acc[3][r];
        if (grow < M) {
            ushort* xp = xwb + (long long)grow * F + coff + l15;
            xp[0] = bf16_rne(v0);
            xp[16] = bf16_rne(v1);
            xp[32] = bf16_rne(v2);
            xp[48] = bf16_rne(v3);
        }
        float ps = 0.f, pd = 0.f;
        ps = fmaf(v0, asl[0], ps); pd = fmaf(v0, adl[0], pd);
        ps = fmaf(v1, asl[1], ps); pd = fmaf(v1, adl[1], pd);
        ps = fmaf(v2, asl[2], ps); pd = fmaf(v2, adl[2], pd);
        ps = fmaf(v3, asl[3], ps); pd = fmaf(v3, adl[3], pd);
#pragma unroll
        for (int off = 1; off < 16; off <<= 1) {
            ps += __shfl_xor(ps, off);
            pd += __shfl_xor(pd, off);
        }
        if (l15 == 0 && grow < M) {
            al_s[grow * H + half] = ps;
            al_d[grow * H + half] = pd;
        }
    }
}

// ---------------- per-dst-wave softmax aggregation (R18 verbatim) -----------
template <int F, int H>
__global__ __launch_bounds__(256) void k_agg(const uint* __restrict__ xwb,
                      const float* __restrict__ al_s,
                      const float* __restrict__ al_d, const int* __restrict__ row_start,
                      const int* __restrict__ col, const float* __restrict__ bias,
                      float* __restrict__ y, int n) {
    int wid = (blockIdx.x * blockDim.x + threadIdx.x) >> 6;  // one wave per dst
    int lane = threadIdx.x & 63;
    if (wid >= n) return;
    int beg = row_start[wid], end = row_start[wid + 1];

    float ald[H];
#pragma unroll
    for (int h = 0; h < H; h++) ald[h] = al_d[wid * H + h];

    if (end - beg <= 64) {
        // ---------------- fast path: one lane = one edge ----------------
        int nb = end - beg;
        int s_c = 0;
        float ev0 = -1e30f, ev1 = -1e30f;
        if (lane < nb) {
            s_c = col[beg + lane];
            if (H == 2) {
                float2 av = ((const float2*)al_s)[s_c];
                float e0 = av.x + ald[0];
                float e1 = av.y + ald[1];
                ev0 = (e0 >= 0.f) ? e0 : 0.2f * e0;
                ev1 = (e1 >= 0.f) ? e1 : 0.2f * e1;
            } else {
                float e0 = al_s[s_c] + ald[0];
                ev0 = (e0 >= 0.f) ? e0 : 0.2f * e0;
            }
        }
        // max butterfly
        float m0 = ev0, m1 = ev1;
#pragma unroll
        for (int off = 32; off; off >>= 1) {
            m0 = fmaxf(m0, __shfl_xor(m0, off));
            if (H == 2) m1 = fmaxf(m1, __shfl_xor(m1, off));
        }
        // exp once; sum butterfly; alpha free (0 for lanes >= nb)
        float x0 = (lane < nb) ? __expf(ev0 - m0) : 0.f;
        float x1 = (H == 2 && lane < nb) ? __expf(ev1 - m1) : 0.f;
        float l0 = x0, l1 = x1;
#pragma unroll
        for (int off = 32; off; off >>= 1) {
            l0 += __shfl_xor(l0, off);
            if (H == 2) l1 += __shfl_xor(l1, off);
        }
        float a0 = x0 / (l0 + 1e-16f);
        float a1 = (H == 2) ? x1 / (l1 + 1e-16f) : a0;

        // ---- accumulate: wide rows-per-load, 8 loads (4KB) in flight ----
        float accv0 = 0.f, accv1 = 0.f, accv2 = 0.f, accv3 = 0.f;
        const uint2* xw2 = (const uint2*)xwb;

        if (F == 128) {
            // lane covers cols 4*li..4*li+3 of rows for half = lane>>5
            int li = lane & 31;
            int half = lane >> 5;
            bool head0 = (li < 16);           // col<64 <=> li<16
            for (int j = 0; j < nb; j += 16) {
                int rr[8];
                float alq[8];
#pragma unroll
                for (int q = 0; q < 8; q++) {
                    int e = j + 2 * q + half;     // <= 63 since nb<=64
                    rr[q] = __shfl(s_c, e);
                    float aa = __shfl(a0, e);
                    float bb = __shfl(a1, e);
                    alq[q] = (H == 2) ? (head0 ? aa : bb) : aa;
                }
                uint2 uu[8];
#pragma unroll
                for (int q = 0; q < 8; q++)
                    uu[q] = xw2[(rr[q] << 5) + li];
#pragma unroll
                for (int q = 0; q < 8; q++) {
                    accv0 = fmaf(alq[q], __uint_as_float(uu[q].x << 16), accv0);
                    accv1 = fmaf(alq[q], __uint_as_float(uu[q].x & 0xffff0000u), accv1);
                    accv2 = fmaf(alq[q], __uint_as_float(uu[q].y << 16), accv2);
                    accv3 = fmaf(alq[q], __uint_as_float(uu[q].y & 0xffff0000u), accv3);
                }
            }
            // cross-half reduce: lane l and l^32 hold same cols
            accv0 += __shfl_xor(accv0, 32);
            accv1 += __shfl_xor(accv1, 32);
            accv2 += __shfl_xor(accv2, 32);
            accv3 += __shfl_xor(accv3, 32);
            if (li == lane) {  // lane < 32
                float4 o;
                o.x = fmaxf(accv0 + bias[4 * li + 0], 0.f);
                o.y = fmaxf(accv1 + bias[4 * li + 1], 0.f);
                o.z = fmaxf(accv2 + bias[4 * li + 2], 0.f);
                o.w = fmaxf(accv3 + bias[4 * li + 3], 0.f);
                ((float4*)y)[(long long)wid * 32 + li] = o;
            }
        } else {
            // F=64, H=1: lane covers cols 4*li..4*li+3, group g = lane>>4
            int li = lane & 15;
            int g = lane >> 4;
            for (int j = 0; j < nb; j += 32) {
                int rr[8];
                float alq[8];
#pragma unroll
                for (int q = 0; q < 8; q++) {
                    int e = j + 4 * q + g;        // <= 63 since nb<=64
                    rr[q] = __shfl(s_c, e);
                    alq[q] = __shfl(a0, e);
                }
                uint2 uu[8];
#pragma unroll
                for (int q = 0; q < 8; q++)
                    uu[q] = xw2[(rr[q] << 4) + li];
#pragma unroll
                for (int q = 0; q < 8; q++) {
                    accv0 = fmaf(alq[q], __uint_as_float(uu[q].x << 16), accv0);
                    accv1 = fmaf(alq[q], __uint_as_float(uu[q].x & 0xffff0000u), accv1);
                    accv2 = fmaf(alq[q], __uint_as_float(uu[q].y << 16), accv2);
                    accv3 = fmaf(alq[q], __uint_as_float(uu[q].y & 0xffff0000u), accv3);
                }
            }
            // reduce across 4 groups (lanes sharing li)
            accv0 += __shfl_xor(accv0, 16); accv0 += __shfl_xor(accv0, 32);
            accv1 += __shfl_xor(accv1, 16); accv1 += __shfl_xor(accv1, 32);
            accv2 += __shfl_xor(accv2, 16); accv2 += __shfl_xor(accv2, 32);
            accv3 += __shfl_xor(accv3, 16); accv3 += __shfl_xor(accv3, 32);
            if (lane < 16) {
                float4 o;
                o.x = fmaxf(accv0 + bias[4 * li + 0], 0.f);
                o.y = fmaxf(accv1 + bias[4 * li + 1], 0.f);
                o.z = fmaxf(accv2 + bias[4 * li + 2], 0.f);
                o.w = fmaxf(accv3 + bias[4 * li + 3], 0.f);
                ((float4*)y)[(long long)wid * 16 + li] = o;
            }
        }
        return;
    }

    // ---------------- generic path (deg > 64), original code ----------------
    float acc0 = 0.f, acc1 = 0.f;
    {
        float m[H], l[H];
#pragma unroll
        for (int h = 0; h < H; h++) {
            m[h] = -1e30f;
            l[h] = 0.f;
        }
        for (int e = beg + lane; e < end; e += 64) {
            int s = col[e];
#pragma unroll
            for (int h = 0; h < H; h++) {
                float ev = al_s[s * H + h] + ald[h];
                ev = (ev >= 0.f) ? ev : 0.2f * ev;
                if (ev > m[h]) {
                    l[h] = l[h] * __expf(m[h] - ev) + 1.f;
                    m[h] = ev;
                } else {
                    l[h] += __expf(ev - m[h]);
                }
            }
        }
#pragma unroll
        for (int off = 32; off; off >>= 1) {
#pragma unroll
            for (int h = 0; h < H; h++) {
                float mo = __shfl_xor(m[h], off);
                float lo = __shfl_xor(l[h], off);
                float mn = fmaxf(m[h], mo);
                l[h] = l[h] * __expf(m[h] - mn) + lo * __expf(mo - mn);
                m[h] = mn;
            }
        }
        float inv[H];
#pragma unroll
        for (int h = 0; h < H; h++) inv[h] = 1.f / (l[h] + 1e-16f);

        for (int base = beg; base < end; base += 64) {
            int nb = min(64, end - base);
            int ec = min(base + lane, end - 1);
            int s = col[ec];
            float a0, a1;
            {
                float av[H];
#pragma unroll
                for (int h = 0; h < H; h++) {
                    float ev = al_s[s * H + h] + ald[h];
                    ev = (ev >= 0.f) ? ev : 0.2f * ev;
                    av[h] = __expf(ev - m[h]) * inv[h];
                }
                a0 = av[0];
                a1 = av[H - 1];
            }
            int j = 0;
            for (; j + 4 <= nb; j += 4) {
                int s0 = __shfl(s, j + 0), s1 = __shfl(s, j + 1);
                int s2 = __shfl(s, j + 2), s3 = __shfl(s, j + 3);
                float q00 = __shfl(a0, j + 0), q01 = __shfl(a1, j + 0);
                float q10 = __shfl(a0, j + 1), q11 = __shfl(a1, j + 1);
                float q20 = __shfl(a0, j + 2), q21 = __shfl(a1, j + 2);
                float q30 = __shfl(a0, j + 3), q31 = __shfl(a1, j + 3);
                float p0, p1, p2, p3;
                if (H == 2) {
                    p0 = (lane < 32) ? q00 : q01;
                    p1 = (lane < 32) ? q10 : q11;
                    p2 = (lane < 32) ? q20 : q21;
                    p3 = (lane < 32) ? q30 : q31;
                } else {
                    p0 = q00; p1 = q10; p2 = q20; p3 = q30;
                }
                if (F == 128) {
                    uint u0 = xwb[(s0 << 6) + lane];
                    uint u1 = xwb[(s1 << 6) + lane];
                    uint u2 = xwb[(s2 << 6) + lane];
                    uint u3 = xwb[(s3 << 6) + lane];
                    acc0 = fmaf(p0, __uint_as_float(u0 << 16), acc0);
                    acc1 = fmaf(p0, __uint_as_float(u0 & 0xffff0000u), acc1);
                    acc0 = fmaf(p1, __uint_as_float(u1 << 16), acc0);
                    acc1 = fmaf(p1, __uint_as_float(u1 & 0xffff0000u), acc1);
                    acc0 = fmaf(p2, __uint_as_float(u2 << 16), acc0);
                    acc1 = fmaf(p2, __uint_as_float(u2 & 0xffff0000u), acc1);
                    acc0 = fmaf(p3, __uint_as_float(u3 << 16), acc0);
                    acc1 = fmaf(p3, __uint_as_float(u3 & 0xffff0000u), acc1);
                } else {
                    int idx = lane >> 1;
                    bool hi = (lane & 1) != 0;
                    uint u0 = xwb[(s0 << 5) + idx];
                    uint u1 = xwb[(s1 << 5) + idx];
                    uint u2 = xwb[(s2 << 5) + idx];
                    uint u3 = xwb[(s3 << 5) + idx];
                    acc0 = fmaf(p0, __uint_as_float(hi ? (u0 & 0xffff0000u) : (u0 << 16)), acc0);
                    acc0 = fmaf(p1, __uint_as_float(hi ? (u1 & 0xffff0000u) : (u1 << 16)), acc0);
                    acc0 = fmaf(p2, __uint_as_float(hi ? (u2 & 0xffff0000u) : (u2 << 16)), acc0);
                    acc0 = fmaf(p3, __uint_as_float(hi ? (u3 & 0xffff0000u) : (u3 << 16)), acc0);
                }
            }
            for (; j < nb; ++j) {
                int sj = __shfl(s, j);
                float q0 = __shfl(a0, j);
                float q1 = __shfl(a1, j);
                float alpha;
                if (H == 2) {
                    alpha = (lane < 32) ? q0 : q1;
                } else {
                    alpha = q0;
                }
                if (F == 128) {
                    uint u = xwb[(sj << 6) + lane];
                    acc0 = fmaf(alpha, __uint_as_float(u << 16), acc0);
                    acc1 = fmaf(alpha, __uint_as_float(u & 0xffff0000u), acc1);
                } else {
                    uint u = xwb[(sj << 5) + (lane >> 1)];
                    acc0 = fmaf(alpha, __uint_as_float((lane & 1) ? (u & 0xffff0000u) : (u << 16)), acc0);
                }
            }
        }
    }

    if (F == 128) {
        float2 o;
        o.x = fmaxf(acc0 + bias[2 * lane], 0.f);
        o.y = fmaxf(acc1 + bias[2 * lane + 1], 0.f);
        ((float2*)y)[(long long)wid * 64 + lane] = o;
    } else {
        y[(long long)wid * 64 + lane] = fmaxf(acc0 + bias[lane], 0.f);
    }
}

// ---------------- BatchNorm ----------------
template <int F>
__global__ void k_bn_stats(const float* __restrict__ y, float* __restrict__ sums, int n) {
    constexpr int C4 = F / 4;
    constexpr int NPB = 256 / C4;
    int c4 = threadIdx.x % C4;
    int sub = threadIdx.x / C4;
    float4 s = {0, 0, 0, 0}, s2 = {0, 0, 0, 0};
    for (int node = blockIdx.x * NPB + sub; node < n; node += gridDim.x * NPB) {
        float4 v = ((const float4*)y)[node * C4 + c4];
        s.x += v.x; s.y += v.y; s.z += v.z; s.w += v.w;
        s2.x += v.x * v.x; s2.y += v.y * v.y; s2.z += v.z * v.z; s2.w += v.w * v.w;
    }
    __shared__ float4 ls[256], ls2[256];
    ls[threadIdx.x] = s;
    ls2[threadIdx.x] = s2;
    __syncthreads();
    if (sub == 0) {
#pragma unroll
        for (int k = 1; k < NPB; k++) {
            float4 t = ls[c4 + k * C4], t2 = ls2[c4 + k * C4];
            s.x += t.x; s.y += t.y; s.z += t.z; s.w += t.w;
            s2.x += t2.x; s2.y += t2.y; s2.z += t2.z; s2.w += t2.w;
        }
        atomicAdd(&sums[c4 * 4 + 0], s.x);
        atomicAdd(&sums[c4 * 4 + 1], s.y);
        atomicAdd(&sums[c4 * 4 + 2], s.z);
        atomicAdd(&sums[c4 * 4 + 3], s.w);
        atomicAdd(&sums[F + c4 * 4 + 0], s2.x);
        atomicAdd(&sums[F + c4 * 4 + 1], s2.y);
        atomicAdd(&sums[F + c4 * 4 + 2], s2.z);
        atomicAdd(&sums[F + c4 * 4 + 3], s2.w);
    }
}

// BN apply for F=64 with in-kernel prep (reads stats directly)
__global__ void k_bn_apply64p(const float* __restrict__ y, const float* __restrict__ stats,
                              const float* __restrict__ g, const float* __restrict__ be,
                              float invN, float* __restrict__ outp, int n) {
    constexpr int C4 = 16;
    int t = blockIdx.x * blockDim.x + threadIdx.x;
    if (t >= n * C4) return;
    int node = t / C4, c4 = t % C4;
    float4 v = ((const float4*)y)[t];
    float4 o;
#pragma unroll
    for (int i = 0; i < 4; i++) {
        int ch = c4 * 4 + i;
        float mean = stats[ch] * invN;
        float var = stats[64 + ch] * invN - mean * mean;
        float s = g[ch] * rsqrtf(var + 1e-5f);
        float sh = be[ch] - mean * s;
        float vi = (i == 0) ? v.x : (i == 1) ? v.y : (i == 2) ? v.z : v.w;
        float oi = vi * s + sh;
        if (i == 0) o.x = oi;
        else if (i == 1) o.y = oi;
        else if (i == 2) o.z = oi;
        else o.w = oi;
    }
    ((float4*)(outp + (long long)node * 320))[c4] = o;
}

// ---------------------------------------------------------------------------
extern "C" void kernel_launch(void* const* d_in, const int* in_sizes, int n_in,
                              void* d_out, int out_size, void* d_ws, size_t ws_size,
                              hipStream_t stream) {
    const float* x   = (const float*)d_in[0];
    const int*   adj = (const int*)d_in[1];
    const float* W1  = (const float*)d_in[2];
    const float* as1 = (const float*)d_in[3];
    const float* ad1 = (const float*)d_in[4];
    const float* b1  = (const float*)d_in[5];
    const float* g1  = (const float*)d_in[6];
    const float* be1 = (const float*)d_in[7];
    const float* W2  = (const float*)d_in[8];
    const float* as2 = (const float*)d_in[9];
    const float* ad2 = (const float*)d_in[10];
    const float* b2  = (const float*)d_in[11];
    const float* g2  = (const float*)d_in[12];
    const float* be2 = (const float*)d_in[13];
    const float* W3  = (const float*)d_in[14];
    const float* as3 = (const float*)d_in[15];
    const float* ad3 = (const float*)d_in[16];
    const float* b3  = (const float*)d_in[17];
    const float* g3  = (const float*)d_in[18];
    const float* be3 = (const float*)d_in[19];
    float* out = (float*)d_out;

    const int N = in_sizes[0] / 128;
    const int E = in_sizes[1] / 2;

    // workspace (stats and bcntp contiguous -> one memset)
    float* ws    = (float*)d_ws;
    float* ybuf  = ws;                          // N*128
    float* al_s  = ybuf + (size_t)N * 128;      // N*2
    float* al_d  = al_s + (size_t)N * 2;        // N*2
    float* stats1 = al_d + (size_t)N * 2;       // 256
    float* stats2 = stats1 + 256;               // 256
    float* stats3 = stats2 + 256;               // 256
    int* bcntp     = (int*)(stats3 + 256);      // 512*16 (line-padded counts)
    int* bcurp     = bcntp + 8192;              // 512*16 (line-padded cursors)
    int* bbase     = bcurp + 8192;              // 513
    int* row_start = bbase + 513;               // N+1
    int* col       = row_start + (N + 1);       // E+N

    // xwb: 256B-ALIGNED (R25 fix -- misalignment cost +25% line fetches)
    uintptr_t xp = (uintptr_t)(col + (E + N));
    xp = (xp + 255) & ~(uintptr_t)255;
    uint* xwb = (uint*)xp;                      // N*64 uints (bf16x2)

    // pre-converted W (bf16 hi/lo fragment blocks), 256B-aligned
    uintptr_t wp = (uintptr_t)(xwb + (size_t)N * 64);
    wp = (wp + 255) & ~(uintptr_t)255;
    ushort* w1hi = (ushort*)wp;                 // 128*128
    ushort* w1lo = w1hi + 16384;
    ushort* w2hi = w1lo + 16384;
    ushort* w2lo = w2hi + 16384;
    ushort* w3hi = w2lo + 16384;                // 64*128
    ushort* w3lo = w3hi + 8192;

    // packed bucket-sorted edges alias ybuf (dead before k_agg L1 writes it)
    int* pk = (int*)ybuf;                       // E+N ints

    const int* esrc = adj;
    const int* edst = adj + E;

    const int B = 256;
    auto cdiv = [](int a, int b) { return (a + b - 1) / b; };

    // ---- ONE memset: stats (768 floats) + bcntp (8192 ints) contiguous ----
    hipMemsetAsync(stats1, 0, 768 * sizeof(float) + 8192 * sizeof(int), stream);

    // ---- all W conversions in one launch (stats-independent now) ----
    k_wconvAll<<<80, 256, 0, stream>>>(W1, W2, W3, w1hi, w1lo, w2hi, w2lo, w3hi, w3lo);

    // ---- CSR build: bucket counting sort ----
    const int NB = (N + 127) >> 7;              // buckets (needs N<=65536)
    k_bcount<<<128, 256, 0, stream>>>(edst, E, bcntp);
    k_bscan<<<1, 512, 0, stream>>>(bcntp, bbase, bcurp, NB, N, E + N, row_start);
    int nchunk = (E + N + 8191) >> 13;
    k_bscatter<<<nchunk, 512, 0, stream>>>(esrc, edst, E, N, bcurp, pk);
    k_bfill<<<NB, 256, 0, stream>>>(pk, bbase, N, row_start, col);

    const float invN = 1.f / (float)N;
    ushort* xwb_us = (ushort*)xwb;

    // ---- layer 1: 128 -> 128 (H=2), raw A ----
    k_gemm4<128, 2, false><<<cdiv(N, 32), B, 0, stream>>>(
        x, w1hi, w1lo, as1, ad1, xwb_us, al_s, al_d,
        nullptr, nullptr, nullptr, 0.f, nullptr, N);
    k_agg<128, 2><<<cdiv(N, 4), B, 0, stream>>>(xwb, al_s, al_d, row_start, col, b1, ybuf, N);
    k_bn_stats<128><<<256, B, 0, stream>>>(ybuf, stats1, N);

    // ---- layer 2: A-side BN1; gemm also emits out+0 = BN1(ybuf) ----
    k_gemm4<128, 2, true><<<cdiv(N, 32), B, 0, stream>>>(
        ybuf, w2hi, w2lo, as2, ad2, xwb_us, al_s, al_d,
        stats1, g1, be1, invN, out + 0, N);
    k_agg<128, 2><<<cdiv(N, 4), B, 0, stream>>>(xwb, al_s, al_d, row_start, col, b2, ybuf, N);
    k_bn_stats<128><<<256, B, 0, stream>>>(ybuf, stats2, N);

    // ---- layer 3: A-side BN2; gemm also emits out+128 = BN2(ybuf) ----
    k_gemm4<64, 1, true><<<cdiv(N, 64), B, 0, stream>>>(
        ybuf, w3hi, w3lo, as3, ad3, xwb_us, al_s, al_d,
        stats2, g2, be2, invN, out + 128, N);
    k_agg<64, 1><<<cdiv(N, 4), B, 0, stream>>>(xwb, al_s, al_d, row_start, col, b3, ybuf, N);
    k_bn_stats<64><<<256, B, 0, stream>>>(ybuf, stats3, N);
    k_bn_apply64p<<<cdiv(N * 16, B), B, 0, stream>>>(ybuf, stats3, g3, be3, invN,
                                                     out + 256, N);
}

// Round 18
// 413.137 us; speedup vs baseline: 1.2189x; 1.0007x over previous
//
#include <hip/hip_runtime.h>

typedef unsigned int uint;
typedef unsigned short ushort;

// ---------------------------------------------------------------------------
// GAT x3 + ReLU + BatchNorm, MI355X.
// R26 change (single theory): de-SPLIT k_gemm4 for F=128. The SPLIT wave
// pairs each loaded + bf16-converted the SAME 16 A-rows (2x A-traffic,
// 2x cvt VALU). Now one wave owns 16 rows x all F cols (NT=F/16 tiles,
// acc 8xfloat4=32 VGPR at F=128), grid cdiv(N,64)=782. Logits: tiles
// 0..NT/2-1 -> head0, rest -> head1 (R1-verified mapping); fused BN
// out-store once per row (half guard gone). B-traffic/MFMA count same.
// k_agg (R18 local optimum) / bn_stats / CSR / wconvAll / alignment (R25)
// byte-identical to R25 (413us verified best).
// ---------------------------------------------------------------------------

static __device__ __forceinline__ ushort bf16_rne(float x) {
    uint u = __float_as_uint(x);
    return (ushort)((u + 0x7fffu + ((u >> 16) & 1u)) >> 16);
}
static __device__ __forceinline__ float bf16_f(ushort h) {
    return __uint_as_float(((uint)h) << 16);
}

// ---------------- bucket-sort CSR build ----------------
__global__ __launch_bounds__(256) void k_bcount(const int* __restrict__ dst, int e,
                                                int* __restrict__ bcntp) {
    __shared__ int h[512];
    int tid = threadIdx.x;
    h[tid] = 0;
    h[tid + 256] = 0;
    __syncthreads();
    int stride = gridDim.x * 256;
    for (int i = blockIdx.x * 256 + tid; i < e; i += stride)
        atomicAdd(&h[dst[i] >> 7], 1);
    __syncthreads();
    if (h[tid]) atomicAdd(&bcntp[tid * 16], h[tid]);
    if (h[tid + 256]) atomicAdd(&bcntp[(tid + 256) * 16], h[tid + 256]);
}

__global__ __launch_bounds__(512) void k_bscan(const int* __restrict__ bcntp,
                                               int* __restrict__ bbase,
                                               int* __restrict__ bcurp, int nb, int n,
                                               int total, int* __restrict__ row_start) {
    __shared__ int s[512];
    int tid = threadIdx.x;
    int v = 0;
    if (tid < nb) v = bcntp[tid * 16] + min(128, n - (tid << 7));  // + self-loops
    s[tid] = v;
    __syncthreads();
    for (int off = 1; off < 512; off <<= 1) {
        int t = (tid >= off) ? s[tid - off] : 0;
        __syncthreads();
        s[tid] += t;
        __syncthreads();
    }
    if (tid < nb) {
        int excl = s[tid] - v;
        bbase[tid] = excl;
        bcurp[tid * 16] = excl;
    }
    if (tid == 0) {
        bbase[nb] = total;
        row_start[n] = total;
    }
}

// multisplit: chunk of 8192 items -> LDS bucket-sort -> coalesced copy-out
__global__ __launch_bounds__(512) void k_bscatter(const int* __restrict__ src,
                                                  const int* __restrict__ dst, int e, int n,
                                                  int* __restrict__ bcurp,
                                                  int* __restrict__ pk) {
    __shared__ int hcnt[512], bstart[512], bcursor[512], gbase[512];
    __shared__ int stage[8192];
    int tid = threadIdx.x;
    int total = e + n;
    int nchunk = (total + 8191) >> 13;
    for (int c = blockIdx.x; c < nchunk; c += gridDim.x) {
        int base = c << 13;
        int cnt = min(8192, total - base);
        hcnt[tid] = 0;
        __syncthreads();
        for (int j = tid; j < cnt; j += 512) {
            int i = base + j;
            int d = (i < e) ? dst[i] : (i - e);
            atomicAdd(&hcnt[d >> 7], 1);
        }
        __syncthreads();
        int v = hcnt[tid];
        bstart[tid] = v;
        __syncthreads();
        for (int off = 1; off < 512; off <<= 1) {  // inclusive scan in-place
            int t = (tid >= off) ? bstart[tid - off] : 0;
            __syncthreads();
            bstart[tid] += t;
            __syncthreads();
        }
        int excl = bstart[tid] - v;
        __syncthreads();
        bstart[tid] = excl;
        bcursor[tid] = excl;
        if (v) gbase[tid] = atomicAdd(&bcurp[tid * 16], v);
        __syncthreads();
        for (int j = tid; j < cnt; j += 512) {
            int i = base + j;
            int d, sv;
            if (i < e) { d = dst[i]; sv = src[i]; }
            else       { d = i - e; sv = d; }
            uint b = (uint)(d >> 7);
            int r = atomicAdd(&bcursor[b], 1);
            stage[r] = (int)((b << 23) | ((uint)(d & 127) << 16) | (uint)sv);
        }
        __syncthreads();
        for (int j = tid; j < cnt; j += 512) {
            int p = stage[j];
            int b = (int)(((uint)p) >> 23);
            pk[gbase[b] + (j - bstart[b])] = p;   // coalesced runs per bucket
        }
        __syncthreads();
    }
}

// one block per bucket: local CSR entirely in LDS, coalesced global I/O
__global__ __launch_bounds__(256) void k_bfill(const int* __restrict__ pk,
                                               const int* __restrict__ bbase, int n,
                                               int* __restrict__ row_start,
                                               int* __restrict__ col) {
    int b = blockIdx.x;
    int s0 = bbase[b], s1 = bbase[b + 1];
    int seg = s1 - s0;
    int node0 = b << 7;
    int nn = min(128, n - node0);
    int tid = threadIdx.x;
    __shared__ int cnt[128], scn[128];
    __shared__ int colst[4608];
    if (tid < 128) cnt[tid] = 0;
    __syncthreads();
    for (int j = tid; j < seg; j += 256)
        atomicAdd(&cnt[(pk[s0 + j] >> 16) & 127], 1);
    __syncthreads();
    int myc = 0;
    if (tid < 128) { myc = cnt[tid]; scn[tid] = myc; }
    __syncthreads();
    for (int off = 1; off < 128; off <<= 1) {
        int t = (tid >= off && tid < 128) ? scn[tid - off] : 0;
        __syncthreads();
        if (tid < 128) scn[tid] += t;
        __syncthreads();
    }
    int excl = 0;
    if (tid < 128) excl = scn[tid] - myc;
    if (tid < nn) row_start[node0 + tid] = s0 + excl;
    __syncthreads();
    if (tid < 128) cnt[tid] = excl;   // becomes cursor
    __syncthreads();
    bool big = seg > 4608;            // fallback guard (never expected)
    for (int j = tid; j < seg; j += 256) {
        int p = pk[s0 + j];
        int r = atomicAdd(&cnt[(p >> 16) & 127], 1);
        if (big) col[s0 + r] = p & 0xffff;
        else colst[r] = p & 0xffff;
    }
    if (!big) {
        __syncthreads();
        for (int j = tid; j < seg; j += 256) col[s0 + j] = colst[j];
    }
}

// ---------------- W pre-conversion: all 3 layers in ONE launch --------------
typedef __attribute__((ext_vector_type(8))) short short8;
typedef __attribute__((ext_vector_type(4))) float float4v;

// Emit W fp32 [128][F] as bf16 hi/lo lane-major fragment blocks (R16 layout):
//   block (tg,ks): 64 lanes x short8; lane=quad*16+l15 holds column
//   n=tg*16+l15, k=ks*32+quad*8..+8. Pure conversion (no BN fold).
template <int F>
static __device__ __forceinline__ void wconv_emit(const float* __restrict__ W, int bb,
                                                  int tid, ushort* __restrict__ whi,
                                                  ushort* __restrict__ wlo) {
    int n = (bb * 256 + tid) >> 6;
    int lane = tid & 63;
    if (n >= F || lane >= 16) return;
    int ks = lane >> 2, quad = lane & 3;
    int tg = n >> 4, l15 = n & 15;
    long long off8 = ((long long)((tg * 4 + ks) * 64 + quad * 16 + l15)) * 8;
    short8 h8, l8;
#pragma unroll
    for (int j = 0; j < 8; j++) {
        int k = ks * 32 + quad * 8 + j;
        float w = W[k * F + n];
        ushort h = bf16_rne(w);
        h8[j] = (short)h;
        l8[j] = (short)bf16_rne(w - bf16_f(h));
    }
    *(short8*)(whi + off8) = h8;
    *(short8*)(wlo + off8) = l8;
}

__global__ __launch_bounds__(256) void k_wconvAll(const float* __restrict__ W1,
                                                  const float* __restrict__ W2,
                                                  const float* __restrict__ W3,
                                                  ushort* __restrict__ w1hi,
                                                  ushort* __restrict__ w1lo,
                                                  ushort* __restrict__ w2hi,
                                                  ushort* __restrict__ w2lo,
                                                  ushort* __restrict__ w3hi,
                                                  ushort* __restrict__ w3lo) {
    int b = blockIdx.x;
    int tid = threadIdx.x;
    if (b < 32) wconv_emit<128>(W1, b, tid, w1hi, w1lo);
    else if (b < 64) wconv_emit<128>(W2, b - 32, tid, w2hi, w2lo);
    else wconv_emit<64>(W3, b - 64, tid, w3hi, w3lo);
}

// ---- GEMM: BN_A(A)[M,128] @ Wfrag -> bf16 xwb + logits. Non-SPLIT. --------
// One wave owns 16 rows x F cols. BNA: LDS prologue computes sc/sh from raw
// stats; per k-step b=a*sc+sh BEFORE the bf16 split; BN'd values stored to
// outp once per row (this IS the previous layer's output).
static __device__ __forceinline__ void cvt8(const float4& f0, const float4& f1,
                                            short8& hi, short8& lo) {
#define CV8(i, val)                                        \
    {                                                      \
        ushort h_ = bf16_rne(val);                         \
        hi[i] = (short)h_;                                 \
        lo[i] = (short)bf16_rne((val)-bf16_f(h_));         \
    }
    CV8(0, f0.x) CV8(1, f0.y) CV8(2, f0.z) CV8(3, f0.w)
    CV8(4, f1.x) CV8(5, f1.y) CV8(6, f1.z) CV8(7, f1.w)
#undef CV8
}

template <int F, int H, bool BNA>
__global__ __launch_bounds__(256) void k_gemm5(const float* __restrict__ A,
                                               const ushort* __restrict__ whi,
                                               const ushort* __restrict__ wlo,
                                               const float* __restrict__ asrc,
                                               const float* __restrict__ adst,
                                               ushort* __restrict__ xwb,
                                               float* __restrict__ al_s,
                                               float* __restrict__ al_d,
                                               const float* __restrict__ stats,
                                               const float* __restrict__ g,
                                               const float* __restrict__ be,
                                               float invN,
                                               float* __restrict__ outp, int M) {
    constexpr int NT = F / 16;                  // 8 (F=128) or 4 (F=64) tiles
    __shared__ float lsc[128], lsh[128];
    int tid = threadIdx.x;
    if (BNA) {
        if (tid < 128) {
            float mean = stats[tid] * invN;
            float var = stats[128 + tid] * invN - mean * mean;
            float s = g[tid] * rsqrtf(var + 1e-5f);
            lsc[tid] = s;
            lsh[tid] = be[tid] - mean * s;
        }
        __syncthreads();
    }
    int wave = tid >> 6, lane = tid & 63;
    int quad = lane >> 4, l15 = lane & 15;
    int base = blockIdx.x * 64 + wave * 16;

    float4v acc[NT];
#pragma unroll
    for (int t = 0; t < NT; t++) acc[t] = (float4v){0.f, 0.f, 0.f, 0.f};

    int arow = base + l15;
    bool aval = (arow < M);
    const float* Ap = A + (long long)arow * 128;

#pragma unroll
    for (int ks = 0; ks < 4; ks++) {
        float4 f0 = {0.f, 0.f, 0.f, 0.f}, f1 = {0.f, 0.f, 0.f, 0.f};
        if (aval) {
            f0 = *(const float4*)(Ap + ks * 32 + quad * 8);
            f1 = *(const float4*)(Ap + ks * 32 + quad * 8 + 4);
        }
        if (BNA) {
            int kk = ks * 32 + quad * 8;
            f0.x = fmaf(f0.x, lsc[kk + 0], lsh[kk + 0]);
            f0.y = fmaf(f0.y, lsc[kk + 1], lsh[kk + 1]);
            f0.z = fmaf(f0.z, lsc[kk + 2], lsh[kk + 2]);
            f0.w = fmaf(f0.w, lsc[kk + 3], lsh[kk + 3]);
            f1.x = fmaf(f1.x, lsc[kk + 4], lsh[kk + 4]);
            f1.y = fmaf(f1.y, lsc[kk + 5], lsh[kk + 5]);
            f1.z = fmaf(f1.z, lsc[kk + 6], lsh[kk + 6]);
            f1.w = fmaf(f1.w, lsc[kk + 7], lsh[kk + 7]);
            if (aval) {
                float* op = outp + (long long)arow * 320 + ks * 32 + quad * 8;
                *(float4*)op = f0;
                *(float4*)(op + 4) = f1;
            }
        }
        short8 ah, al;
        cvt8(f0, f1, ah, al);
#pragma unroll
        for (int t = 0; t < NT; t++) {
            // coalesced lane-major fragment block
            long long boff = ((long long)((t * 4 + ks) * 64 + lane)) * 8;
            short8 bh = *(const short8*)(whi + boff);
            short8 bl = *(const short8*)(wlo + boff);
            acc[t] = __builtin_amdgcn_mfma_f32_16x16x32_bf16(ah, bh, acc[t], 0, 0, 0);
            acc[t] = __builtin_amdgcn_mfma_f32_16x16x32_bf16(ah, bl, acc[t], 0, 0, 0);
            acc[t] = __builtin_amdgcn_mfma_f32_16x16x32_bf16(al, bh, acc[t], 0, 0, 0);
        }
    }

    // ---- epilogue: C[row=quad*4+r][col=t*16+l15] ----
    float asl[NT], adl[NT];
#pragma unroll
    for (int t = 0; t < NT; t++) {
        asl[t] = asrc[t * 16 + l15];
        adl[t] = adst[t * 16 + l15];
    }
#pragma unroll
    for (int r = 0; r < 4; r++) {
        int grow = base + quad * 4 + r;
        if (grow < M) {
            ushort* xp = xwb + (long long)grow * F + l15;
#pragma unroll
            for (int t = 0; t < NT; t++) xp[t * 16] = bf16_rne(acc[t][r]);
        }
        float ps0 = 0.f, pd0 = 0.f, ps1 = 0.f, pd1 = 0.f;
#pragma unroll
        for (int t = 0; t < NT; t++) {
            float v = acc[t][r];
            if (H == 2 && t >= NT / 2) {
                ps1 = fmaf(v, asl[t], ps1);
                pd1 = fmaf(v, adl[t], pd1);
            } else {
                ps0 = fmaf(v, asl[t], ps0);
                pd0 = fmaf(v, adl[t], pd0);
            }
        }
#pragma unroll
        for (int off = 1; off < 16; off <<= 1) {
            ps0 += __shfl_xor(ps0, off);
            pd0 += __shfl_xor(pd0, off);
            if (H == 2) {
                ps1 += __shfl_xor(ps1, off);
                pd1 += __shfl_xor(pd1, off);
            }
        }
        if (l15 == 0 && grow < M) {
            al_s[grow * H + 0] = ps0;
            al_d[grow * H + 0] = pd0;
            if (H == 2) {
                al_s[grow * H + 1] = ps1;
                al_d[grow * H + 1] = pd1;
            }
        }
    }
}

// ---------------- per-dst-wave softmax aggregation (R18 verbatim) -----------
template <int F, int H>
__global__ __launch_bounds__(256) void k_agg(const uint* __restrict__ xwb,
                      const float* __restrict__ al_s,
                      const float* __restrict__ al_d, const int* __restrict__ row_start,
                      const int* __restrict__ col, const float* __restrict__ bias,
                      float* __restrict__ y, int n) {
    int wid = (blockIdx.x * blockDim.x + threadIdx.x) >> 6;  // one wave per dst
    int lane = threadIdx.x & 63;
    if (wid >= n) return;
    int beg = row_start[wid], end = row_start[wid + 1];

    float ald[H];
#pragma unroll
    for (int h = 0; h < H; h++) ald[h] = al_d[wid * H + h];

    if (end - beg <= 64) {
        // ---------------- fast path: one lane = one edge ----------------
        int nb = end - beg;
        int s_c = 0;
        float ev0 = -1e30f, ev1 = -1e30f;
        if (lane < nb) {
            s_c = col[beg + lane];
            if (H == 2) {
                float2 av = ((const float2*)al_s)[s_c];
                float e0 = av.x + ald[0];
                float e1 = av.y + ald[1];
                ev0 = (e0 >= 0.f) ? e0 : 0.2f * e0;
                ev1 = (e1 >= 0.f) ? e1 : 0.2f * e1;
            } else {
                float e0 = al_s[s_c] + ald[0];
                ev0 = (e0 >= 0.f) ? e0 : 0.2f * e0;
            }
        }
        // max butterfly
        float m0 = ev0, m1 = ev1;
#pragma unroll
        for (int off = 32; off; off >>= 1) {
            m0 = fmaxf(m0, __shfl_xor(m0, off));
            if (H == 2) m1 = fmaxf(m1, __shfl_xor(m1, off));
        }
        // exp once; sum butterfly; alpha free (0 for lanes >= nb)
        float x0 = (lane < nb) ? __expf(ev0 - m0) : 0.f;
        float x1 = (H == 2 && lane < nb) ? __expf(ev1 - m1) : 0.f;
        float l0 = x0, l1 = x1;
#pragma unroll
        for (int off = 32; off; off >>= 1) {
            l0 += __shfl_xor(l0, off);
            if (H == 2) l1 += __shfl_xor(l1, off);
        }
        float a0 = x0 / (l0 + 1e-16f);
        float a1 = (H == 2) ? x1 / (l1 + 1e-16f) : a0;

        // ---- accumulate: wide rows-per-load, 8 loads (4KB) in flight ----
        float accv0 = 0.f, accv1 = 0.f, accv2 = 0.f, accv3 = 0.f;
        const uint2* xw2 = (const uint2*)xwb;

        if (F == 128) {
            // lane covers cols 4*li..4*li+3 of rows for half = lane>>5
            int li = lane & 31;
            int half = lane >> 5;
            bool head0 = (li < 16);           // col<64 <=> li<16
            for (int j = 0; j < nb; j += 16) {
                int rr[8];
                float alq[8];
#pragma unroll
                for (int q = 0; q < 8; q++) {
                    int e = j + 2 * q + half;     // <= 63 since nb<=64
                    rr[q] = __shfl(s_c, e);
                    float aa = __shfl(a0, e);
                    float bb = __shfl(a1, e);
                    alq[q] = (H == 2) ? (head0 ? aa : bb) : aa;
                }
                uint2 uu[8];
#pragma unroll
                for (int q = 0; q < 8; q++)
                    uu[q] = xw2[(rr[q] << 5) + li];
#pragma unroll
                for (int q = 0; q < 8; q++) {
                    accv0 = fmaf(alq[q], __uint_as_float(uu[q].x << 16), accv0);
                    accv1 = fmaf(alq[q], __uint_as_float(uu[q].x & 0xffff0000u), accv1);
                    accv2 = fmaf(alq[q], __uint_as_float(uu[q].y << 16), accv2);
                    accv3 = fmaf(alq[q], __uint_as_float(uu[q].y & 0xffff0000u), accv3);
                }
            }
            // cross-half reduce: lane l and l^32 hold same cols
            accv0 += __shfl_xor(accv0, 32);
            accv1 += __shfl_xor(accv1, 32);
            accv2 += __shfl_xor(accv2, 32);
            accv3 += __shfl_xor(accv3, 32);
            if (li == lane) {  // lane < 32
                float4 o;
                o.x = fmaxf(accv0 + bias[4 * li + 0], 0.f);
                o.y = fmaxf(accv1 + bias[4 * li + 1], 0.f);
                o.z = fmaxf(accv2 + bias[4 * li + 2], 0.f);
                o.w = fmaxf(accv3 + bias[4 * li + 3], 0.f);
                ((float4*)y)[(long long)wid * 32 + li] = o;
            }
        } else {
            // F=64, H=1: lane covers cols 4*li..4*li+3, group g = lane>>4
            int li = lane & 15;
            int g = lane >> 4;
            for (int j = 0; j < nb; j += 32) {
                int rr[8];
                float alq[8];
#pragma unroll
                for (int q = 0; q < 8; q++) {
                    int e = j + 4 * q + g;        // <= 63 since nb<=64
                    rr[q] = __shfl(s_c, e);
                    alq[q] = __shfl(a0, e);
                }
                uint2 uu[8];
#pragma unroll
                for (int q = 0; q < 8; q++)
                    uu[q] = xw2[(rr[q] << 4) + li];
#pragma unroll
                for (int q = 0; q < 8; q++) {
                    accv0 = fmaf(alq[q], __uint_as_float(uu[q].x << 16), accv0);
                    accv1 = fmaf(alq[q], __uint_as_float(uu[q].x & 0xffff0000u), accv1);
                    accv2 = fmaf(alq[q], __uint_as_float(uu[q].y << 16), accv2);
                    accv3 = fmaf(alq[q], __uint_as_float(uu[q].y & 0xffff0000u), accv3);
                }
            }
            // reduce across 4 groups (lanes sharing li)
            accv0 += __shfl_xor(accv0, 16); accv0 += __shfl_xor(accv0, 32);
            accv1 += __shfl_xor(accv1, 16); accv1 += __shfl_xor(accv1, 32);
            accv2 += __shfl_xor(accv2, 16); accv2 += __shfl_xor(accv2, 32);
            accv3 += __shfl_xor(accv3, 16); accv3 += __shfl_xor(accv3, 32);
            if (lane < 16) {
                float4 o;
                o.x = fmaxf(accv0 + bias[4 * li + 0], 0.f);
                o.y = fmaxf(accv1 + bias[4 * li + 1], 0.f);
                o.z = fmaxf(accv2 + bias[4 * li + 2], 0.f);
                o.w = fmaxf(accv3 + bias[4 * li + 3], 0.f);
                ((float4*)y)[(long long)wid * 16 + li] = o;
            }
        }
        return;
    }

    // ---------------- generic path (deg > 64), original code ----------------
    float acc0 = 0.f, acc1 = 0.f;
    {
        float m[H], l[H];
#pragma unroll
        for (int h = 0; h < H; h++) {
            m[h] = -1e30f;
            l[h] = 0.f;
        }
        for (int e = beg + lane; e < end; e += 64) {
            int s = col[e];
#pragma unroll
            for (int h = 0; h < H; h++) {
                float ev = al_s[s * H + h] + ald[h];
                ev = (ev >= 0.f) ? ev : 0.2f * ev;
                if (ev > m[h]) {
                    l[h] = l[h] * __expf(m[h] - ev) + 1.f;
                    m[h] = ev;
                } else {
                    l[h] += __expf(ev - m[h]);
                }
            }
        }
#pragma unroll
        for (int off = 32; off; off >>= 1) {
#pragma unroll
            for (int h = 0; h < H; h++) {
                float mo = __shfl_xor(m[h], off);
                float lo = __shfl_xor(l[h], off);
                float mn = fmaxf(m[h], mo);
                l[h] = l[h] * __expf(m[h] - mn) + lo * __expf(mo - mn);
                m[h] = mn;
            }
        }
        float inv[H];
#pragma unroll
        for (int h = 0; h < H; h++) inv[h] = 1.f / (l[h] + 1e-16f);

        for (int base = beg; base < end; base += 64) {
            int nb = min(64, end - base);
            int ec = min(base + lane, end - 1);
            int s = col[ec];
            float a0, a1;
            {
                float av[H];
#pragma unroll
                for (int h = 0; h < H; h++) {
                    float ev = al_s[s * H + h] + ald[h];
                    ev = (ev >= 0.f) ? ev : 0.2f * ev;
                    av[h] = __expf(ev - m[h]) * inv[h];
                }
                a0 = av[0];
                a1 = av[H - 1];
            }
            int j = 0;
            for (; j + 4 <= nb; j += 4) {
                int s0 = __shfl(s, j + 0), s1 = __shfl(s, j + 1);
                int s2 = __shfl(s, j + 2), s3 = __shfl(s, j + 3);
                float q00 = __shfl(a0, j + 0), q01 = __shfl(a1, j + 0);
                float q10 = __shfl(a0, j + 1), q11 = __shfl(a1, j + 1);
                float q20 = __shfl(a0, j + 2), q21 = __shfl(a1, j + 2);
                float q30 = __shfl(a0, j + 3), q31 = __shfl(a1, j + 3);
                float p0, p1, p2, p3;
                if (H == 2) {
                    p0 = (lane < 32) ? q00 : q01;
                    p1 = (lane < 32) ? q10 : q11;
                    p2 = (lane < 32) ? q20 : q21;
                    p3 = (lane < 32) ? q30 : q31;
                } else {
                    p0 = q00; p1 = q10; p2 = q20; p3 = q30;
                }
                if (F == 128) {
                    uint u0 = xwb[(s0 << 6) + lane];
                    uint u1 = xwb[(s1 << 6) + lane];
                    uint u2 = xwb[(s2 << 6) + lane];
                    uint u3 = xwb[(s3 << 6) + lane];
                    acc0 = fmaf(p0, __uint_as_float(u0 << 16), acc0);
                    acc1 = fmaf(p0, __uint_as_float(u0 & 0xffff0000u), acc1);
                    acc0 = fmaf(p1, __uint_as_float(u1 << 16), acc0);
                    acc1 = fmaf(p1, __uint_as_float(u1 & 0xffff0000u), acc1);
                    acc0 = fmaf(p2, __uint_as_float(u2 << 16), acc0);
                    acc1 = fmaf(p2, __uint_as_float(u2 & 0xffff0000u), acc1);
                    acc0 = fmaf(p3, __uint_as_float(u3 << 16), acc0);
                    acc1 = fmaf(p3, __uint_as_float(u3 & 0xffff0000u), acc1);
                } else {
                    int idx = lane >> 1;
                    bool hi = (lane & 1) != 0;
                    uint u0 = xwb[(s0 << 5) + idx];
                    uint u1 = xwb[(s1 << 5) + idx];
                    uint u2 = xwb[(s2 << 5) + idx];
                    uint u3 = xwb[(s3 << 5) + idx];
                    acc0 = fmaf(p0, __uint_as_float(hi ? (u0 & 0xffff0000u) : (u0 << 16)), acc0);
                    acc0 = fmaf(p1, __uint_as_float(hi ? (u1 & 0xffff0000u) : (u1 << 16)), acc0);
                    acc0 = fmaf(p2, __uint_as_float(hi ? (u2 & 0xffff0000u) : (u2 << 16)), acc0);
                    acc0 = fmaf(p3, __uint_as_float(hi ? (u3 & 0xffff0000u) : (u3 << 16)), acc0);
                }
            }
            for (; j < nb; ++j) {
                int sj = __shfl(s, j);
                float q0 = __shfl(a0, j);
                float q1 = __shfl(a1, j);
                float alpha;
                if (H == 2) {
                    alpha = (lane < 32) ? q0 : q1;
                } else {
                    alpha = q0;
                }
                if (F == 128) {
                    uint u = xwb[(sj << 6) + lane];
                    acc0 = fmaf(alpha, __uint_as_float(u << 16), acc0);
                    acc1 = fmaf(alpha, __uint_as_float(u & 0xffff0000u), acc1);
                } else {
                    uint u = xwb[(sj << 5) + (lane >> 1)];
                    acc0 = fmaf(alpha, __uint_as_float((lane & 1) ? (u & 0xffff0000u) : (u << 16)), acc0);
                }
            }
        }
    }

    if (F == 128) {
        float2 o;
        o.x = fmaxf(acc0 + bias[2 * lane], 0.f);
        o.y = fmaxf(acc1 + bias[2 * lane + 1], 0.f);
        ((float2*)y)[(long long)wid * 64 + lane] = o;
    } else {
        y[(long long)wid * 64 + lane] = fmaxf(acc0 + bias[lane], 0.f);
    }
}

// ---------------- BatchNorm ----------------
template <int F>
__global__ void k_bn_stats(const float* __restrict__ y, float* __restrict__ sums, int n) {
    constexpr int C4 = F / 4;
    constexpr int NPB = 256 / C4;
    int c4 = threadIdx.x % C4;
    int sub = threadIdx.x / C4;
    float4 s = {0, 0, 0, 0}, s2 = {0, 0, 0, 0};
    for (int node = blockIdx.x * NPB + sub; node < n; node += gridDim.x * NPB) {
        float4 v = ((const float4*)y)[node * C4 + c4];
        s.x += v.x; s.y += v.y; s.z += v.z; s.w += v.w;
        s2.x += v.x * v.x; s2.y += v.y * v.y; s2.z += v.z * v.z; s2.w += v.w * v.w;
    }
    __shared__ float4 ls[256], ls2[256];
    ls[threadIdx.x] = s;
    ls2[threadIdx.x] = s2;
    __syncthreads();
    if (sub == 0) {
#pragma unroll
        for (int k = 1; k < NPB; k++) {
            float4 t = ls[c4 + k * C4], t2 = ls2[c4 + k * C4];
            s.x += t.x; s.y += t.y; s.z += t.z; s.w += t.w;
            s2.x += t2.x; s2.y += t2.y; s2.z += t2.z; s2.w += t2.w;
        }
        atomicAdd(&sums[c4 * 4 + 0], s.x);
        atomicAdd(&sums[c4 * 4 + 1], s.y);
        atomicAdd(&sums[c4 * 4 + 2], s.z);
        atomicAdd(&sums[c4 * 4 + 3], s.w);
        atomicAdd(&sums[F + c4 * 4 + 0], s2.x);
        atomicAdd(&sums[F + c4 * 4 + 1], s2.y);
        atomicAdd(&sums[F + c4 * 4 + 2], s2.z);
        atomicAdd(&sums[F + c4 * 4 + 3], s2.w);
    }
}

// BN apply for F=64 with in-kernel prep (reads stats directly)
__global__ void k_bn_apply64p(const float* __restrict__ y, const float* __restrict__ stats,
                              const float* __restrict__ g, const float* __restrict__ be,
                              float invN, float* __restrict__ outp, int n) {
    constexpr int C4 = 16;
    int t = blockIdx.x * blockDim.x + threadIdx.x;
    if (t >= n * C4) return;
    int node = t / C4, c4 = t % C4;
    float4 v = ((const float4*)y)[t];
    float4 o;
#pragma unroll
    for (int i = 0; i < 4; i++) {
        int ch = c4 * 4 + i;
        float mean = stats[ch] * invN;
        float var = stats[64 + ch] * invN - mean * mean;
        float s = g[ch] * rsqrtf(var + 1e-5f);
        float sh = be[ch] - mean * s;
        float vi = (i == 0) ? v.x : (i == 1) ? v.y : (i == 2) ? v.z : v.w;
        float oi = vi * s + sh;
        if (i == 0) o.x = oi;
        else if (i == 1) o.y = oi;
        else if (i == 2) o.z = oi;
        else o.w = oi;
    }
    ((float4*)(outp + (long long)node * 320))[c4] = o;
}

// ---------------------------------------------------------------------------
extern "C" void kernel_launch(void* const* d_in, const int* in_sizes, int n_in,
                              void* d_out, int out_size, void* d_ws, size_t ws_size,
                              hipStream_t stream) {
    const float* x   = (const float*)d_in[0];
    const int*   adj = (const int*)d_in[1];
    const float* W1  = (const float*)d_in[2];
    const float* as1 = (const float*)d_in[3];
    const float* ad1 = (const float*)d_in[4];
    const float* b1  = (const float*)d_in[5];
    const float* g1  = (const float*)d_in[6];
    const float* be1 = (const float*)d_in[7];
    const float* W2  = (const float*)d_in[8];
    const float* as2 = (const float*)d_in[9];
    const float* ad2 = (const float*)d_in[10];
    const float* b2  = (const float*)d_in[11];
    const float* g2  = (const float*)d_in[12];
    const float* be2 = (const float*)d_in[13];
    const float* W3  = (const float*)d_in[14];
    const float* as3 = (const float*)d_in[15];
    const float* ad3 = (const float*)d_in[16];
    const float* b3  = (const float*)d_in[17];
    const float* g3  = (const float*)d_in[18];
    const float* be3 = (const float*)d_in[19];
    float* out = (float*)d_out;

    const int N = in_sizes[0] / 128;
    const int E = in_sizes[1] / 2;

    // workspace (stats and bcntp contiguous -> one memset)
    float* ws    = (float*)d_ws;
    float* ybuf  = ws;                          // N*128
    float* al_s  = ybuf + (size_t)N * 128;      // N*2
    float* al_d  = al_s + (size_t)N * 2;        // N*2
    float* stats1 = al_d + (size_t)N * 2;       // 256
    float* stats2 = stats1 + 256;               // 256
    float* stats3 = stats2 + 256;               // 256
    int* bcntp     = (int*)(stats3 + 256);      // 512*16 (line-padded counts)
    int* bcurp     = bcntp + 8192;              // 512*16 (line-padded cursors)
    int* bbase     = bcurp + 8192;              // 513
    int* row_start = bbase + 513;               // N+1
    int* col       = row_start + (N + 1);       // E+N

    // xwb: 256B-ALIGNED (R25 fix -- misalignment cost +25% line fetches)
    uintptr_t xp = (uintptr_t)(col + (E + N));
    xp = (xp + 255) & ~(uintptr_t)255;
    uint* xwb = (uint*)xp;                      // N*64 uints (bf16x2)

    // pre-converted W (bf16 hi/lo fragment blocks), 256B-aligned
    uintptr_t wp = (uintptr_t)(xwb + (size_t)N * 64);
    wp = (wp + 255) & ~(uintptr_t)255;
    ushort* w1hi = (ushort*)wp;                 // 128*128
    ushort* w1lo = w1hi + 16384;
    ushort* w2hi = w1lo + 16384;
    ushort* w2lo = w2hi + 16384;
    ushort* w3hi = w2lo + 16384;                // 64*128
    ushort* w3lo = w3hi + 8192;

    // packed bucket-sorted edges alias ybuf (dead before k_agg L1 writes it)
    int* pk = (int*)ybuf;                       // E+N ints

    const int* esrc = adj;
    const int* edst = adj + E;

    const int B = 256;
    auto cdiv = [](int a, int b) { return (a + b - 1) / b; };

    // ---- ONE memset: stats (768 floats) + bcntp (8192 ints) contiguous ----
    hipMemsetAsync(stats1, 0, 768 * sizeof(float) + 8192 * sizeof(int), stream);

    // ---- all W conversions in one launch (stats-independent) ----
    k_wconvAll<<<80, 256, 0, stream>>>(W1, W2, W3, w1hi, w1lo, w2hi, w2lo, w3hi, w3lo);

    // ---- CSR build: bucket counting sort ----
    const int NB = (N + 127) >> 7;              // buckets (needs N<=65536)
    k_bcount<<<128, 256, 0, stream>>>(edst, E, bcntp);
    k_bscan<<<1, 512, 0, stream>>>(bcntp, bbase, bcurp, NB, N, E + N, row_start);
    int nchunk = (E + N + 8191) >> 13;
    k_bscatter<<<nchunk, 512, 0, stream>>>(esrc, edst, E, N, bcurp, pk);
    k_bfill<<<NB, 256, 0, stream>>>(pk, bbase, N, row_start, col);

    const float invN = 1.f / (float)N;
    ushort* xwb_us = (ushort*)xwb;

    // ---- layer 1: 128 -> 128 (H=2), raw A ----
    k_gemm5<128, 2, false><<<cdiv(N, 64), B, 0, stream>>>(
        x, w1hi, w1lo, as1, ad1, xwb_us, al_s, al_d,
        nullptr, nullptr, nullptr, 0.f, nullptr, N);
    k_agg<128, 2><<<cdiv(N, 4), B, 0, stream>>>(xwb, al_s, al_d, row_start, col, b1, ybuf, N);
    k_bn_stats<128><<<256, B, 0, stream>>>(ybuf, stats1, N);

    // ---- layer 2: A-side BN1; gemm also emits out+0 = BN1(ybuf) ----
    k_gemm5<128, 2, true><<<cdiv(N, 64), B, 0, stream>>>(
        ybuf, w2hi, w2lo, as2, ad2, xwb_us, al_s, al_d,
        stats1, g1, be1, invN, out + 0, N);
    k_agg<128, 2><<<cdiv(N, 4), B, 0, stream>>>(xwb, al_s, al_d, row_start, col, b2, ybuf, N);
    k_bn_stats<128><<<256, B, 0, stream>>>(ybuf, stats2, N);

    // ---- layer 3: A-side BN2; gemm also emits out+128 = BN2(ybuf) ----
    k_gemm5<64, 1, true><<<cdiv(N, 64), B, 0, stream>>>(
        ybuf, w3hi, w3lo, as3, ad3, xwb_us, al_s, al_d,
        stats2, g2, be2, invN, out + 128, N);
    k_agg<64, 1><<<cdiv(N, 4), B, 0, stream>>>(xwb, al_s, al_d, row_start, col, b3, ybuf, N);
    k_bn_stats<64><<<256, B, 0, stream>>>(ybuf, stats3, N);
    k_bn_apply64p<<<cdiv(N * 16, B), B, 0, stream>>>(ybuf, stats3, g3, be3, invN,
                                                     out + 256, N);
}